// Round 1
// 859.312 us; speedup vs baseline: 1.1036x; 1.1036x over previous
//
#include <hip/hip_runtime.h>
#include <cstddef>

// Problem dims
#define NR 4096      // batch
#define CDIM 512     // concepts
#define HDIM 128     // hidden
#define TSTEPS 64
#define DDIM 20
#define KTOP 10

typedef __attribute__((ext_vector_type(8))) short short8;
typedef __attribute__((ext_vector_type(4))) float f32x4;

__device__ __forceinline__ unsigned short f2bf(float f) {
    union { float f; unsigned u; } x; x.f = f;
    unsigned r = (x.u + 0x7fffu + ((x.u >> 16) & 1u)) >> 16;
    return (unsigned short)r;
}
// truncating bf16 (for lo planes: residual already ~2^-9, truncation error 2^-17)
__device__ __forceinline__ unsigned short f2bf_t(float f) {
    union { float f; unsigned u; } x; x.f = f;
    return (unsigned short)(x.u >> 16);
}
__device__ __forceinline__ float bf2f(unsigned short h) {
    union { unsigned u; float f; } x; x.u = ((unsigned)h) << 16;
    return x.f;
}
// inf-safe, clamp-free activations (v_exp + v_rcp only)
__device__ __forceinline__ float sigm(float v) {
    return __builtin_amdgcn_rcpf(1.f + __expf(-v));   // v->-inf: rcp(inf)=0; v->+inf: rcp(1)=1
}
__device__ __forceinline__ float tanh_f(float v) {
    return 1.f - 2.f * __builtin_amdgcn_rcpf(1.f + __expf(2.f * v)); // saturates to +-1
}

#define MFMA16(a, b, c) __builtin_amdgcn_mfma_f32_16x16x32_bf16(a, b, c, 0, 0, 0)

// ---------------------------------------------------------------------------
// Generic MFMA GEMM. flags: 1 bias, 2 lrelu, 4 atomicAdd (split-K),
// 8 fused subtract: sub[r,c] = aux[r,c] - C[r,c], 16 pre-packed A (BT layout:
// same [t][c][lane][8] layout as B packs; A-fragment index == B index with
// t = bm>>4, so existing pbt packs serve as A directly).
// ---------------------------------------------------------------------------
struct MG {
    const float* A; const unsigned short* Bh; const unsigned short* Bl;
    const float* bias; float* C; const float* aux; float* sub;
    const unsigned short* Ah; const unsigned short* Al;
    int N, K, kchunk, flags;
};

__global__ __launch_bounds__(256) void mfma_gemm(MG g)
{
    const int tid = threadIdx.x;
    const int w = tid >> 6, lane = tid & 63, quad = lane >> 4, lm = lane & 15;
    const int bm = (blockIdx.y << 6) + (w << 4);
    const int bn = blockIdx.x << 6;
    const int NC = g.K >> 5;
    const int c0 = (blockIdx.z * g.kchunk) >> 5;
    const int c1 = c0 + (g.kchunk >> 5);
    const float* arow = g.A + (size_t)(bm + lm) * g.K;
    const int packA = g.flags & 16;
    f32x4 acc[4];
    #pragma unroll
    for (int t = 0; t < 4; t++) acc[t] = (f32x4){0.f, 0.f, 0.f, 0.f};

    for (int c = c0; c < c1; c++) {
        short8 ah, al;
        if (packA) {
            size_t aidx = ((size_t)((bm >> 4) * NC + c) * 64 + lane) * 8;
            ah = *(const short8*)(g.Ah + aidx);
            al = *(const short8*)(g.Al + aidx);
        } else {
            const float* ap = arow + (c << 5) + (quad << 3);
            float4 a0 = *(const float4*)ap;
            float4 a1 = *(const float4*)(ap + 4);
            #pragma unroll
            for (int jj = 0; jj < 4; jj++) {
                float f = (&a0.x)[jj];
                unsigned short h = f2bf(f);
                ah[jj] = h; al[jj] = f2bf_t(f - bf2f(h));
                f = (&a1.x)[jj];
                h = f2bf(f);
                ah[4 + jj] = h; al[4 + jj] = f2bf_t(f - bf2f(h));
            }
        }
        #pragma unroll
        for (int t = 0; t < 4; t++) {
            size_t bidx = ((size_t)(((bn >> 4) + t) * NC + c) * 64 + lane) * 8;
            short8 bh = *(const short8*)(g.Bh + bidx);
            short8 bl = *(const short8*)(g.Bl + bidx);
            acc[t] = MFMA16(ah, bh, acc[t]);
            acc[t] = MFMA16(ah, bl, acc[t]);
            acc[t] = MFMA16(al, bh, acc[t]);
        }
    }
    #pragma unroll
    for (int t = 0; t < 4; t++) {
        #pragma unroll
        for (int rg = 0; rg < 4; rg++) {
            int row = bm + (quad << 2) + rg;
            int col = bn + (t << 4) + lm;
            float v = acc[t][rg];
            if (g.flags & 1) v += g.bias[col];
            if (g.flags & 2) v = v > 0.f ? v : 0.01f * v;
            if (g.flags & 4) atomicAdd(&g.C[(size_t)row * g.N + col], v);
            else g.C[(size_t)row * g.N + col] = v;
            if (g.flags & 8)
                g.sub[(size_t)row * g.N + col] = g.aux[(size_t)row * g.N + col] - v;
        }
    }
}

// B-pack from [N,K] rows; layout [nt][c][lane][8], hi/lo planes.
__global__ void pack_bt(const float* __restrict__ src, unsigned short* __restrict__ hi,
                        unsigned short* __restrict__ lo, int K, int total)
{
    int idx = blockIdx.x * 256 + threadIdx.x;
    if (idx >= total) return;
    int NC = K >> 5;
    int lane = idx & 63;
    int c = (idx >> 6) % NC;
    int t = idx / (NC * 64);
    int n = (t << 4) + (lane & 15);
    int kb = (c << 5) + ((lane >> 4) << 3);
    #pragma unroll
    for (int j = 0; j < 8; j++) {
        float f = src[(size_t)n * K + kb + j];
        unsigned short h = f2bf(f);
        hi[(size_t)idx * 8 + j] = h;
        lo[(size_t)idx * 8 + j] = f2bf_t(f - bf2f(h));
    }
}

// Combined pack (K = HDIM = 128 only): BT (B[n][k]) + KN (B[k][n]) in one pass.
__global__ void pack_both(const float* __restrict__ src,
                          unsigned short* __restrict__ bth, unsigned short* __restrict__ btl,
                          unsigned short* __restrict__ knh, unsigned short* __restrict__ knl,
                          int N, int total_kn)
{
    int idx = blockIdx.x * 256 + threadIdx.x;
    int lane = idx & 63;
    int totBT = (N >> 4) * 256;
    if (idx < totBT) {
        int c = (idx >> 6) & 3;
        int t = idx >> 8;
        int n = (t << 4) + (lane & 15);
        int kb = (c << 5) + ((lane >> 4) << 3);
        #pragma unroll
        for (int j = 0; j < 8; j++) {
            float f = src[(size_t)n * HDIM + kb + j];
            unsigned short h = f2bf(f);
            bth[(size_t)idx * 8 + j] = h;
            btl[(size_t)idx * 8 + j] = f2bf_t(f - bf2f(h));
        }
    }
    if (idx < total_kn) {
        int NC = N >> 5;
        int c = (idx >> 6) % NC;
        int t = idx / (NC * 64);
        int n = (t << 4) + (lane & 15);
        int kb = (c << 5) + ((lane >> 4) << 3);
        #pragma unroll
        for (int j = 0; j < 8; j++) {
            float f = src[(size_t)(kb + j) * HDIM + n];
            unsigned short h = f2bf(f);
            knh[(size_t)idx * 8 + j] = h;
            knl[(size_t)idx * 8 + j] = f2bf_t(f - bf2f(h));
        }
    }
}

// Pack all seven [128,128] weight matrices in one launch.
struct W7 {
    const float* src[7];
    unsigned short* hi[7];
    unsigned short* lo[7];
};
__global__ void pack_w7(W7 p)
{
    int idx = blockIdx.x * 256 + threadIdx.x;   // 7 * 2048
    if (idx >= 7 * 2048) return;
    int m = idx >> 11;
    int r = idx & 2047;
    int lane = r & 63;
    int c = (r >> 6) & 3;
    int t = r >> 8;
    int n = (t << 4) + (lane & 15);
    int kb = (c << 5) + ((lane >> 4) << 3);
    const float* src = p.src[m];
    unsigned short* hi = p.hi[m];
    unsigned short* lo = p.lo[m];
    #pragma unroll
    for (int j = 0; j < 8; j++) {
        float f = src[(size_t)n * HDIM + kb + j];
        unsigned short h = f2bf(f);
        hi[(size_t)r * 8 + j] = h;
        lo[(size_t)r * 8 + j] = f2bf_t(f - bf2f(h));
    }
}

// ---------------------------------------------------------------------------
// scan_topk: wave-shuffle argmax reduce, 2 barriers/round (was ~9).
// Tie-break identical to before: value desc, index asc. Similarity values use
// IEEE division (bit-identical to previous kernel) so the selected set cannot
// shift.
// ---------------------------------------------------------------------------
__global__ __launch_bounds__(256) void scan_topk(const float* __restrict__ S,
        const float* __restrict__ hn, float* __restrict__ diagv,
        float* __restrict__ tvals, int* __restrict__ tidx)
{
    int row = blockIdx.x;
    const float* d = S + (size_t)row * NR;
    int tid = threadIdx.x;
    int wv = tid >> 6, lane = tid & 63;
    float hi_ = hn[row];
    float lv[16];
    #pragma unroll
    for (int i = 0; i < 16; i++) {
        int j = tid + (i << 8);
        float v = d[j] / fmaxf(hi_ * hn[j], 1e-12f);
        if (j == row) { diagv[row] = v; v = 0.f; }
        lv[i] = v;
    }
    __shared__ float sv[4];
    __shared__ int si[4];
    for (int k = 0; k < KTOP; k++) {
        float bv = -INFINITY; int bi = 0x7fffffff;
        #pragma unroll
        for (int i = 0; i < 16; i++) {
            int j = tid + (i << 8);
            if (lv[i] > bv || (lv[i] == bv && j < bi)) { bv = lv[i]; bi = j; }
        }
        #pragma unroll
        for (int m = 1; m < 64; m <<= 1) {
            float ov = __shfl_xor(bv, m); int oi = __shfl_xor(bi, m);
            if (ov > bv || (ov == bv && oi < bi)) { bv = ov; bi = oi; }
        }
        if (lane == 0) { sv[wv] = bv; si[wv] = bi; }
        __syncthreads();
        bv = sv[0]; bi = si[0];
        #pragma unroll
        for (int w = 1; w < 4; w++) {
            float ov = sv[w]; int oi = si[w];
            if (ov > bv || (ov == bv && oi < bi)) { bv = ov; bi = oi; }
        }
        if (tid == 0) { tvals[row * KTOP + k] = bv; tidx[row * KTOP + k] = bi; }
        if ((bi & 255) == tid) lv[bi >> 8] = -INFINITY;
        __syncthreads();   // protect sv/si reuse next round
    }
}

// ---------------------------------------------------------------------------
// hc2s_flash: rcp instead of IEEE div in the per-tile normalize (4/iter x 64),
// truncating lo-plane conversions.
// ---------------------------------------------------------------------------
__global__ __launch_bounds__(256) void hc2s_flash(
    const float* __restrict__ hsh, const float* __restrict__ hn,
    const float* __restrict__ hhn, const float* __restrict__ v2,
    const unsigned short* __restrict__ Bh, const unsigned short* __restrict__ Bl,
    const unsigned short* __restrict__ Vh, const unsigned short* __restrict__ Vl,
    float* __restrict__ O)
{
    __shared__ __attribute__((aligned(16))) unsigned short Ph[16 * 72];
    __shared__ __attribute__((aligned(16))) unsigned short Pl[16 * 72];
    __shared__ float redmax[4][16];
    __shared__ float redsum[4][16];

    const int tid = threadIdx.x;
    const int wv = tid >> 6, lane = tid & 63, quad = lane >> 4, lm = lane & 15;
    const int bm = blockIdx.x << 4;

    short8 ahh[4], ahl[4];
    #pragma unroll
    for (int c = 0; c < 4; c++) {
        const float* ap = hsh + (size_t)(bm + lm) * HDIM + (c << 5) + (quad << 3);
        float4 a0 = *(const float4*)ap;
        float4 a1 = *(const float4*)(ap + 4);
        #pragma unroll
        for (int j = 0; j < 4; j++) {
            float f = (&a0.x)[j];
            unsigned short h = f2bf(f);
            ahh[c][j] = h; ahl[c][j] = f2bf_t(f - bf2f(h));
            f = (&a1.x)[j];
            h = f2bf(f);
            ahh[c][4 + j] = h; ahl[c][4 + j] = f2bf_t(f - bf2f(h));
        }
    }
    float hnr[4];
    #pragma unroll
    for (int rg = 0; rg < 4; rg++) hnr[rg] = hn[bm + (quad << 2) + rg];

    float m_old[4], l_old[4];
    #pragma unroll
    for (int rg = 0; rg < 4; rg++) { m_old[rg] = -INFINITY; l_old[rg] = 0.f; }
    f32x4 o0 = (f32x4){0.f, 0.f, 0.f, 0.f};
    f32x4 o1 = (f32x4){0.f, 0.f, 0.f, 0.f};

    for (int jt = 0; jt < NR / 64; jt++) {
        f32x4 s = (f32x4){0.f, 0.f, 0.f, 0.f};
        int nt = (jt << 2) + wv;
        #pragma unroll
        for (int c = 0; c < 4; c++) {
            size_t bidx = ((size_t)(nt * 4 + c) * 64 + lane) * 8;
            short8 bh = *(const short8*)(Bh + bidx);
            short8 bl = *(const short8*)(Bl + bidx);
            s = MFMA16(ahh[c], bh, s);
            s = MFMA16(ahh[c], bl, s);
            s = MFMA16(ahl[c], bh, s);
        }
        int col = (jt << 6) + (wv << 4) + lm;
        float hc = hhn[col];
        float vm = v2[col];
        float sv[4];
        #pragma unroll
        for (int rg = 0; rg < 4; rg++) {
            float v = s[rg] * __builtin_amdgcn_rcpf(fmaxf(hnr[rg] * hc, 1e-12f));
            sv[rg] = (vm == 0.f) ? -1e9f : v;
        }
        float mx[4];
        #pragma unroll
        for (int rg = 0; rg < 4; rg++) {
            float m = sv[rg];
            #pragma unroll
            for (int d = 1; d < 16; d <<= 1) m = fmaxf(m, __shfl_xor(m, d));
            mx[rg] = m;
        }
        if (lm == 0) {
            #pragma unroll
            for (int rg = 0; rg < 4; rg++) redmax[wv][(quad << 2) + rg] = mx[rg];
        }
        __syncthreads();
        float m_new[4], alpha[4];
        #pragma unroll
        for (int rg = 0; rg < 4; rg++) {
            int r = (quad << 2) + rg;
            float mt = fmaxf(fmaxf(redmax[0][r], redmax[1][r]),
                             fmaxf(redmax[2][r], redmax[3][r]));
            m_new[rg] = fmaxf(m_old[rg], mt);
            alpha[rg] = __expf(m_old[rg] - m_new[rg]);
        }
        float psum[4];
        #pragma unroll
        for (int rg = 0; rg < 4; rg++) {
            float p = __expf(sv[rg] - m_new[rg]);
            float ssum = p;
            #pragma unroll
            for (int d = 1; d < 16; d <<= 1) ssum += __shfl_xor(ssum, d);
            psum[rg] = ssum;
            int off = ((quad << 2) + rg) * 72 + (wv << 4) + lm;
            unsigned short h = f2bf(p);
            Ph[off] = h;
            Pl[off] = f2bf_t(p - bf2f(h));
        }
        if (lm == 0) {
            #pragma unroll
            for (int rg = 0; rg < 4; rg++) redsum[wv][(quad << 2) + rg] = psum[rg];
        }
        __syncthreads();
        #pragma unroll
        for (int rg = 0; rg < 4; rg++) {
            int r = (quad << 2) + rg;
            float ts = redsum[0][r] + redsum[1][r] + redsum[2][r] + redsum[3][r];
            l_old[rg] = l_old[rg] * alpha[rg] + ts;
            m_old[rg] = m_new[rg];
            o0[rg] *= alpha[rg];
            o1[rg] *= alpha[rg];
        }
        int vt0 = wv << 1;
        #pragma unroll
        for (int c2 = 0; c2 < 2; c2++) {
            int poff = lm * 72 + (c2 << 5) + (quad << 3);
            short8 pah = *(const short8*)&Ph[poff];
            short8 pal = *(const short8*)&Pl[poff];
            int cg = (jt << 1) + c2;
            size_t b0 = ((size_t)(vt0 * 128 + cg) * 64 + lane) * 8;
            size_t b1 = ((size_t)((vt0 + 1) * 128 + cg) * 64 + lane) * 8;
            short8 vh0 = *(const short8*)(Vh + b0);
            short8 vl0 = *(const short8*)(Vl + b0);
            short8 vh1 = *(const short8*)(Vh + b1);
            short8 vl1 = *(const short8*)(Vl + b1);
            o0 = MFMA16(pah, vh0, o0);
            o0 = MFMA16(pah, vl0, o0);
            o0 = MFMA16(pal, vh0, o0);
            o1 = MFMA16(pah, vh1, o1);
            o1 = MFMA16(pah, vl1, o1);
            o1 = MFMA16(pal, vh1, o1);
        }
        __syncthreads();
    }
    #pragma unroll
    for (int rg = 0; rg < 4; rg++) {
        int row = bm + (quad << 2) + rg;
        float inv = __builtin_amdgcn_rcpf(l_old[rg]);
        O[(size_t)row * HDIM + (wv << 5) + lm] = o0[rg] * inv;
        O[(size_t)row * HDIM + (wv << 5) + 16 + lm] = o1[rg] * inv;
    }
}

// ---------------------------------------------------------------------------
// GRU weight pack
// ---------------------------------------------------------------------------
__global__ void pack_wb(const float* __restrict__ W, unsigned short* __restrict__ Wp,
                        int K, int nch)
{
    int idx = blockIdx.x * 256 + threadIdx.x;
    if (idx >= 24 * nch * 64) return;
    int lane = idx & 63;
    int c = (idx >> 6) % nch;
    int t = idx / (nch * 64);
    int n = t * 16 + (lane & 15);
    int kb = c * 32 + (lane >> 4) * 8;
    #pragma unroll
    for (int j = 0; j < 8; j++) {
        int k = kb + j;
        float f = (k < K) ? W[(size_t)n * K + k] : 0.f;
        Wp[(size_t)idx * 8 + j] = f2bf(f);
    }
}

// x [N, D*T] -> seq [T, N, D], pre-split into bf16 hi|lo packed in one u32
// (halves GRU staging traffic and removes per-step conversion VALU).
__global__ void seq_transpose(const float* __restrict__ x, unsigned* __restrict__ seq)
{
    int idx = blockIdx.x * 256 + threadIdx.x;
    int d = idx % DDIM;
    int r = idx / DDIM;
    int n = r & (NR - 1);
    int t = r >> 12;
    float v = x[(size_t)n * (DDIM * TSTEPS) + d * TSTEPS + t];
    unsigned short h = f2bf(v);
    unsigned short l = f2bf_t(v - bf2f(h));
    seq[idx] = (unsigned)h | ((unsigned)l << 16);
}

// ---------------------------------------------------------------------------
// MFMA 2-layer GRU, 8 waves, register weights, TIME-DOUBLE-BUFFERED h state.
// This revision: t-loop unrolled by 2 so the buffer index is a compile-time
// constant (LDS addressing becomes base+immediate), clamp-free activations,
// truncating lo-plane converts, x pre-packed as bf16 hi|lo u32 with the
// global load issued at step top (latency hidden under L0 MFMAs) and the
// LDS write landing in phase 2 (same ordering as before: the single
// per-step barrier orders xA[rb] writes before the next step's reads).
// ---------------------------------------------------------------------------
__global__ __launch_bounds__(512) void gru_mfma(
    const unsigned* __restrict__ seq,
    const unsigned short* __restrict__ wih0p,
    const unsigned short* __restrict__ whh0p,
    const unsigned short* __restrict__ wih1p,
    const unsigned short* __restrict__ whh1p,
    const float* __restrict__ bih0, const float* __restrict__ bhh0,
    const float* __restrict__ bih1, const float* __restrict__ bhh1,
    float* __restrict__ xh)
{
    __shared__ __attribute__((aligned(16))) unsigned short hA[2][2][2][16 * 136]; // 34.8 KB
    __shared__ __attribute__((aligned(16))) unsigned short xA[2][2][16 * 40];     // 5.1 KB

    const int tid = threadIdx.x;
    const int w2 = tid >> 6;
    const int lane = tid & 63;
    const int quad = lane >> 4;
    const int lm = lane & 15;
    const int n0 = blockIdx.x << 4;
    const int j = (w2 << 4) + lm;

    for (int i = tid; i < 2 * 2 * 2 * 16 * 136; i += 512) ((unsigned short*)hA)[i] = 0;
    for (int i = tid; i < 2 * 2 * 16 * 40; i += 512) ((unsigned short*)xA)[i] = 0;

    float br0 = bih0[j] + bhh0[j];
    float bz0 = bih0[128 + j] + bhh0[128 + j];
    float bni0 = bih0[256 + j];
    float bnh0 = bhh0[256 + j];
    float br1 = bih1[j] + bhh1[j];
    float bz1 = bih1[128 + j] + bhh1[128 + j];
    float bni1 = bih1[256 + j];
    float bnh1 = bhh1[256 + j];

    // register-resident weight fragments (t-invariant)
    short8 W0x[3], W0h[3][4], W1x[3][4], W1h[3][4];
    {
        const int lb = lane * 8;
        W0x[0] = *(const short8*)&wih0p[(size_t)(w2) * 512 + lb];
        W0x[1] = *(const short8*)&wih0p[(size_t)(8 + w2) * 512 + lb];
        W0x[2] = *(const short8*)&wih0p[(size_t)(16 + w2) * 512 + lb];
        #pragma unroll
        for (int c = 0; c < 4; c++) {
            W0h[0][c] = *(const short8*)&whh0p[(size_t)((w2) * 4 + c) * 512 + lb];
            W0h[1][c] = *(const short8*)&whh0p[(size_t)((8 + w2) * 4 + c) * 512 + lb];
            W0h[2][c] = *(const short8*)&whh0p[(size_t)((16 + w2) * 4 + c) * 512 + lb];
            W1x[0][c] = *(const short8*)&wih1p[(size_t)((w2) * 4 + c) * 512 + lb];
            W1x[1][c] = *(const short8*)&wih1p[(size_t)((8 + w2) * 4 + c) * 512 + lb];
            W1x[2][c] = *(const short8*)&wih1p[(size_t)((16 + w2) * 4 + c) * 512 + lb];
            W1h[0][c] = *(const short8*)&whh1p[(size_t)((w2) * 4 + c) * 512 + lb];
            W1h[1][c] = *(const short8*)&whh1p[(size_t)((8 + w2) * 4 + c) * 512 + lb];
            W1h[2][c] = *(const short8*)&whh1p[(size_t)((16 + w2) * 4 + c) * 512 + lb];
        }
    }

    const int aoff = lm * 136 + quad * 8;
    const int xoff = lm * 40 + quad * 8;
    const bool stager = tid < 16 * DDIM;
    const int soff = stager ? (tid / DDIM) * 40 + (tid % DDIM) : 0;  // hoisted div/mod

    const unsigned* sp = seq + (size_t)n0 * DDIM;
    if (stager) {
        unsigned v = sp[tid];
        xA[0][0][soff] = (unsigned short)(v & 0xffffu);
        xA[0][1][soff] = (unsigned short)(v >> 16);
    }
    sp += (size_t)NR * DDIM;
    __syncthreads();

#define GRU_STEP(B, RB, LAST)                                                     \
{                                                                                 \
    unsigned xv = 0;                                                              \
    if (!(LAST) && stager) xv = sp[tid];   /* issue early, write late */          \
    f32x4 accr = (f32x4){0.f, 0.f, 0.f, 0.f};                                     \
    f32x4 accz = (f32x4){0.f, 0.f, 0.f, 0.f};                                     \
    f32x4 accni = (f32x4){0.f, 0.f, 0.f, 0.f};                                    \
    f32x4 accnh = (f32x4){0.f, 0.f, 0.f, 0.f};                                    \
    /* ---- phase 1: L0 (reads hA[RB][0], xA[B]) ---- */                          \
    {                                                                             \
        short8 axh = *(const short8*)&xA[B][0][xoff];                             \
        short8 axl = *(const short8*)&xA[B][1][xoff];                             \
        accr = MFMA16(axh, W0x[0], accr);                                         \
        accr = MFMA16(axl, W0x[0], accr);                                         \
        accz = MFMA16(axh, W0x[1], accz);                                         \
        accz = MFMA16(axl, W0x[1], accz);                                         \
        accni = MFMA16(axh, W0x[2], accni);                                       \
        accni = MFMA16(axl, W0x[2], accni);                                       \
    }                                                                             \
    _Pragma("unroll")                                                             \
    for (int c = 0; c < 4; c++) {                                                 \
        short8 ahh = *(const short8*)&hA[RB][0][0][aoff + c * 32];                \
        short8 ahl = *(const short8*)&hA[RB][0][1][aoff + c * 32];                \
        accr = MFMA16(ahh, W0h[0][c], accr);                                      \
        accr = MFMA16(ahl, W0h[0][c], accr);                                      \
        accz = MFMA16(ahh, W0h[1][c], accz);                                      \
        accz = MFMA16(ahl, W0h[1][c], accz);                                      \
        accnh = MFMA16(ahh, W0h[2][c], accnh);                                    \
        accnh = MFMA16(ahl, W0h[2][c], accnh);                                    \
    }                                                                             \
    float hold[4];                                                                \
    _Pragma("unroll")                                                             \
    for (int rg = 0; rg < 4; rg++) {                                              \
        int off = (quad * 4 + rg) * 136 + j;                                      \
        hold[rg] = bf2f(hA[RB][0][0][off]) + bf2f(hA[RB][0][1][off]);             \
    }                                                                             \
    /* ---- phase 2: write h0-new -> hA[B][0]; stage x(t+1) -> xA[RB] ---- */     \
    _Pragma("unroll")                                                             \
    for (int rg = 0; rg < 4; rg++) {                                              \
        float r = sigm(accr[rg] + br0);                                           \
        float z = sigm(accz[rg] + bz0);                                           \
        float nc = tanh_f(accni[rg] + bni0 + r * (accnh[rg] + bnh0));             \
        float hnew = nc + z * (hold[rg] - nc);                                    \
        int off = (quad * 4 + rg) * 136 + j;                                      \
        unsigned short hh_ = f2bf(hnew);                                          \
        hA[B][0][0][off] = hh_;                                                   \
        hA[B][0][1][off] = f2bf_t(hnew - bf2f(hh_));                              \
    }                                                                             \
    if (!(LAST) && stager) {                                                      \
        xA[RB][0][soff] = (unsigned short)(xv & 0xffffu);                         \
        xA[RB][1][soff] = (unsigned short)(xv >> 16);                             \
    }                                                                             \
    __syncthreads();     /* the ONE barrier: h0-new + x(t+1) visible */           \
    /* ---- phase 3: L1 (reads hA[B][0] new, hA[RB][1] old) ---- */               \
    accr = (f32x4){0.f, 0.f, 0.f, 0.f};                                           \
    accz = (f32x4){0.f, 0.f, 0.f, 0.f};                                           \
    accni = (f32x4){0.f, 0.f, 0.f, 0.f};                                          \
    accnh = (f32x4){0.f, 0.f, 0.f, 0.f};                                          \
    _Pragma("unroll")                                                             \
    for (int c = 0; c < 4; c++) {                                                 \
        short8 a0h = *(const short8*)&hA[B][0][0][aoff + c * 32];                 \
        short8 a0l = *(const short8*)&hA[B][0][1][aoff + c * 32];                 \
        short8 a1h = *(const short8*)&hA[RB][1][0][aoff + c * 32];                \
        short8 a1l = *(const short8*)&hA[RB][1][1][aoff + c * 32];                \
        accr = MFMA16(a0h, W1x[0][c], accr);                                      \
        accr = MFMA16(a0l, W1x[0][c], accr);                                      \
        accr = MFMA16(a1h, W1h[0][c], accr);                                      \
        accr = MFMA16(a1l, W1h[0][c], accr);                                      \
        accz = MFMA16(a0h, W1x[1][c], accz);                                      \
        accz = MFMA16(a0l, W1x[1][c], accz);                                      \
        accz = MFMA16(a1h, W1h[1][c], accz);                                      \
        accz = MFMA16(a1l, W1h[1][c], accz);                                      \
        accni = MFMA16(a0h, W1x[2][c], accni);                                    \
        accni = MFMA16(a0l, W1x[2][c], accni);                                    \
        accnh = MFMA16(a1h, W1h[2][c], accnh);                                    \
        accnh = MFMA16(a1l, W1h[2][c], accnh);                                    \
    }                                                                             \
    _Pragma("unroll")                                                             \
    for (int rg = 0; rg < 4; rg++) {                                              \
        int off = (quad * 4 + rg) * 136 + j;                                      \
        hold[rg] = bf2f(hA[RB][1][0][off]) + bf2f(hA[RB][1][1][off]);             \
    }                                                                             \
    /* ---- phase 4: write h1-new -> hA[B][1] (next step's barrier orders) */     \
    _Pragma("unroll")                                                             \
    for (int rg = 0; rg < 4; rg++) {                                              \
        float r = sigm(accr[rg] + br1);                                           \
        float z = sigm(accz[rg] + bz1);                                           \
        float nc = tanh_f(accni[rg] + bni1 + r * (accnh[rg] + bnh1));             \
        float hnew = nc + z * (hold[rg] - nc);                                    \
        int off = (quad * 4 + rg) * 136 + j;                                      \
        unsigned short hh_ = f2bf(hnew);                                          \
        hA[B][1][0][off] = hh_;                                                   \
        hA[B][1][1][off] = f2bf_t(hnew - bf2f(hh_));                              \
        if (LAST)                                                                 \
            xh[(size_t)(n0 + quad * 4 + rg) * HDIM + j] = hnew;                   \
    }                                                                             \
    sp += (size_t)NR * DDIM;                                                      \
}

    for (int t = 0; t < TSTEPS - 2; t += 2) {
        GRU_STEP(0, 1, false)
        GRU_STEP(1, 0, false)
    }
    GRU_STEP(0, 1, false)
    GRU_STEP(1, 0, true)
#undef GRU_STEP
}

// ---------------------------------------------------------------------------
// den / s2ct (unchanged)
// ---------------------------------------------------------------------------
__global__ __launch_bounds__(256) void den_atomic(const float* __restrict__ cm,
        const float* __restrict__ mv, float* __restrict__ den)
{
    int c = blockIdx.x * 64 + (threadIdx.x & 63);
    int rg = threadIdx.x >> 6;
    int nbase = blockIdx.y * 128;
    float acc = 0.f;
    for (int i = 0; i < 32; i++) {
        int n = nbase + rg + (i << 2);
        acc += cm[(size_t)n * CDIM + c] * mv[n];
    }
    __shared__ float red[4][64];
    red[rg][threadIdx.x & 63] = acc;
    __syncthreads();
    if (rg == 0)
        atomicAdd(&den[c], red[0][threadIdx.x] + red[1][threadIdx.x] +
                           red[2][threadIdx.x] + red[3][threadIdx.x]);
}

__global__ __launch_bounds__(256) void s2ct_trans(const float* __restrict__ cm,
        const float* __restrict__ mv, const float* __restrict__ den,
        float* __restrict__ s2cT)
{
    __shared__ float tile[64][65];
    __shared__ float mvs[64];
    const int tid = threadIdx.x;
    const int n0 = blockIdx.x << 6;
    const int c0 = blockIdx.y << 6;
    const int lc = tid & 63, lr = tid >> 6;
    if (tid < 64) mvs[tid] = mv[n0 + tid];
    #pragma unroll
    for (int i = 0; i < 16; i++) {
        int n = lr + (i << 2);
        tile[n][lc] = cm[(size_t)(n0 + n) * CDIM + c0 + lc];
    }
    __syncthreads();
    #pragma unroll
    for (int i = 0; i < 16; i++) {
        int c = lr + (i << 2);
        float m = tile[lc][c];
        float d = den[c0 + c];
        s2cT[(size_t)(c0 + c) * NR + n0 + lc] = (m * mvs[lc]) / (d * m + 1.f);
    }
}

// ---------------------------------------------------------------------------
// Small helpers
// ---------------------------------------------------------------------------
__global__ void row_norm(const float* __restrict__ a, float* __restrict__ out)
{
    int r = blockIdx.x;
    float acc = 0.f;
    for (int h = threadIdx.x; h < HDIM; h += 64) {
        float v = a[(size_t)r * HDIM + h];
        acc += v * v;
    }
    for (int o = 32; o > 0; o >>= 1) acc += __shfl_down(acc, o);
    if (threadIdx.x == 0) out[r] = sqrtf(acc);
}

__global__ void row_nonzero(const float* __restrict__ a, float* __restrict__ out)
{
    int r = blockIdx.x;
    float acc = 0.f;
    for (int h = threadIdx.x; h < HDIM; h += 64) acc += a[(size_t)r * HDIM + h];
    for (int o = 32; o > 0; o >>= 1) acc += __shfl_down(acc, o);
    if (threadIdx.x == 0) out[r] = (acc != 0.f) ? 1.f : 0.f;
}

__global__ void row_norm_nz(const float* __restrict__ a, float* __restrict__ nrm,
                            float* __restrict__ nz)
{
    int r = blockIdx.x;
    float acc = 0.f, s = 0.f;
    for (int h = threadIdx.x; h < HDIM; h += 64) {
        float v = a[(size_t)r * HDIM + h];
        acc += v * v;
        s += v;
    }
    for (int o = 32; o > 0; o >>= 1) { acc += __shfl_down(acc, o); s += __shfl_down(s, o); }
    if (threadIdx.x == 0) { nrm[r] = sqrtf(acc); nz[r] = (s != 0.f) ? 1.f : 0.f; }
}

// cos_softmax_row: wave-shuffle reductions (2 barriers, was ~16 tree levels),
// __expf + rcp instead of libm expf + IEEE div.
__global__ __launch_bounds__(256) void cos_softmax_row(float* __restrict__ data, int N,
        const float* __restrict__ rn, const float* __restrict__ cn,
        const float* __restrict__ vmask)
{
    int row = blockIdx.x;
    float* d = data + (size_t)row * N;
    int tid = threadIdx.x;
    int wv = tid >> 6, lane = tid & 63;
    __shared__ float red[8];
    float rnv = rn ? rn[row] : 0.f;
    float mx = -INFINITY;
    for (int j = tid; j < N; j += 256) {
        float v = d[j];
        if (cn) v = v * __builtin_amdgcn_rcpf(fmaxf(rnv * cn[j], 1e-12f));
        if (vmask && vmask[j] == 0.f) v = -1e9f;
        d[j] = v;
        mx = fmaxf(mx, v);
    }
    #pragma unroll
    for (int m = 1; m < 64; m <<= 1) mx = fmaxf(mx, __shfl_xor(mx, m));
    if (lane == 0) red[wv] = mx;
    __syncthreads();
    float M = fmaxf(fmaxf(red[0], red[1]), fmaxf(red[2], red[3]));
    float sum = 0.f;
    for (int j = tid; j < N; j += 256) {
        float e = __expf(d[j] - M);
        d[j] = e;
        sum += e;
    }
    #pragma unroll
    for (int m = 1; m < 64; m <<= 1) sum += __shfl_xor(sum, m);
    if (lane == 0) red[4 + wv] = sum;
    __syncthreads();
    float inv = __builtin_amdgcn_rcpf(red[4] + red[5] + red[6] + red[7]);
    for (int j = tid; j < N; j += 256) {
        float v = d[j] * inv;
        if (vmask) v *= vmask[j];
        d[j] = v;
    }
}

__global__ void colsum_scatter(const float* __restrict__ vals, const int* __restrict__ idxs,
                               float* __restrict__ colsum)
{
    int idx = blockIdx.x * 256 + threadIdx.x;
    if (idx < NR * KTOP) atomicAdd(&colsum[idxs[idx]], vals[idx]);
}

__global__ void hh_scatter(const float* __restrict__ vals, const int* __restrict__ idxs,
                           const float* __restrict__ hsh, float* __restrict__ hh)
{
    int p = blockIdx.x;
    int j = idxs[p];
    float v = vals[p];
    int i = p / KTOP;
    atomicAdd(&hh[(size_t)j * HDIM + threadIdx.x], v * hsh[(size_t)i * HDIM + threadIdx.x]);
}

__global__ void hh_diag(const float* __restrict__ colsum, const float* __restrict__ diag,
                        const float* __restrict__ hsh, float* __restrict__ hh)
{
    int idx = blockIdx.x * 256 + threadIdx.x;
    int j = idx >> 7;
    if (colsum[j] != 0.f) hh[idx] += diag[j] * hsh[idx];
}

__global__ void head_kernel(const float* __restrict__ ps, const float* __restrict__ hs,
                            const float* __restrict__ indi, const float* __restrict__ w,
                            const float* __restrict__ b, float* __restrict__ out)
{
    int n = blockIdx.x;
    int t = threadIdx.x;
    float acc = 0.f;
    for (int h = t; h < HDIM; h += 64) {
        size_t k = (size_t)n * HDIM + h;
        acc += (ps[k] + hs[k] + indi[k]) * w[h];
    }
    for (int o = 32; o > 0; o >>= 1) acc += __shfl_down(acc, o);
    if (t == 0) out[n] = acc + b[0];
}

// ---------------------------------------------------------------------------
// host-side helpers
// ---------------------------------------------------------------------------
static inline void mg(hipStream_t s, const float* A, const unsigned short* Bh,
                      const unsigned short* Bl, const float* bias, float* C,
                      int M, int N, int K, int z, int flags,
                      const float* aux = nullptr, float* sub = nullptr,
                      const unsigned short* Ah = nullptr, const unsigned short* Al = nullptr)
{
    MG g{A, Bh, Bl, bias, C, aux, sub, Ah, Al, N, K, K / z,
         flags | (z > 1 ? 4 : 0) | (Ah ? 16 : 0)};
    mfma_gemm<<<dim3(N / 64, M / 64, z), 256, 0, s>>>(g);
}
static inline void pbt(hipStream_t s, const float* src, unsigned short* hi,
                       unsigned short* lo, int N, int K)
{
    int total = (N / 16) * (K / 32) * 64;
    pack_bt<<<(total + 255) / 256, 256, 0, s>>>(src, hi, lo, K, total);
}
static inline void pboth(hipStream_t s, const float* src,
                         unsigned short* bth, unsigned short* btl,
                         unsigned short* knh, unsigned short* knl, int N)
{
    int totBT = (N / 16) * 4 * 64;
    int totKN = 8 * (N / 32) * 64;
    int tot = totBT > totKN ? totBT : totKN;
    pack_both<<<(tot + 255) / 256, 256, 0, s>>>(src, bth, btl, knh, knl, N, totKN);
}

extern "C" void kernel_launch(void* const* d_in, const int* in_sizes, int n_in,
                              void* d_out, int out_size, void* d_ws, size_t ws_size,
                              hipStream_t stream)
{
    (void)in_sizes; (void)n_in; (void)out_size; (void)ws_size;
    const float* x    = (const float*)d_in[0];
    const float* cm   = (const float*)d_in[1];
    const float* mv   = (const float*)d_in[2];
    const float* wih0 = (const float*)d_in[3];
    const float* whh0 = (const float*)d_in[4];
    const float* bih0 = (const float*)d_in[5];
    const float* bhh0 = (const float*)d_in[6];
    const float* wih1 = (const float*)d_in[7];
    const float* whh1 = (const float*)d_in[8];
    const float* bih1 = (const float*)d_in[9];
    const float* bhh1 = (const float*)d_in[10];
    const float* w_ps = (const float*)d_in[11];
    const float* b_ps = (const float*)d_in[12];
    const float* w_hs = (const float*)d_in[13];
    const float* b_hs = (const float*)d_in[14];
    const float* w_ps_fore = (const float*)d_in[15];
    const float* b_ps_fore = (const float*)d_in[16];
    const float* w_hs_fore = (const float*)d_in[17];
    const float* b_hs_fore = (const float*)d_in[18];
    const float* w_ps_back = (const float*)d_in[19];
    const float* b_ps_back = (const float*)d_in[20];
    const float* w_hs_back = (const float*)d_in[21];
    const float* b_hs_back = (const float*)d_in[22];
    const float* w_indi = (const float*)d_in[23];
    const float* b_indi = (const float*)d_in[24];
    const float* w_out  = (const float*)d_in[25];
    const float* b_out  = (const float*)d_in[26];
    float* out = (float*)d_out;

    // ---- workspace layout (floats) ----
    float* ws = (float*)d_ws;
    float* BIG = ws;                         // 16,777,216 (overlaid)
    float* h0 = ws + 16777216;               // 524288 (unused)
    float* h1 = h0 + 524288;                 // x_hidden
    float* den = h1 + 524288;                // 512
    float* v1 = den + 512;                   // 512
    float* hidden = v1 + 512;                // 65536
    float* hidden2 = hidden + 65536;         // 65536
    float* xnorm = hidden2 + 65536;          // 4096
    float* h2n = xnorm + 4096;               // 512
    float* p0 = h2n + 512;                   // 524288
    float* p_shared = p0 + 524288;
    float* p_back = p_shared + 524288;
    float* out_ps = p_back + 524288;
    float* h_shared = out_ps + 524288;
    float* hn = h_shared + 524288;           // 4096
    float* diagv = hn + 4096;                // 4096
    float* colsum = diagv + 4096;            // 4096
    float* tvals = colsum + 4096;            // 40960
    int*   tidx = (int*)(tvals + 40960);     // 40960 ints
    float* hidden_h = (float*)(tidx + 40960);
    float* v2 = hidden_h + 524288;           // 4096
    float* hhn = v2 + 4096;                  // 4096
    float* hsi0 = hhn + 4096;                // 524288
    float* h_si = hsi0 + 524288;
    float* h_back = h_si + 524288;
    float* out_hs = h_back + 524288;
    float* indi = out_hs + 524288;
    float* out_indi = indi + 524288;
    float* extra = out_indi + 524288;

    // GRU-phase overlays inside BIG:
    unsigned* seqt = (unsigned*)BIG;
    unsigned short* wih0p = (unsigned short*)(BIG + 5242880);
    unsigned short* whh0p = wih0p + 12288;
    unsigned short* wih1p = whh0p + 49152;
    unsigned short* whh1p = wih1p + 49152;
    // concept-phase overlays inside BIG:
    float* s2cT = BIG;
    float* L    = BIG + 2097152;
    float* c2s  = BIG + 4194304;
    unsigned short* PB = (unsigned short*)(BIG + 6291456);
    unsigned short* pbt_xh_hi = PB;
    unsigned short* pbt_xh_lo = pbt_xh_hi + 524288;
    unsigned short* pkn_xh_hi = pbt_xh_lo + 524288;
    unsigned short* pkn_xh_lo = pkn_xh_hi + 524288;
    unsigned short* pbt_h2_hi = pkn_xh_lo + 524288;
    unsigned short* pbt_h2_lo = pbt_h2_hi + 65536;
    unsigned short* pkn_h2_hi = pbt_h2_lo + 65536;
    unsigned short* pkn_h2_lo = pkn_h2_hi + 65536;
    unsigned short* wps_hi  = pkn_h2_lo + 65536;
    unsigned short* wps_lo  = wps_hi + 16384;
    unsigned short* wpsb_hi = wps_lo + 16384;
    unsigned short* wpsb_lo = wpsb_hi + 16384;
    unsigned short* wpsf_hi = wpsb_lo + 16384;
    unsigned short* wpsf_lo = wpsf_hi + 16384;
    unsigned short* pbt_hsh_hi = (unsigned short*)p0;
    unsigned short* pbt_hsh_lo = pbt_hsh_hi + 524288;
    unsigned short* pbt_hh_hi = (unsigned short*)indi;
    unsigned short* pbt_hh_lo = pbt_hh_hi + 524288;
    unsigned short* pkn_hh_hi = (unsigned short*)out_indi;
    unsigned short* pkn_hh_lo = pkn_hh_hi + 524288;
    unsigned short* EX = (unsigned short*)extra;
    unsigned short* whs_hi  = EX;            unsigned short* whs_lo  = EX + 16384;
    unsigned short* whsb_hi = EX + 32768;    unsigned short* whsb_lo = EX + 49152;
    unsigned short* whsf_hi = EX + 65536;    unsigned short* whsf_lo = EX + 81920;
    unsigned short* wind_hi = EX + 98304;    unsigned short* wind_lo = EX + 114688;

    // ================= Phase A: MFMA 2-layer GRU =================
    seq_transpose<<<(TSTEPS * NR * DDIM) / 256, 256, 0, stream>>>(x, seqt);
    pack_wb<<<6, 256, 0, stream>>>(wih0, wih0p, DDIM, 1);
    pack_wb<<<24, 256, 0, stream>>>(whh0, whh0p, HDIM, 4);
    pack_wb<<<24, 256, 0, stream>>>(wih1, wih1p, HDIM, 4);
    pack_wb<<<24, 256, 0, stream>>>(whh1, whh1p, HDIM, 4);
    {
        W7 w7;
        w7.src[0] = w_ps;      w7.hi[0] = wps_hi;  w7.lo[0] = wps_lo;
        w7.src[1] = w_ps_back; w7.hi[1] = wpsb_hi; w7.lo[1] = wpsb_lo;
        w7.src[2] = w_ps_fore; w7.hi[2] = wpsf_hi; w7.lo[2] = wpsf_lo;
        w7.src[3] = w_hs;      w7.hi[3] = whs_hi;  w7.lo[3] = whs_lo;
        w7.src[4] = w_hs_back; w7.hi[4] = whsb_hi; w7.lo[4] = whsb_lo;
        w7.src[5] = w_hs_fore; w7.hi[5] = whsf_hi; w7.lo[5] = whsf_lo;
        w7.src[6] = w_indi;    w7.hi[6] = wind_hi; w7.lo[6] = wind_lo;
        pack_w7<<<56, 256, 0, stream>>>(w7);
    }
    gru_mfma<<<NR / 16, 512, 0, stream>>>(seqt, wih0p, whh0p, wih1p, whh1p,
                                          bih0, bhh0, bih1, bhh1, h1);
    float* x_hidden = h1;

    // ================= Phase B: predefined-concept branch =================
    hipMemsetAsync(den, 0, CDIM * sizeof(float), stream);
    den_atomic<<<dim3(CDIM / 64, 32), 256, 0, stream>>>(cm, mv, den);
    s2ct_trans<<<dim3(NR / 64, CDIM / 64), 256, 0, stream>>>(cm, mv, den, s2cT);
    pboth(stream, x_hidden, pbt_xh_hi, pbt_xh_lo, pkn_xh_hi, pkn_xh_lo, NR);
    hipMemsetAsync(hidden, 0, 65536 * sizeof(float), stream);
    mg(stream, s2cT, pkn_xh_hi, pkn_xh_lo, nullptr, hidden, CDIM, HDIM, NR, 8, 0);
    row_nonzero<<<CDIM, 64, 0, stream>>>(hidden, v1);
    mg(stream, hidden, pbt_xh_hi, pbt_xh_lo, nullptr, L, CDIM, NR, HDIM, 1, 0);
    cos_softmax_row<<<CDIM, 256, 0, stream>>>(L, NR, nullptr, nullptr, nullptr);
    hipMemsetAsync(hidden2, 0, 65536 * sizeof(float), stream);
    mg(stream, L, pkn_xh_hi, pkn_xh_lo, nullptr, hidden2, CDIM, HDIM, NR, 8, 0);
    row_norm<<<NR, 64, 0, stream>>>(x_hidden, xnorm);
    row_norm<<<CDIM, 64, 0, stream>>>(hidden2, h2n);
    pboth(stream, hidden2, pbt_h2_hi, pbt_h2_lo, pkn_h2_hi, pkn_h2_lo, CDIM);
    // packed-A: x_hidden already packed as pbt_xh (A index == B index layout)
    mg(stream, x_hidden, pbt_h2_hi, pbt_h2_lo, nullptr, c2s, NR, CDIM, HDIM, 1, 0,
       nullptr, nullptr, pbt_xh_hi, pbt_xh_lo);
    cos_softmax_row<<<NR, 256, 0, stream>>>(c2s, CDIM, xnorm, h2n, v1);
    hipMemsetAsync(p0, 0, 524288 * sizeof(float), stream);
    mg(stream, c2s, pkn_h2_hi, pkn_h2_lo, nullptr, p0, NR, HDIM, CDIM, 2, 0);
    mg(stream, p0, wps_hi, wps_lo, b_ps, p_shared, NR, HDIM, HDIM, 1, 1);
    // p_back fused with h_shared = x_hidden - p_back
    mg(stream, p_shared, wpsb_hi, wpsb_lo, b_ps_back, p_back, NR, HDIM, HDIM, 1, 1 | 8,
       x_hidden, h_shared);
    mg(stream, p_shared, wpsf_hi, wpsf_lo, b_ps_fore, out_ps, NR, HDIM, HDIM, 1, 1 | 2);

    // ================= Phase C: hidden-concept branch =================
    row_norm<<<NR, 64, 0, stream>>>(h_shared, hn);
    pbt(stream, h_shared, pbt_hsh_hi, pbt_hsh_lo, NR, HDIM);
    // packed-A: the 4096-block NxN GEMM reuses pbt_hsh for BOTH operands
    // (kills the 64x-redundant per-block A fp32->bf16 conversion).
    mg(stream, h_shared, pbt_hsh_hi, pbt_hsh_lo, nullptr, BIG, NR, NR, HDIM, 1, 0,
       nullptr, nullptr, pbt_hsh_hi, pbt_hsh_lo);
    scan_topk<<<NR, 256, 0, stream>>>(BIG, hn, diagv, tvals, tidx);
    hipMemsetAsync(colsum, 0, NR * sizeof(float), stream);
    hipMemsetAsync(hidden_h, 0, 524288 * sizeof(float), stream);
    colsum_scatter<<<(NR * KTOP + 255) / 256, 256, 0, stream>>>(tvals, tidx, colsum);
    hh_scatter<<<NR * KTOP, HDIM, 0, stream>>>(tvals, tidx, h_shared, hidden_h);
    hh_diag<<<2048, 256, 0, stream>>>(colsum, diagv, h_shared, hidden_h);
    row_norm_nz<<<NR, 64, 0, stream>>>(hidden_h, hhn, v2);
    pboth(stream, hidden_h, pbt_hh_hi, pbt_hh_lo, pkn_hh_hi, pkn_hh_lo, NR);
    hc2s_flash<<<NR / 16, 256, 0, stream>>>(h_shared, hn, hhn, v2,
                                            pbt_hh_hi, pbt_hh_lo,
                                            pkn_hh_hi, pkn_hh_lo, hsi0);
    mg(stream, hsi0, whs_hi, whs_lo, b_hs, h_si, NR, HDIM, HDIM, 1, 1);
    // h_back fused with indi = h_shared - h_back = x_hidden - p_back - h_back
    mg(stream, h_si, whsb_hi, whsb_lo, b_hs_back, h_back, NR, HDIM, HDIM, 1, 1 | 8,
       h_shared, indi);
    mg(stream, h_si, whsf_hi, whsf_lo, b_hs_fore, out_hs, NR, HDIM, HDIM, 1, 1 | 2);

    // ================= Phase D: individual branch + head =================
    mg(stream, indi, wind_hi, wind_lo, b_indi, out_indi, NR, HDIM, HDIM, 1, 1 | 2);
    head_kernel<<<NR, 64, 0, stream>>>(out_ps, out_hs, out_indi, w_out, b_out, out);
}

// Round 2
// 771.778 us; speedup vs baseline: 1.2288x; 1.1134x over previous
//
#include <hip/hip_runtime.h>
#include <cstddef>

// Problem dims
#define NR 4096      // batch
#define CDIM 512     // concepts
#define HDIM 128     // hidden
#define TSTEPS 64
#define DDIM 20
#define KTOP 10

typedef __attribute__((ext_vector_type(8))) short short8;
typedef __attribute__((ext_vector_type(4))) float f32x4;

__device__ __forceinline__ unsigned short f2bf(float f) {
    union { float f; unsigned u; } x; x.f = f;
    unsigned r = (x.u + 0x7fffu + ((x.u >> 16) & 1u)) >> 16;
    return (unsigned short)r;
}
// truncating bf16 (for lo planes: residual already ~2^-9, truncation error 2^-17)
__device__ __forceinline__ unsigned short f2bf_t(float f) {
    union { float f; unsigned u; } x; x.f = f;
    return (unsigned short)(x.u >> 16);
}
__device__ __forceinline__ float bf2f(unsigned short h) {
    union { unsigned u; float f; } x; x.u = ((unsigned)h) << 16;
    return x.f;
}
// inf-safe, clamp-free activations (v_exp + v_rcp only)
__device__ __forceinline__ float sigm(float v) {
    return __builtin_amdgcn_rcpf(1.f + __expf(-v));   // v->-inf: rcp(inf)=0; v->+inf: rcp(1)=1
}
__device__ __forceinline__ float tanh_f(float v) {
    return 1.f - 2.f * __builtin_amdgcn_rcpf(1.f + __expf(2.f * v)); // saturates to +-1
}

#define MFMA16(a, b, c) __builtin_amdgcn_mfma_f32_16x16x32_bf16(a, b, c, 0, 0, 0)

// ---------------------------------------------------------------------------
// Generic MFMA GEMM. flags: 1 bias, 2 lrelu, 4 atomicAdd (split-K),
// 8 fused subtract: sub[r,c] = aux[r,c] - C[r,c], 16 pre-packed A (BT layout).
// ---------------------------------------------------------------------------
struct MG {
    const float* A; const unsigned short* Bh; const unsigned short* Bl;
    const float* bias; float* C; const float* aux; float* sub;
    const unsigned short* Ah; const unsigned short* Al;
    int N, K, kchunk, flags;
};

__global__ __launch_bounds__(256) void mfma_gemm(MG g)
{
    const int tid = threadIdx.x;
    const int w = tid >> 6, lane = tid & 63, quad = lane >> 4, lm = lane & 15;
    const int bm = (blockIdx.y << 6) + (w << 4);
    const int bn = blockIdx.x << 6;
    const int NC = g.K >> 5;
    const int c0 = (blockIdx.z * g.kchunk) >> 5;
    const int c1 = c0 + (g.kchunk >> 5);
    const float* arow = g.A + (size_t)(bm + lm) * g.K;
    const int packA = g.flags & 16;
    f32x4 acc[4];
    #pragma unroll
    for (int t = 0; t < 4; t++) acc[t] = (f32x4){0.f, 0.f, 0.f, 0.f};

    for (int c = c0; c < c1; c++) {
        short8 ah, al;
        if (packA) {
            size_t aidx = ((size_t)((bm >> 4) * NC + c) * 64 + lane) * 8;
            ah = *(const short8*)(g.Ah + aidx);
            al = *(const short8*)(g.Al + aidx);
        } else {
            const float* ap = arow + (c << 5) + (quad << 3);
            float4 a0 = *(const float4*)ap;
            float4 a1 = *(const float4*)(ap + 4);
            #pragma unroll
            for (int jj = 0; jj < 4; jj++) {
                float f = (&a0.x)[jj];
                unsigned short h = f2bf(f);
                ah[jj] = h; al[jj] = f2bf_t(f - bf2f(h));
                f = (&a1.x)[jj];
                h = f2bf(f);
                ah[4 + jj] = h; al[4 + jj] = f2bf_t(f - bf2f(h));
            }
        }
        #pragma unroll
        for (int t = 0; t < 4; t++) {
            size_t bidx = ((size_t)(((bn >> 4) + t) * NC + c) * 64 + lane) * 8;
            short8 bh = *(const short8*)(g.Bh + bidx);
            short8 bl = *(const short8*)(g.Bl + bidx);
            acc[t] = MFMA16(ah, bh, acc[t]);
            acc[t] = MFMA16(ah, bl, acc[t]);
            acc[t] = MFMA16(al, bh, acc[t]);
        }
    }
    #pragma unroll
    for (int t = 0; t < 4; t++) {
        #pragma unroll
        for (int rg = 0; rg < 4; rg++) {
            int row = bm + (quad << 2) + rg;
            int col = bn + (t << 4) + lm;
            float v = acc[t][rg];
            if (g.flags & 1) v += g.bias[col];
            if (g.flags & 2) v = v > 0.f ? v : 0.01f * v;
            if (g.flags & 4) atomicAdd(&g.C[(size_t)row * g.N + col], v);
            else g.C[(size_t)row * g.N + col] = v;
            if (g.flags & 8)
                g.sub[(size_t)row * g.N + col] = g.aux[(size_t)row * g.N + col] - v;
        }
    }
}

// B-pack from [N,K] rows; layout [nt][c][lane][8], hi/lo planes.
__global__ void pack_bt(const float* __restrict__ src, unsigned short* __restrict__ hi,
                        unsigned short* __restrict__ lo, int K, int total)
{
    int idx = blockIdx.x * 256 + threadIdx.x;
    if (idx >= total) return;
    int NC = K >> 5;
    int lane = idx & 63;
    int c = (idx >> 6) % NC;
    int t = idx / (NC * 64);
    int n = (t << 4) + (lane & 15);
    int kb = (c << 5) + ((lane >> 4) << 3);
    #pragma unroll
    for (int j = 0; j < 8; j++) {
        float f = src[(size_t)n * K + kb + j];
        unsigned short h = f2bf(f);
        hi[(size_t)idx * 8 + j] = h;
        lo[(size_t)idx * 8 + j] = f2bf_t(f - bf2f(h));
    }
}

// Combined pack (K = HDIM = 128 only): BT (B[n][k]) + KN (B[k][n]) in one pass.
__global__ void pack_both(const float* __restrict__ src,
                          unsigned short* __restrict__ bth, unsigned short* __restrict__ btl,
                          unsigned short* __restrict__ knh, unsigned short* __restrict__ knl,
                          int N, int total_kn)
{
    int idx = blockIdx.x * 256 + threadIdx.x;
    int lane = idx & 63;
    int totBT = (N >> 4) * 256;
    if (idx < totBT) {
        int c = (idx >> 6) & 3;
        int t = idx >> 8;
        int n = (t << 4) + (lane & 15);
        int kb = (c << 5) + ((lane >> 4) << 3);
        #pragma unroll
        for (int j = 0; j < 8; j++) {
            float f = src[(size_t)n * HDIM + kb + j];
            unsigned short h = f2bf(f);
            bth[(size_t)idx * 8 + j] = h;
            btl[(size_t)idx * 8 + j] = f2bf_t(f - bf2f(h));
        }
    }
    if (idx < total_kn) {
        int NC = N >> 5;
        int c = (idx >> 6) % NC;
        int t = idx / (NC * 64);
        int n = (t << 4) + (lane & 15);
        int kb = (c << 5) + ((lane >> 4) << 3);
        #pragma unroll
        for (int j = 0; j < 8; j++) {
            float f = src[(size_t)(kb + j) * HDIM + n];
            unsigned short h = f2bf(f);
            knh[(size_t)idx * 8 + j] = h;
            knl[(size_t)idx * 8 + j] = f2bf_t(f - bf2f(h));
        }
    }
}

// Pack all seven [128,128] weight matrices in one launch.
struct W7 {
    const float* src[7];
    unsigned short* hi[7];
    unsigned short* lo[7];
};
__global__ void pack_w7(W7 p)
{
    int idx = blockIdx.x * 256 + threadIdx.x;   // 7 * 2048
    if (idx >= 7 * 2048) return;
    int m = idx >> 11;
    int r = idx & 2047;
    int lane = r & 63;
    int c = (r >> 6) & 3;
    int t = r >> 8;
    int n = (t << 4) + (lane & 15);
    int kb = (c << 5) + ((lane >> 4) << 3);
    const float* src = p.src[m];
    unsigned short* hi = p.hi[m];
    unsigned short* lo = p.lo[m];
    #pragma unroll
    for (int j = 0; j < 8; j++) {
        float f = src[(size_t)n * HDIM + kb + j];
        unsigned short h = f2bf(f);
        hi[(size_t)r * 8 + j] = h;
        lo[(size_t)r * 8 + j] = f2bf_t(f - bf2f(h));
    }
}

// ---------------------------------------------------------------------------
// scan_topk: wave-shuffle argmax reduce. Tie-break: value desc, index asc.
// ---------------------------------------------------------------------------
__global__ __launch_bounds__(256) void scan_topk(const float* __restrict__ S,
        const float* __restrict__ hn, float* __restrict__ diagv,
        float* __restrict__ tvals, int* __restrict__ tidx)
{
    int row = blockIdx.x;
    const float* d = S + (size_t)row * NR;
    int tid = threadIdx.x;
    int wv = tid >> 6, lane = tid & 63;
    float hi_ = hn[row];
    float lv[16];
    #pragma unroll
    for (int i = 0; i < 16; i++) {
        int j = tid + (i << 8);
        float v = d[j] / fmaxf(hi_ * hn[j], 1e-12f);
        if (j == row) { diagv[row] = v; v = 0.f; }
        lv[i] = v;
    }
    __shared__ float sv[4];
    __shared__ int si[4];
    for (int k = 0; k < KTOP; k++) {
        float bv = -INFINITY; int bi = 0x7fffffff;
        #pragma unroll
        for (int i = 0; i < 16; i++) {
            int j = tid + (i << 8);
            if (lv[i] > bv || (lv[i] == bv && j < bi)) { bv = lv[i]; bi = j; }
        }
        #pragma unroll
        for (int m = 1; m < 64; m <<= 1) {
            float ov = __shfl_xor(bv, m); int oi = __shfl_xor(bi, m);
            if (ov > bv || (ov == bv && oi < bi)) { bv = ov; bi = oi; }
        }
        if (lane == 0) { sv[wv] = bv; si[wv] = bi; }
        __syncthreads();
        bv = sv[0]; bi = si[0];
        #pragma unroll
        for (int w = 1; w < 4; w++) {
            float ov = sv[w]; int oi = si[w];
            if (ov > bv || (ov == bv && oi < bi)) { bv = ov; bi = oi; }
        }
        if (tid == 0) { tvals[row * KTOP + k] = bv; tidx[row * KTOP + k] = bi; }
        if ((bi & 255) == tid) lv[bi >> 8] = -INFINITY;
        __syncthreads();   // protect sv/si reuse next round
    }
}

// ---------------------------------------------------------------------------
// hc2s_flash REWRITE: split-KV flash with wave-private online softmax.
// Grid (NR/64, 4), 512 threads = 8 waves = 4 row-groups x 2 col-chunks.
// Each wave owns 16 query rows x 512 cols (8 tiles of 64) with PRIVATE
// (m, l, O) state -> zero barriers and zero cross-wave traffic in the loop.
// K/V traffic: 256 blocks x 1MB = 256MB (was 2GB with 16-row blocks).
// Partials (m, l, O[16x128]) per wave -> workspace; hc2s_merge combines the
// 8 col-partials per 16-row group exactly in fp32.
// P transpose for PV goes through a wave-private LDS slot; in-wave DS
// ordering + explicit lgkmcnt(0) fence (memory-clobber asm orders the
// subsequent LDS reads; reads are memory ops so they cannot hoist past it).
// ---------------------------------------------------------------------------
__global__ __launch_bounds__(512) void hc2s_flash(
    const float* __restrict__ hsh, const float* __restrict__ hn,
    const float* __restrict__ hhn, const float* __restrict__ v2,
    const unsigned short* __restrict__ Bh, const unsigned short* __restrict__ Bl,
    const unsigned short* __restrict__ Vh, const unsigned short* __restrict__ Vl,
    float* __restrict__ pO, float* __restrict__ pM, float* __restrict__ pL)
{
    __shared__ __attribute__((aligned(16))) unsigned short Ph[8][16 * 72];
    __shared__ __attribute__((aligned(16))) unsigned short Plo[8][16 * 72];

    const int tid = threadIdx.x;
    const int wv = tid >> 6, lane = tid & 63, quad = lane >> 4, lm = lane & 15;
    const int rg2 = wv >> 1;             // row-group within block (0..3)
    const int cc = wv & 1;               // col-chunk within block (0..1)
    const int bm = (blockIdx.x << 6) + (rg2 << 4);   // wave's 16 rows
    const int rgg = (blockIdx.x << 2) + rg2;         // global 16-row group
    const int pidx = (blockIdx.y << 1) + cc;         // partial index (0..7)
    const int jt0 = (blockIdx.y << 4) + (cc << 3);   // first 64-col tile

    // Q fragments for this wave's 16 rows (hi/lo bf16)
    short8 ahh[4], ahl[4];
    #pragma unroll
    for (int c = 0; c < 4; c++) {
        const float* ap = hsh + (size_t)(bm + lm) * HDIM + (c << 5) + (quad << 3);
        float4 a0 = *(const float4*)ap;
        float4 a1 = *(const float4*)(ap + 4);
        #pragma unroll
        for (int j = 0; j < 4; j++) {
            float f = (&a0.x)[j];
            unsigned short h = f2bf(f);
            ahh[c][j] = h; ahl[c][j] = f2bf_t(f - bf2f(h));
            f = (&a1.x)[j];
            h = f2bf(f);
            ahh[c][4 + j] = h; ahl[c][4 + j] = f2bf_t(f - bf2f(h));
        }
    }
    float hnr[4];
    #pragma unroll
    for (int rg = 0; rg < 4; rg++) hnr[rg] = hn[bm + (quad << 2) + rg];

    float m_old[4], l_old[4];
    #pragma unroll
    for (int rg = 0; rg < 4; rg++) { m_old[rg] = -INFINITY; l_old[rg] = 0.f; }
    f32x4 o[8];
    #pragma unroll
    for (int vt = 0; vt < 8; vt++) o[vt] = (f32x4){0.f, 0.f, 0.f, 0.f};

    const int pwr = lm * 72;                  // read base (row lm) in wave slot
    for (int it = 0; it < 8; it++) {
        const int jt = jt0 + it;
        // ---- QK^T: full 64-col tile (4 col-groups), wave-private ----
        f32x4 s[4];
        #pragma unroll
        for (int tg = 0; tg < 4; tg++) {
            s[tg] = (f32x4){0.f, 0.f, 0.f, 0.f};
            #pragma unroll
            for (int c = 0; c < 4; c++) {
                size_t bidx = ((size_t)(((jt << 2) + tg) * 4 + c) * 64 + lane) * 8;
                short8 bh = *(const short8*)(Bh + bidx);
                short8 bl = *(const short8*)(Bl + bidx);
                s[tg] = MFMA16(ahh[c], bh, s[tg]);
                s[tg] = MFMA16(ahh[c], bl, s[tg]);
                s[tg] = MFMA16(ahl[c], bh, s[tg]);
            }
        }
        // ---- normalize + mask ----
        float sv[4][4];
        #pragma unroll
        for (int tg = 0; tg < 4; tg++) {
            int col = (jt << 6) + (tg << 4) + lm;
            float hc = hhn[col];
            float vm = v2[col];
            #pragma unroll
            for (int rg = 0; rg < 4; rg++) {
                float v = s[tg][rg] * __builtin_amdgcn_rcpf(fmaxf(hnr[rg] * hc, 1e-12f));
                sv[tg][rg] = (vm == 0.f) ? -1e9f : v;
            }
        }
        // ---- in-wave online softmax (shfl within 16-lane groups) ----
        float m_new[4], alpha[4], tsum[4], pv[4][4];
        #pragma unroll
        for (int rg = 0; rg < 4; rg++) {
            float m = fmaxf(fmaxf(sv[0][rg], sv[1][rg]), fmaxf(sv[2][rg], sv[3][rg]));
            #pragma unroll
            for (int d = 1; d < 16; d <<= 1) m = fmaxf(m, __shfl_xor(m, d));
            m_new[rg] = fmaxf(m_old[rg], m);
            alpha[rg] = __expf(m_old[rg] - m_new[rg]);
        }
        #pragma unroll
        for (int rg = 0; rg < 4; rg++) {
            float p0_ = __expf(sv[0][rg] - m_new[rg]);
            float p1_ = __expf(sv[1][rg] - m_new[rg]);
            float p2_ = __expf(sv[2][rg] - m_new[rg]);
            float p3_ = __expf(sv[3][rg] - m_new[rg]);
            pv[0][rg] = p0_; pv[1][rg] = p1_; pv[2][rg] = p2_; pv[3][rg] = p3_;
            float ss = p0_ + p1_ + p2_ + p3_;
            #pragma unroll
            for (int d = 1; d < 16; d <<= 1) ss += __shfl_xor(ss, d);
            tsum[rg] = ss;
        }
        #pragma unroll
        for (int rg = 0; rg < 4; rg++) {
            l_old[rg] = l_old[rg] * alpha[rg] + tsum[rg];
            m_old[rg] = m_new[rg];
        }
        #pragma unroll
        for (int vt = 0; vt < 8; vt++) {
            #pragma unroll
            for (int rg = 0; rg < 4; rg++) o[vt][rg] *= alpha[rg];
        }
        // ---- stage P (hi/lo) into wave-private LDS slot ----
        #pragma unroll
        for (int tg = 0; tg < 4; tg++) {
            #pragma unroll
            for (int rg = 0; rg < 4; rg++) {
                int off = ((quad << 2) + rg) * 72 + (tg << 4) + lm;
                float p = pv[tg][rg];
                unsigned short h = f2bf(p);
                Ph[wv][off] = h;
                Plo[wv][off] = f2bf_t(p - bf2f(h));
            }
        }
        __asm__ volatile("s_waitcnt lgkmcnt(0)" ::: "memory");
        // ---- PV: P(16x64) @ V(64x128) ----
        #pragma unroll
        for (int c2 = 0; c2 < 2; c2++) {
            int poff = pwr + (c2 << 5) + (quad << 3);
            short8 pah = *(const short8*)&Ph[wv][poff];
            short8 pal = *(const short8*)&Plo[wv][poff];
            int cg = (jt << 1) + c2;
            #pragma unroll
            for (int vt = 0; vt < 8; vt++) {
                size_t b0 = ((size_t)(vt * 128 + cg) * 64 + lane) * 8;
                short8 vh = *(const short8*)(Vh + b0);
                short8 vl = *(const short8*)(Vl + b0);
                o[vt] = MFMA16(pah, vh, o[vt]);
                o[vt] = MFMA16(pah, vl, o[vt]);
                o[vt] = MFMA16(pal, vh, o[vt]);
            }
        }
    }
    // ---- write partials ----
    size_t pb = ((size_t)rgg * 8 + pidx) * 16;
    #pragma unroll
    for (int rg = 0; rg < 4; rg++) {
        int r = (quad << 2) + rg;
        #pragma unroll
        for (int vt = 0; vt < 8; vt++)
            pO[(pb + r) * 128 + (vt << 4) + lm] = o[vt][rg];
    }
    if (lm == 0) {
        #pragma unroll
        for (int rg = 0; rg < 4; rg++) {
            int r = (quad << 2) + rg;
            pM[pb + r] = m_old[rg];
            pL[pb + r] = l_old[rg];
        }
    }
}

// Merge the 8 col-chunk partials per 16-row group (exact fp32 softmax merge).
__global__ __launch_bounds__(256) void hc2s_merge(const float* __restrict__ pO,
        const float* __restrict__ pM, const float* __restrict__ pL,
        float* __restrict__ O)
{
    int rgg = blockIdx.x;
    int tid = threadIdx.x;
    int r = tid >> 4;
    int c0 = (tid & 15) << 3;
    float m[8], e[8];
    float M = -INFINITY;
    #pragma unroll
    for (int i = 0; i < 8; i++) {
        m[i] = pM[((size_t)rgg * 8 + i) * 16 + r];
        M = fmaxf(M, m[i]);
    }
    float L = 0.f;
    #pragma unroll
    for (int i = 0; i < 8; i++) {
        e[i] = __expf(m[i] - M);
        L += pL[((size_t)rgg * 8 + i) * 16 + r] * e[i];
    }
    float invL = __builtin_amdgcn_rcpf(L);
    float a[8];
    #pragma unroll
    for (int k = 0; k < 8; k++) a[k] = 0.f;
    #pragma unroll
    for (int i = 0; i < 8; i++) {
        const float* src = pO + (((size_t)rgg * 8 + i) * 16 + r) * 128 + c0;
        float4 v0 = *(const float4*)src;
        float4 v1 = *(const float4*)(src + 4);
        a[0] += v0.x * e[i]; a[1] += v0.y * e[i]; a[2] += v0.z * e[i]; a[3] += v0.w * e[i];
        a[4] += v1.x * e[i]; a[5] += v1.y * e[i]; a[6] += v1.z * e[i]; a[7] += v1.w * e[i];
    }
    float* dst = O + ((size_t)rgg * 16 + r) * 128 + c0;
    #pragma unroll
    for (int k = 0; k < 8; k++) dst[k] = a[k] * invL;
}

// ---------------------------------------------------------------------------
// GRU weight pack
// ---------------------------------------------------------------------------
__global__ void pack_wb(const float* __restrict__ W, unsigned short* __restrict__ Wp,
                        int K, int nch)
{
    int idx = blockIdx.x * 256 + threadIdx.x;
    if (idx >= 24 * nch * 64) return;
    int lane = idx & 63;
    int c = (idx >> 6) % nch;
    int t = idx / (nch * 64);
    int n = t * 16 + (lane & 15);
    int kb = c * 32 + (lane >> 4) * 8;
    #pragma unroll
    for (int j = 0; j < 8; j++) {
        int k = kb + j;
        float f = (k < K) ? W[(size_t)n * K + k] : 0.f;
        Wp[(size_t)idx * 8 + j] = f2bf(f);
    }
}

// x [N, D*T] -> seq [T, N, D], pre-split into bf16 hi|lo packed in one u32
__global__ void seq_transpose(const float* __restrict__ x, unsigned* __restrict__ seq)
{
    int idx = blockIdx.x * 256 + threadIdx.x;
    int d = idx % DDIM;
    int r = idx / DDIM;
    int n = r & (NR - 1);
    int t = r >> 12;
    float v = x[(size_t)n * (DDIM * TSTEPS) + d * TSTEPS + t];
    unsigned short h = f2bf(v);
    unsigned short l = f2bf_t(v - bf2f(h));
    seq[idx] = (unsigned)h | ((unsigned)l << 16);
}

// ---------------------------------------------------------------------------
// MFMA 2-layer GRU, 8 waves, register weights, time-double-buffered h state,
// t-loop unrolled by 2 (compile-time buffer indices), clamp-free activations,
// pre-packed x with issue-early/write-late staging.
// ---------------------------------------------------------------------------
__global__ __launch_bounds__(512) void gru_mfma(
    const unsigned* __restrict__ seq,
    const unsigned short* __restrict__ wih0p,
    const unsigned short* __restrict__ whh0p,
    const unsigned short* __restrict__ wih1p,
    const unsigned short* __restrict__ whh1p,
    const float* __restrict__ bih0, const float* __restrict__ bhh0,
    const float* __restrict__ bih1, const float* __restrict__ bhh1,
    float* __restrict__ xh)
{
    __shared__ __attribute__((aligned(16))) unsigned short hA[2][2][2][16 * 136]; // 34.8 KB
    __shared__ __attribute__((aligned(16))) unsigned short xA[2][2][16 * 40];     // 5.1 KB

    const int tid = threadIdx.x;
    const int w2 = tid >> 6;
    const int lane = tid & 63;
    const int quad = lane >> 4;
    const int lm = lane & 15;
    const int n0 = blockIdx.x << 4;
    const int j = (w2 << 4) + lm;

    for (int i = tid; i < 2 * 2 * 2 * 16 * 136; i += 512) ((unsigned short*)hA)[i] = 0;
    for (int i = tid; i < 2 * 2 * 16 * 40; i += 512) ((unsigned short*)xA)[i] = 0;

    float br0 = bih0[j] + bhh0[j];
    float bz0 = bih0[128 + j] + bhh0[128 + j];
    float bni0 = bih0[256 + j];
    float bnh0 = bhh0[256 + j];
    float br1 = bih1[j] + bhh1[j];
    float bz1 = bih1[128 + j] + bhh1[128 + j];
    float bni1 = bih1[256 + j];
    float bnh1 = bhh1[256 + j];

    // register-resident weight fragments (t-invariant)
    short8 W0x[3], W0h[3][4], W1x[3][4], W1h[3][4];
    {
        const int lb = lane * 8;
        W0x[0] = *(const short8*)&wih0p[(size_t)(w2) * 512 + lb];
        W0x[1] = *(const short8*)&wih0p[(size_t)(8 + w2) * 512 + lb];
        W0x[2] = *(const short8*)&wih0p[(size_t)(16 + w2) * 512 + lb];
        #pragma unroll
        for (int c = 0; c < 4; c++) {
            W0h[0][c] = *(const short8*)&whh0p[(size_t)((w2) * 4 + c) * 512 + lb];
            W0h[1][c] = *(const short8*)&whh0p[(size_t)((8 + w2) * 4 + c) * 512 + lb];
            W0h[2][c] = *(const short8*)&whh0p[(size_t)((16 + w2) * 4 + c) * 512 + lb];
            W1x[0][c] = *(const short8*)&wih1p[(size_t)((w2) * 4 + c) * 512 + lb];
            W1x[1][c] = *(const short8*)&wih1p[(size_t)((8 + w2) * 4 + c) * 512 + lb];
            W1x[2][c] = *(const short8*)&wih1p[(size_t)((16 + w2) * 4 + c) * 512 + lb];
            W1h[0][c] = *(const short8*)&whh1p[(size_t)((w2) * 4 + c) * 512 + lb];
            W1h[1][c] = *(const short8*)&whh1p[(size_t)((8 + w2) * 4 + c) * 512 + lb];
            W1h[2][c] = *(const short8*)&whh1p[(size_t)((16 + w2) * 4 + c) * 512 + lb];
        }
    }

    const int aoff = lm * 136 + quad * 8;
    const int xoff = lm * 40 + quad * 8;
    const bool stager = tid < 16 * DDIM;
    const int soff = stager ? (tid / DDIM) * 40 + (tid % DDIM) : 0;  // hoisted div/mod

    const unsigned* sp = seq + (size_t)n0 * DDIM;
    if (stager) {
        unsigned v = sp[tid];
        xA[0][0][soff] = (unsigned short)(v & 0xffffu);
        xA[0][1][soff] = (unsigned short)(v >> 16);
    }
    sp += (size_t)NR * DDIM;
    __syncthreads();

#define GRU_STEP(B, RB, LAST)                                                     \
{                                                                                 \
    unsigned xv = 0;                                                              \
    if (!(LAST) && stager) xv = sp[tid];   /* issue early, write late */          \
    f32x4 accr = (f32x4){0.f, 0.f, 0.f, 0.f};                                     \
    f32x4 accz = (f32x4){0.f, 0.f, 0.f, 0.f};                                     \
    f32x4 accni = (f32x4){0.f, 0.f, 0.f, 0.f};                                    \
    f32x4 accnh = (f32x4){0.f, 0.f, 0.f, 0.f};                                    \
    /* ---- phase 1: L0 (reads hA[RB][0], xA[B]) ---- */                          \
    {                                                                             \
        short8 axh = *(const short8*)&xA[B][0][xoff];                             \
        short8 axl = *(const short8*)&xA[B][1][xoff];                             \
        accr = MFMA16(axh, W0x[0], accr);                                         \
        accr = MFMA16(axl, W0x[0], accr);                                         \
        accz = MFMA16(axh, W0x[1], accz);                                         \
        accz = MFMA16(axl, W0x[1], accz);                                         \
        accni = MFMA16(axh, W0x[2], accni);                                       \
        accni = MFMA16(axl, W0x[2], accni);                                       \
    }                                                                             \
    _Pragma("unroll")                                                             \
    for (int c = 0; c < 4; c++) {                                                 \
        short8 ahh = *(const short8*)&hA[RB][0][0][aoff + c * 32];                \
        short8 ahl = *(const short8*)&hA[RB][0][1][aoff + c * 32];                \
        accr = MFMA16(ahh, W0h[0][c], accr);                                      \
        accr = MFMA16(ahl, W0h[0][c], accr);                                      \
        accz = MFMA16(ahh, W0h[1][c], accz);                                      \
        accz = MFMA16(ahl, W0h[1][c], accz);                                      \
        accnh = MFMA16(ahh, W0h[2][c], accnh);                                    \
        accnh = MFMA16(ahl, W0h[2][c], accnh);                                    \
    }                                                                             \
    float hold[4];                                                                \
    _Pragma("unroll")                                                             \
    for (int rg = 0; rg < 4; rg++) {                                              \
        int off = (quad * 4 + rg) * 136 + j;                                      \
        hold[rg] = bf2f(hA[RB][0][0][off]) + bf2f(hA[RB][0][1][off]);             \
    }                                                                             \
    /* ---- phase 2: write h0-new -> hA[B][0]; stage x(t+1) -> xA[RB] ---- */     \
    _Pragma("unroll")                                                             \
    for (int rg = 0; rg < 4; rg++) {                                              \
        float r = sigm(accr[rg] + br0);                                           \
        float z = sigm(accz[rg] + bz0);                                           \
        float nc = tanh_f(accni[rg] + bni0 + r * (accnh[rg] + bnh0));             \
        float hnew = nc + z * (hold[rg] - nc);                                    \
        int off = (quad * 4 + rg) * 136 + j;                                      \
        unsigned short hh_ = f2bf(hnew);                                          \
        hA[B][0][0][off] = hh_;                                                   \
        hA[B][0][1][off] = f2bf_t(hnew - bf2f(hh_));                              \
    }                                                                             \
    if (!(LAST) && stager) {                                                      \
        xA[RB][0][soff] = (unsigned short)(xv & 0xffffu);                         \
        xA[RB][1][soff] = (unsigned short)(xv >> 16);                             \
    }                                                                             \
    __syncthreads();     /* the ONE barrier: h0-new + x(t+1) visible */           \
    /* ---- phase 3: L1 (reads hA[B][0] new, hA[RB][1] old) ---- */               \
    accr = (f32x4){0.f, 0.f, 0.f, 0.f};                                           \
    accz = (f32x4){0.f, 0.f, 0.f, 0.f};                                           \
    accni = (f32x4){0.f, 0.f, 0.f, 0.f};                                          \
    accnh = (f32x4){0.f, 0.f, 0.f, 0.f};                                          \
    _Pragma("unroll")                                                             \
    for (int c = 0; c < 4; c++) {                                                 \
        short8 a0h = *(const short8*)&hA[B][0][0][aoff + c * 32];                 \
        short8 a0l = *(const short8*)&hA[B][0][1][aoff + c * 32];                 \
        short8 a1h = *(const short8*)&hA[RB][1][0][aoff + c * 32];                \
        short8 a1l = *(const short8*)&hA[RB][1][1][aoff + c * 32];                \
        accr = MFMA16(a0h, W1x[0][c], accr);                                      \
        accr = MFMA16(a0l, W1x[0][c], accr);                                      \
        accr = MFMA16(a1h, W1h[0][c], accr);                                      \
        accr = MFMA16(a1l, W1h[0][c], accr);                                      \
        accz = MFMA16(a0h, W1x[1][c], accz);                                      \
        accz = MFMA16(a0l, W1x[1][c], accz);                                      \
        accz = MFMA16(a1h, W1h[1][c], accz);                                      \
        accz = MFMA16(a1l, W1h[1][c], accz);                                      \
        accni = MFMA16(a0h, W1x[2][c], accni);                                    \
        accni = MFMA16(a0l, W1x[2][c], accni);                                    \
        accnh = MFMA16(a1h, W1h[2][c], accnh);                                    \
        accnh = MFMA16(a1l, W1h[2][c], accnh);                                    \
    }                                                                             \
    _Pragma("unroll")                                                             \
    for (int rg = 0; rg < 4; rg++) {                                              \
        int off = (quad * 4 + rg) * 136 + j;                                      \
        hold[rg] = bf2f(hA[RB][1][0][off]) + bf2f(hA[RB][1][1][off]);             \
    }                                                                             \
    /* ---- phase 4: write h1-new -> hA[B][1] (next step's barrier orders) */     \
    _Pragma("unroll")                                                             \
    for (int rg = 0; rg < 4; rg++) {                                              \
        float r = sigm(accr[rg] + br1);                                           \
        float z = sigm(accz[rg] + bz1);                                           \
        float nc = tanh_f(accni[rg] + bni1 + r * (accnh[rg] + bnh1));             \
        float hnew = nc + z * (hold[rg] - nc);                                    \
        int off = (quad * 4 + rg) * 136 + j;                                      \
        unsigned short hh_ = f2bf(hnew);                                          \
        hA[B][1][0][off] = hh_;                                                   \
        hA[B][1][1][off] = f2bf_t(hnew - bf2f(hh_));                              \
        if (LAST)                                                                 \
            xh[(size_t)(n0 + quad * 4 + rg) * HDIM + j] = hnew;                   \
    }                                                                             \
    sp += (size_t)NR * DDIM;                                                      \
}

    for (int t = 0; t < TSTEPS - 2; t += 2) {
        GRU_STEP(0, 1, false)
        GRU_STEP(1, 0, false)
    }
    GRU_STEP(0, 1, false)
    GRU_STEP(1, 0, true)
#undef GRU_STEP
}

// ---------------------------------------------------------------------------
// den / s2ct (unchanged)
// ---------------------------------------------------------------------------
__global__ __launch_bounds__(256) void den_atomic(const float* __restrict__ cm,
        const float* __restrict__ mv, float* __restrict__ den)
{
    int c = blockIdx.x * 64 + (threadIdx.x & 63);
    int rg = threadIdx.x >> 6;
    int nbase = blockIdx.y * 128;
    float acc = 0.f;
    for (int i = 0; i < 32; i++) {
        int n = nbase + rg + (i << 2);
        acc += cm[(size_t)n * CDIM + c] * mv[n];
    }
    __shared__ float red[4][64];
    red[rg][threadIdx.x & 63] = acc;
    __syncthreads();
    if (rg == 0)
        atomicAdd(&den[c], red[0][threadIdx.x] + red[1][threadIdx.x] +
                           red[2][threadIdx.x] + red[3][threadIdx.x]);
}

__global__ __launch_bounds__(256) void s2ct_trans(const float* __restrict__ cm,
        const float* __restrict__ mv, const float* __restrict__ den,
        float* __restrict__ s2cT)
{
    __shared__ float tile[64][65];
    __shared__ float mvs[64];
    const int tid = threadIdx.x;
    const int n0 = blockIdx.x << 6;
    const int c0 = blockIdx.y << 6;
    const int lc = tid & 63, lr = tid >> 6;
    if (tid < 64) mvs[tid] = mv[n0 + tid];
    #pragma unroll
    for (int i = 0; i < 16; i++) {
        int n = lr + (i << 2);
        tile[n][lc] = cm[(size_t)(n0 + n) * CDIM + c0 + lc];
    }
    __syncthreads();
    #pragma unroll
    for (int i = 0; i < 16; i++) {
        int c = lr + (i << 2);
        float m = tile[lc][c];
        float d = den[c0 + c];
        s2cT[(size_t)(c0 + c) * NR + n0 + lc] = (m * mvs[lc]) / (d * m + 1.f);
    }
}

// ---------------------------------------------------------------------------
// Small helpers
// ---------------------------------------------------------------------------
__global__ void row_norm(const float* __restrict__ a, float* __restrict__ out)
{
    int r = blockIdx.x;
    float acc = 0.f;
    for (int h = threadIdx.x; h < HDIM; h += 64) {
        float v = a[(size_t)r * HDIM + h];
        acc += v * v;
    }
    for (int o = 32; o > 0; o >>= 1) acc += __shfl_down(acc, o);
    if (threadIdx.x == 0) out[r] = sqrtf(acc);
}

__global__ void row_nonzero(const float* __restrict__ a, float* __restrict__ out)
{
    int r = blockIdx.x;
    float acc = 0.f;
    for (int h = threadIdx.x; h < HDIM; h += 64) acc += a[(size_t)r * HDIM + h];
    for (int o = 32; o > 0; o >>= 1) acc += __shfl_down(acc, o);
    if (threadIdx.x == 0) out[r] = (acc != 0.f) ? 1.f : 0.f;
}

__global__ void row_norm_nz(const float* __restrict__ a, float* __restrict__ nrm,
                            float* __restrict__ nz)
{
    int r = blockIdx.x;
    float acc = 0.f, s = 0.f;
    for (int h = threadIdx.x; h < HDIM; h += 64) {
        float v = a[(size_t)r * HDIM + h];
        acc += v * v;
        s += v;
    }
    for (int o = 32; o > 0; o >>= 1) { acc += __shfl_down(acc, o); s += __shfl_down(s, o); }
    if (threadIdx.x == 0) { nrm[r] = sqrtf(acc); nz[r] = (s != 0.f) ? 1.f : 0.f; }
}

// cos_softmax_row: wave-shuffle reductions, __expf + rcp.
__global__ __launch_bounds__(256) void cos_softmax_row(float* __restrict__ data, int N,
        const float* __restrict__ rn, const float* __restrict__ cn,
        const float* __restrict__ vmask)
{
    int row = blockIdx.x;
    float* d = data + (size_t)row * N;
    int tid = threadIdx.x;
    int wv = tid >> 6, lane = tid & 63;
    __shared__ float red[8];
    float rnv = rn ? rn[row] : 0.f;
    float mx = -INFINITY;
    for (int j = tid; j < N; j += 256) {
        float v = d[j];
        if (cn) v = v * __builtin_amdgcn_rcpf(fmaxf(rnv * cn[j], 1e-12f));
        if (vmask && vmask[j] == 0.f) v = -1e9f;
        d[j] = v;
        mx = fmaxf(mx, v);
    }
    #pragma unroll
    for (int m = 1; m < 64; m <<= 1) mx = fmaxf(mx, __shfl_xor(mx, m));
    if (lane == 0) red[wv] = mx;
    __syncthreads();
    float M = fmaxf(fmaxf(red[0], red[1]), fmaxf(red[2], red[3]));
    float sum = 0.f;
    for (int j = tid; j < N; j += 256) {
        float e = __expf(d[j] - M);
        d[j] = e;
        sum += e;
    }
    #pragma unroll
    for (int m = 1; m < 64; m <<= 1) sum += __shfl_xor(sum, m);
    if (lane == 0) red[4 + wv] = sum;
    __syncthreads();
    float inv = __builtin_amdgcn_rcpf(red[4] + red[5] + red[6] + red[7]);
    for (int j = tid; j < N; j += 256) {
        float v = d[j] * inv;
        if (vmask) v *= vmask[j];
        d[j] = v;
    }
}

__global__ void colsum_scatter(const float* __restrict__ vals, const int* __restrict__ idxs,
                               float* __restrict__ colsum)
{
    int idx = blockIdx.x * 256 + threadIdx.x;
    if (idx < NR * KTOP) atomicAdd(&colsum[idxs[idx]], vals[idx]);
}

__global__ void hh_scatter(const float* __restrict__ vals, const int* __restrict__ idxs,
                           const float* __restrict__ hsh, float* __restrict__ hh)
{
    int p = blockIdx.x;
    int j = idxs[p];
    float v = vals[p];
    int i = p / KTOP;
    atomicAdd(&hh[(size_t)j * HDIM + threadIdx.x], v * hsh[(size_t)i * HDIM + threadIdx.x]);
}

__global__ void hh_diag(const float* __restrict__ colsum, const float* __restrict__ diag,
                        const float* __restrict__ hsh, float* __restrict__ hh)
{
    int idx = blockIdx.x * 256 + threadIdx.x;
    int j = idx >> 7;
    if (colsum[j] != 0.f) hh[idx] += diag[j] * hsh[idx];
}

__global__ void head_kernel(const float* __restrict__ ps, const float* __restrict__ hs,
                            const float* __restrict__ indi, const float* __restrict__ w,
                            const float* __restrict__ b, float* __restrict__ out)
{
    int n = blockIdx.x;
    int t = threadIdx.x;
    float acc = 0.f;
    for (int h = t; h < HDIM; h += 64) {
        size_t k = (size_t)n * HDIM + h;
        acc += (ps[k] + hs[k] + indi[k]) * w[h];
    }
    for (int o = 32; o > 0; o >>= 1) acc += __shfl_down(acc, o);
    if (t == 0) out[n] = acc + b[0];
}

// ---------------------------------------------------------------------------
// host-side helpers
// ---------------------------------------------------------------------------
static inline void mg(hipStream_t s, const float* A, const unsigned short* Bh,
                      const unsigned short* Bl, const float* bias, float* C,
                      int M, int N, int K, int z, int flags,
                      const float* aux = nullptr, float* sub = nullptr,
                      const unsigned short* Ah = nullptr, const unsigned short* Al = nullptr)
{
    MG g{A, Bh, Bl, bias, C, aux, sub, Ah, Al, N, K, K / z,
         flags | (z > 1 ? 4 : 0) | (Ah ? 16 : 0)};
    mfma_gemm<<<dim3(N / 64, M / 64, z), 256, 0, s>>>(g);
}
static inline void pbt(hipStream_t s, const float* src, unsigned short* hi,
                       unsigned short* lo, int N, int K)
{
    int total = (N / 16) * (K / 32) * 64;
    pack_bt<<<(total + 255) / 256, 256, 0, s>>>(src, hi, lo, K, total);
}
static inline void pboth(hipStream_t s, const float* src,
                         unsigned short* bth, unsigned short* btl,
                         unsigned short* knh, unsigned short* knl, int N)
{
    int totBT = (N / 16) * 4 * 64;
    int totKN = 8 * (N / 32) * 64;
    int tot = totBT > totKN ? totBT : totKN;
    pack_both<<<(tot + 255) / 256, 256, 0, s>>>(src, bth, btl, knh, knl, N, totKN);
}

extern "C" void kernel_launch(void* const* d_in, const int* in_sizes, int n_in,
                              void* d_out, int out_size, void* d_ws, size_t ws_size,
                              hipStream_t stream)
{
    (void)in_sizes; (void)n_in; (void)out_size; (void)ws_size;
    const float* x    = (const float*)d_in[0];
    const float* cm   = (const float*)d_in[1];
    const float* mv   = (const float*)d_in[2];
    const float* wih0 = (const float*)d_in[3];
    const float* whh0 = (const float*)d_in[4];
    const float* bih0 = (const float*)d_in[5];
    const float* bhh0 = (const float*)d_in[6];
    const float* wih1 = (const float*)d_in[7];
    const float* whh1 = (const float*)d_in[8];
    const float* bih1 = (const float*)d_in[9];
    const float* bhh1 = (const float*)d_in[10];
    const float* w_ps = (const float*)d_in[11];
    const float* b_ps = (const float*)d_in[12];
    const float* w_hs = (const float*)d_in[13];
    const float* b_hs = (const float*)d_in[14];
    const float* w_ps_fore = (const float*)d_in[15];
    const float* b_ps_fore = (const float*)d_in[16];
    const float* w_hs_fore = (const float*)d_in[17];
    const float* b_hs_fore = (const float*)d_in[18];
    const float* w_ps_back = (const float*)d_in[19];
    const float* b_ps_back = (const float*)d_in[20];
    const float* w_hs_back = (const float*)d_in[21];
    const float* b_hs_back = (const float*)d_in[22];
    const float* w_indi = (const float*)d_in[23];
    const float* b_indi = (const float*)d_in[24];
    const float* w_out  = (const float*)d_in[25];
    const float* b_out  = (const float*)d_in[26];
    float* out = (float*)d_out;

    // ---- workspace layout (floats) ----
    float* ws = (float*)d_ws;
    float* BIG = ws;                         // 16,777,216 (overlaid)
    float* h0 = ws + 16777216;               // 524288 (unused)
    float* h1 = h0 + 524288;                 // x_hidden
    float* den = h1 + 524288;                // 512
    float* v1 = den + 512;                   // 512
    float* hidden = v1 + 512;                // 65536
    float* hidden2 = hidden + 65536;         // 65536
    float* xnorm = hidden2 + 65536;          // 4096
    float* h2n = xnorm + 4096;               // 512
    float* p0 = h2n + 512;                   // 524288
    float* p_shared = p0 + 524288;
    float* p_back = p_shared + 524288;
    float* out_ps = p_back + 524288;
    float* h_shared = out_ps + 524288;
    float* hn = h_shared + 524288;           // 4096
    float* diagv = hn + 4096;                // 4096
    float* colsum = diagv + 4096;            // 4096
    float* tvals = colsum + 4096;            // 40960
    int*   tidx = (int*)(tvals + 40960);     // 40960 ints
    float* hidden_h = (float*)(tidx + 40960);
    float* v2 = hidden_h + 524288;           // 4096
    float* hhn = v2 + 4096;                  // 4096
    float* hsi0 = hhn + 4096;                // 524288
    float* h_si = hsi0 + 524288;
    float* h_back = h_si + 524288;
    float* out_hs = h_back + 524288;
    float* indi = out_hs + 524288;
    float* out_indi = indi + 524288;
    float* extra = out_indi + 524288;

    // GRU-phase overlays inside BIG:
    unsigned* seqt = (unsigned*)BIG;
    unsigned short* wih0p = (unsigned short*)(BIG + 5242880);
    unsigned short* whh0p = wih0p + 12288;
    unsigned short* wih1p = whh0p + 49152;
    unsigned short* whh1p = wih1p + 49152;
    // concept-phase overlays inside BIG:
    float* s2cT = BIG;
    float* L    = BIG + 2097152;
    float* c2s  = BIG + 4194304;
    unsigned short* PB = (unsigned short*)(BIG + 6291456);
    unsigned short* pbt_xh_hi = PB;
    unsigned short* pbt_xh_lo = pbt_xh_hi + 524288;
    unsigned short* pkn_xh_hi = pbt_xh_lo + 524288;
    unsigned short* pkn_xh_lo = pkn_xh_hi + 524288;
    unsigned short* pbt_h2_hi = pkn_xh_lo + 524288;
    unsigned short* pbt_h2_lo = pbt_h2_hi + 65536;
    unsigned short* pkn_h2_hi = pbt_h2_lo + 65536;
    unsigned short* pkn_h2_lo = pkn_h2_hi + 65536;
    unsigned short* wps_hi  = pkn_h2_lo + 65536;
    unsigned short* wps_lo  = wps_hi + 16384;
    unsigned short* wpsb_hi = wps_lo + 16384;
    unsigned short* wpsb_lo = wpsb_hi + 16384;
    unsigned short* wpsf_hi = wpsb_lo + 16384;
    unsigned short* wpsf_lo = wpsf_hi + 16384;
    unsigned short* pbt_hsh_hi = (unsigned short*)p0;
    unsigned short* pbt_hsh_lo = pbt_hsh_hi + 524288;
    unsigned short* pbt_hh_hi = (unsigned short*)indi;
    unsigned short* pbt_hh_lo = pbt_hh_hi + 524288;
    unsigned short* pkn_hh_hi = (unsigned short*)out_indi;
    unsigned short* pkn_hh_lo = pkn_hh_hi + 524288;
    // flash-partial overlays inside BIG (dead after scan_topk):
    float* part_O = BIG;                     // 4,194,304 floats
    float* part_m = BIG + 4194304;           // 32,768
    float* part_l = BIG + 4227072;           // 32,768
    unsigned short* EX = (unsigned short*)extra;
    unsigned short* whs_hi  = EX;            unsigned short* whs_lo  = EX + 16384;
    unsigned short* whsb_hi = EX + 32768;    unsigned short* whsb_lo = EX + 49152;
    unsigned short* whsf_hi = EX + 65536;    unsigned short* whsf_lo = EX + 81920;
    unsigned short* wind_hi = EX + 98304;    unsigned short* wind_lo = EX + 114688;

    // ================= Phase A: MFMA 2-layer GRU =================
    seq_transpose<<<(TSTEPS * NR * DDIM) / 256, 256, 0, stream>>>(x, seqt);
    pack_wb<<<6, 256, 0, stream>>>(wih0, wih0p, DDIM, 1);
    pack_wb<<<24, 256, 0, stream>>>(whh0, whh0p, HDIM, 4);
    pack_wb<<<24, 256, 0, stream>>>(wih1, wih1p, HDIM, 4);
    pack_wb<<<24, 256, 0, stream>>>(whh1, whh1p, HDIM, 4);
    {
        W7 w7;
        w7.src[0] = w_ps;      w7.hi[0] = wps_hi;  w7.lo[0] = wps_lo;
        w7.src[1] = w_ps_back; w7.hi[1] = wpsb_hi; w7.lo[1] = wpsb_lo;
        w7.src[2] = w_ps_fore; w7.hi[2] = wpsf_hi; w7.lo[2] = wpsf_lo;
        w7.src[3] = w_hs;      w7.hi[3] = whs_hi;  w7.lo[3] = whs_lo;
        w7.src[4] = w_hs_back; w7.hi[4] = whsb_hi; w7.lo[4] = whsb_lo;
        w7.src[5] = w_hs_fore; w7.hi[5] = whsf_hi; w7.lo[5] = whsf_lo;
        w7.src[6] = w_indi;    w7.hi[6] = wind_hi; w7.lo[6] = wind_lo;
        pack_w7<<<56, 256, 0, stream>>>(w7);
    }
    gru_mfma<<<NR / 16, 512, 0, stream>>>(seqt, wih0p, whh0p, wih1p, whh1p,
                                          bih0, bhh0, bih1, bhh1, h1);
    float* x_hidden = h1;

    // ================= Phase B: predefined-concept branch =================
    hipMemsetAsync(den, 0, CDIM * sizeof(float), stream);
    den_atomic<<<dim3(CDIM / 64, 32), 256, 0, stream>>>(cm, mv, den);
    s2ct_trans<<<dim3(NR / 64, CDIM / 64), 256, 0, stream>>>(cm, mv, den, s2cT);
    pboth(stream, x_hidden, pbt_xh_hi, pbt_xh_lo, pkn_xh_hi, pkn_xh_lo, NR);
    hipMemsetAsync(hidden, 0, 65536 * sizeof(float), stream);
    mg(stream, s2cT, pkn_xh_hi, pkn_xh_lo, nullptr, hidden, CDIM, HDIM, NR, 8, 0);
    row_nonzero<<<CDIM, 64, 0, stream>>>(hidden, v1);
    mg(stream, hidden, pbt_xh_hi, pbt_xh_lo, nullptr, L, CDIM, NR, HDIM, 1, 0);
    cos_softmax_row<<<CDIM, 256, 0, stream>>>(L, NR, nullptr, nullptr, nullptr);
    hipMemsetAsync(hidden2, 0, 65536 * sizeof(float), stream);
    mg(stream, L, pkn_xh_hi, pkn_xh_lo, nullptr, hidden2, CDIM, HDIM, NR, 8, 0);
    row_norm<<<NR, 64, 0, stream>>>(x_hidden, xnorm);
    row_norm<<<CDIM, 64, 0, stream>>>(hidden2, h2n);
    pboth(stream, hidden2, pbt_h2_hi, pbt_h2_lo, pkn_h2_hi, pkn_h2_lo, CDIM);
    // packed-A: x_hidden already packed as pbt_xh
    mg(stream, x_hidden, pbt_h2_hi, pbt_h2_lo, nullptr, c2s, NR, CDIM, HDIM, 1, 0,
       nullptr, nullptr, pbt_xh_hi, pbt_xh_lo);
    cos_softmax_row<<<NR, 256, 0, stream>>>(c2s, CDIM, xnorm, h2n, v1);
    hipMemsetAsync(p0, 0, 524288 * sizeof(float), stream);
    mg(stream, c2s, pkn_h2_hi, pkn_h2_lo, nullptr, p0, NR, HDIM, CDIM, 2, 0);
    mg(stream, p0, wps_hi, wps_lo, b_ps, p_shared, NR, HDIM, HDIM, 1, 1);
    // p_back fused with h_shared = x_hidden - p_back
    mg(stream, p_shared, wpsb_hi, wpsb_lo, b_ps_back, p_back, NR, HDIM, HDIM, 1, 1 | 8,
       x_hidden, h_shared);
    mg(stream, p_shared, wpsf_hi, wpsf_lo, b_ps_fore, out_ps, NR, HDIM, HDIM, 1, 1 | 2);

    // ================= Phase C: hidden-concept branch =================
    row_norm<<<NR, 64, 0, stream>>>(h_shared, hn);
    pbt(stream, h_shared, pbt_hsh_hi, pbt_hsh_lo, NR, HDIM);
    // packed-A: the 4096-block NxN GEMM reuses pbt_hsh for BOTH operands
    mg(stream, h_shared, pbt_hsh_hi, pbt_hsh_lo, nullptr, BIG, NR, NR, HDIM, 1, 0,
       nullptr, nullptr, pbt_hsh_hi, pbt_hsh_lo);
    scan_topk<<<NR, 256, 0, stream>>>(BIG, hn, diagv, tvals, tidx);
    hipMemsetAsync(colsum, 0, NR * sizeof(float), stream);
    hipMemsetAsync(hidden_h, 0, 524288 * sizeof(float), stream);
    colsum_scatter<<<(NR * KTOP + 255) / 256, 256, 0, stream>>>(tvals, tidx, colsum);
    hh_scatter<<<NR * KTOP, HDIM, 0, stream>>>(tvals, tidx, h_shared, hidden_h);
    hh_diag<<<2048, 256, 0, stream>>>(colsum, diagv, h_shared, hidden_h);
    row_norm_nz<<<NR, 64, 0, stream>>>(hidden_h, hhn, v2);
    pboth(stream, hidden_h, pbt_hh_hi, pbt_hh_lo, pkn_hh_hi, pkn_hh_lo, NR);
    hc2s_flash<<<dim3(NR / 64, 4), 512, 0, stream>>>(h_shared, hn, hhn, v2,
                                                     pbt_hh_hi, pbt_hh_lo,
                                                     pkn_hh_hi, pkn_hh_lo,
                                                     part_O, part_m, part_l);
    hc2s_merge<<<NR / 16, 256, 0, stream>>>(part_O, part_m, part_l, hsi0);
    mg(stream, hsi0, whs_hi, whs_lo, b_hs, h_si, NR, HDIM, HDIM, 1, 1);
    // h_back fused with indi = h_shared - h_back = x_hidden - p_back - h_back
    mg(stream, h_si, whsb_hi, whsb_lo, b_hs_back, h_back, NR, HDIM, HDIM, 1, 1 | 8,
       h_shared, indi);
    mg(stream, h_si, whsf_hi, whsf_lo, b_hs_fore, out_hs, NR, HDIM, HDIM, 1, 1 | 2);

    // ================= Phase D: individual branch + head =================
    mg(stream, indi, wind_hi, wind_lo, b_indi, out_indi, NR, HDIM, HDIM, 1, 1 | 2);
    head_kernel<<<NR, 64, 0, stream>>>(out_ps, out_hs, out_indi, w_out, b_out, out);
}

// Round 3
// 749.584 us; speedup vs baseline: 1.2652x; 1.0296x over previous
//
#include <hip/hip_runtime.h>
#include <cstddef>

// Problem dims
#define NR 4096      // batch
#define CDIM 512     // concepts
#define HDIM 128     // hidden
#define TSTEPS 64
#define DDIM 20
#define KTOP 10

typedef __attribute__((ext_vector_type(8))) short short8;
typedef __attribute__((ext_vector_type(4))) float f32x4;

__device__ __forceinline__ unsigned short f2bf(float f) {
    union { float f; unsigned u; } x; x.f = f;
    unsigned r = (x.u + 0x7fffu + ((x.u >> 16) & 1u)) >> 16;
    return (unsigned short)r;
}
// truncating bf16 (lo plane captures the residual; hi+lo exact to ~2^-17)
__device__ __forceinline__ unsigned short f2bf_t(float f) {
    union { float f; unsigned u; } x; x.f = f;
    return (unsigned short)(x.u >> 16);
}
__device__ __forceinline__ float bf2f(unsigned short h) {
    union { unsigned u; float f; } x; x.u = ((unsigned)h) << 16;
    return x.f;
}
// inf-safe, clamp-free activations (v_exp + v_rcp only)
__device__ __forceinline__ float sigm(float v) {
    return __builtin_amdgcn_rcpf(1.f + __expf(-v));
}
__device__ __forceinline__ float tanh_f(float v) {
    return 1.f - 2.f * __builtin_amdgcn_rcpf(1.f + __expf(2.f * v));
}

#define MFMA16(a, b, c) __builtin_amdgcn_mfma_f32_16x16x32_bf16(a, b, c, 0, 0, 0)

// ---------------------------------------------------------------------------
// Generic MFMA GEMM. flags: 1 bias, 2 lrelu, 4 atomicAdd (split-K),
// 8 fused subtract: sub[r,c] = aux[r,c] - C[r,c], 16 pre-packed A (BT layout).
// ---------------------------------------------------------------------------
struct MG {
    const float* A; const unsigned short* Bh; const unsigned short* Bl;
    const float* bias; float* C; const float* aux; float* sub;
    const unsigned short* Ah; const unsigned short* Al;
    int N, K, kchunk, flags;
};

__global__ __launch_bounds__(256) void mfma_gemm(MG g)
{
    const int tid = threadIdx.x;
    const int w = tid >> 6, lane = tid & 63, quad = lane >> 4, lm = lane & 15;
    const int bm = (blockIdx.y << 6) + (w << 4);
    const int bn = blockIdx.x << 6;
    const int NC = g.K >> 5;
    const int c0 = (blockIdx.z * g.kchunk) >> 5;
    const int c1 = c0 + (g.kchunk >> 5);
    const float* arow = g.A + (size_t)(bm + lm) * g.K;
    const int packA = g.flags & 16;
    f32x4 acc[4];
    #pragma unroll
    for (int t = 0; t < 4; t++) acc[t] = (f32x4){0.f, 0.f, 0.f, 0.f};

    for (int c = c0; c < c1; c++) {
        short8 ah, al;
        if (packA) {
            size_t aidx = ((size_t)((bm >> 4) * NC + c) * 64 + lane) * 8;
            ah = *(const short8*)(g.Ah + aidx);
            al = *(const short8*)(g.Al + aidx);
        } else {
            const float* ap = arow + (c << 5) + (quad << 3);
            float4 a0 = *(const float4*)ap;
            float4 a1 = *(const float4*)(ap + 4);
            #pragma unroll
            for (int jj = 0; jj < 4; jj++) {
                float f = (&a0.x)[jj];
                unsigned short h = f2bf(f);
                ah[jj] = h; al[jj] = f2bf_t(f - bf2f(h));
                f = (&a1.x)[jj];
                h = f2bf(f);
                ah[4 + jj] = h; al[4 + jj] = f2bf_t(f - bf2f(h));
            }
        }
        #pragma unroll
        for (int t = 0; t < 4; t++) {
            size_t bidx = ((size_t)(((bn >> 4) + t) * NC + c) * 64 + lane) * 8;
            short8 bh = *(const short8*)(g.Bh + bidx);
            short8 bl = *(const short8*)(g.Bl + bidx);
            acc[t] = MFMA16(ah, bh, acc[t]);
            acc[t] = MFMA16(ah, bl, acc[t]);
            acc[t] = MFMA16(al, bh, acc[t]);
        }
    }
    #pragma unroll
    for (int t = 0; t < 4; t++) {
        #pragma unroll
        for (int rg = 0; rg < 4; rg++) {
            int row = bm + (quad << 2) + rg;
            int col = bn + (t << 4) + lm;
            float v = acc[t][rg];
            if (g.flags & 1) v += g.bias[col];
            if (g.flags & 2) v = v > 0.f ? v : 0.01f * v;
            if (g.flags & 4) atomicAdd(&g.C[(size_t)row * g.N + col], v);
            else g.C[(size_t)row * g.N + col] = v;
            if (g.flags & 8)
                g.sub[(size_t)row * g.N + col] = g.aux[(size_t)row * g.N + col] - v;
        }
    }
}

// B-pack from [N,K] rows; layout [nt][c][lane][8], hi/lo planes.
__global__ void pack_bt(const float* __restrict__ src, unsigned short* __restrict__ hi,
                        unsigned short* __restrict__ lo, int K, int total)
{
    int idx = blockIdx.x * 256 + threadIdx.x;
    if (idx >= total) return;
    int NC = K >> 5;
    int lane = idx & 63;
    int c = (idx >> 6) % NC;
    int t = idx / (NC * 64);
    int n = (t << 4) + (lane & 15);
    int kb = (c << 5) + ((lane >> 4) << 3);
    #pragma unroll
    for (int j = 0; j < 8; j++) {
        float f = src[(size_t)n * K + kb + j];
        unsigned short h = f2bf(f);
        hi[(size_t)idx * 8 + j] = h;
        lo[(size_t)idx * 8 + j] = f2bf_t(f - bf2f(h));
    }
}

// Combined pack (K = HDIM = 128 only): BT (B[n][k]) + KN (B[k][n]) in one pass.
__global__ void pack_both(const float* __restrict__ src,
                          unsigned short* __restrict__ bth, unsigned short* __restrict__ btl,
                          unsigned short* __restrict__ knh, unsigned short* __restrict__ knl,
                          int N, int total_kn)
{
    int idx = blockIdx.x * 256 + threadIdx.x;
    int lane = idx & 63;
    int totBT = (N >> 4) * 256;
    if (idx < totBT) {
        int c = (idx >> 6) & 3;
        int t = idx >> 8;
        int n = (t << 4) + (lane & 15);
        int kb = (c << 5) + ((lane >> 4) << 3);
        #pragma unroll
        for (int j = 0; j < 8; j++) {
            float f = src[(size_t)n * HDIM + kb + j];
            unsigned short h = f2bf(f);
            bth[(size_t)idx * 8 + j] = h;
            btl[(size_t)idx * 8 + j] = f2bf_t(f - bf2f(h));
        }
    }
    if (idx < total_kn) {
        int NC = N >> 5;
        int c = (idx >> 6) % NC;
        int t = idx / (NC * 64);
        int n = (t << 4) + (lane & 15);
        int kb = (c << 5) + ((lane >> 4) << 3);
        #pragma unroll
        for (int j = 0; j < 8; j++) {
            float f = src[(size_t)(kb + j) * HDIM + n];
            unsigned short h = f2bf(f);
            knh[(size_t)idx * 8 + j] = h;
            knl[(size_t)idx * 8 + j] = f2bf_t(f - bf2f(h));
        }
    }
}

// Pack all seven [128,128] weight matrices in one launch.
struct W7 {
    const float* src[7];
    unsigned short* hi[7];
    unsigned short* lo[7];
};
__global__ void pack_w7(W7 p)
{
    int idx = blockIdx.x * 256 + threadIdx.x;   // 7 * 2048
    if (idx >= 7 * 2048) return;
    int m = idx >> 11;
    int r = idx & 2047;
    int lane = r & 63;
    int c = (r >> 6) & 3;
    int t = r >> 8;
    int n = (t << 4) + (lane & 15);
    int kb = (c << 5) + ((lane >> 4) << 3);
    const float* src = p.src[m];
    unsigned short* hi = p.hi[m];
    unsigned short* lo = p.lo[m];
    #pragma unroll
    for (int j = 0; j < 8; j++) {
        float f = src[(size_t)n * HDIM + kb + j];
        unsigned short h = f2bf(f);
        hi[(size_t)r * 8 + j] = h;
        lo[(size_t)r * 8 + j] = f2bf_t(f - bf2f(h));
    }
}

// ---------------------------------------------------------------------------
// scan_topk: wave-shuffle argmax reduce. Tie-break: value desc, index asc.
// ---------------------------------------------------------------------------
__global__ __launch_bounds__(256) void scan_topk(const float* __restrict__ S,
        const float* __restrict__ hn, float* __restrict__ diagv,
        float* __restrict__ tvals, int* __restrict__ tidx)
{
    int row = blockIdx.x;
    const float* d = S + (size_t)row * NR;
    int tid = threadIdx.x;
    int wv = tid >> 6, lane = tid & 63;
    float hi_ = hn[row];
    float lv[16];
    #pragma unroll
    for (int i = 0; i < 16; i++) {
        int j = tid + (i << 8);
        float v = d[j] / fmaxf(hi_ * hn[j], 1e-12f);
        if (j == row) { diagv[row] = v; v = 0.f; }
        lv[i] = v;
    }
    __shared__ float sv[4];
    __shared__ int si[4];
    for (int k = 0; k < KTOP; k++) {
        float bv = -INFINITY; int bi = 0x7fffffff;
        #pragma unroll
        for (int i = 0; i < 16; i++) {
            int j = tid + (i << 8);
            if (lv[i] > bv || (lv[i] == bv && j < bi)) { bv = lv[i]; bi = j; }
        }
        #pragma unroll
        for (int m = 1; m < 64; m <<= 1) {
            float ov = __shfl_xor(bv, m); int oi = __shfl_xor(bi, m);
            if (ov > bv || (ov == bv && oi < bi)) { bv = ov; bi = oi; }
        }
        if (lane == 0) { sv[wv] = bv; si[wv] = bi; }
        __syncthreads();
        bv = sv[0]; bi = si[0];
        #pragma unroll
        for (int w = 1; w < 4; w++) {
            float ov = sv[w]; int oi = si[w];
            if (ov > bv || (ov == bv && oi < bi)) { bv = ov; bi = oi; }
        }
        if (tid == 0) { tvals[row * KTOP + k] = bv; tidx[row * KTOP + k] = bi; }
        if ((bi & 255) == tid) lv[bi >> 8] = -INFINITY;
        __syncthreads();   // protect sv/si reuse next round
    }
}

// ---------------------------------------------------------------------------
// hc2s_flash: split-KV flash with wave-private online softmax (see R1 notes).
// ---------------------------------------------------------------------------
__global__ __launch_bounds__(512) void hc2s_flash(
    const float* __restrict__ hsh, const float* __restrict__ hn,
    const float* __restrict__ hhn, const float* __restrict__ v2,
    const unsigned short* __restrict__ Bh, const unsigned short* __restrict__ Bl,
    const unsigned short* __restrict__ Vh, const unsigned short* __restrict__ Vl,
    float* __restrict__ pO, float* __restrict__ pM, float* __restrict__ pL)
{
    __shared__ __attribute__((aligned(16))) unsigned short Ph[8][16 * 72];
    __shared__ __attribute__((aligned(16))) unsigned short Plo[8][16 * 72];

    const int tid = threadIdx.x;
    const int wv = tid >> 6, lane = tid & 63, quad = lane >> 4, lm = lane & 15;
    const int rg2 = wv >> 1;             // row-group within block (0..3)
    const int cc = wv & 1;               // col-chunk within block (0..1)
    const int bm = (blockIdx.x << 6) + (rg2 << 4);   // wave's 16 rows
    const int rgg = (blockIdx.x << 2) + rg2;         // global 16-row group
    const int pidx = (blockIdx.y << 1) + cc;         // partial index (0..7)
    const int jt0 = (blockIdx.y << 4) + (cc << 3);   // first 64-col tile

    short8 ahh[4], ahl[4];
    #pragma unroll
    for (int c = 0; c < 4; c++) {
        const float* ap = hsh + (size_t)(bm + lm) * HDIM + (c << 5) + (quad << 3);
        float4 a0 = *(const float4*)ap;
        float4 a1 = *(const float4*)(ap + 4);
        #pragma unroll
        for (int j = 0; j < 4; j++) {
            float f = (&a0.x)[j];
            unsigned short h = f2bf(f);
            ahh[c][j] = h; ahl[c][j] = f2bf_t(f - bf2f(h));
            f = (&a1.x)[j];
            h = f2bf(f);
            ahh[c][4 + j] = h; ahl[c][4 + j] = f2bf_t(f - bf2f(h));
        }
    }
    float hnr[4];
    #pragma unroll
    for (int rg = 0; rg < 4; rg++) hnr[rg] = hn[bm + (quad << 2) + rg];

    float m_old[4], l_old[4];
    #pragma unroll
    for (int rg = 0; rg < 4; rg++) { m_old[rg] = -INFINITY; l_old[rg] = 0.f; }
    f32x4 o[8];
    #pragma unroll
    for (int vt = 0; vt < 8; vt++) o[vt] = (f32x4){0.f, 0.f, 0.f, 0.f};

    const int pwr = lm * 72;
    for (int it = 0; it < 8; it++) {
        const int jt = jt0 + it;
        f32x4 s[4];
        #pragma unroll
        for (int tg = 0; tg < 4; tg++) {
            s[tg] = (f32x4){0.f, 0.f, 0.f, 0.f};
            #pragma unroll
            for (int c = 0; c < 4; c++) {
                size_t bidx = ((size_t)(((jt << 2) + tg) * 4 + c) * 64 + lane) * 8;
                short8 bh = *(const short8*)(Bh + bidx);
                short8 bl = *(const short8*)(Bl + bidx);
                s[tg] = MFMA16(ahh[c], bh, s[tg]);
                s[tg] = MFMA16(ahh[c], bl, s[tg]);
                s[tg] = MFMA16(ahl[c], bh, s[tg]);
            }
        }
        float sv[4][4];
        #pragma unroll
        for (int tg = 0; tg < 4; tg++) {
            int col = (jt << 6) + (tg << 4) + lm;
            float hc = hhn[col];
            float vm = v2[col];
            #pragma unroll
            for (int rg = 0; rg < 4; rg++) {
                float v = s[tg][rg] * __builtin_amdgcn_rcpf(fmaxf(hnr[rg] * hc, 1e-12f));
                sv[tg][rg] = (vm == 0.f) ? -1e9f : v;
            }
        }
        float m_new[4], alpha[4], tsum[4], pv[4][4];
        #pragma unroll
        for (int rg = 0; rg < 4; rg++) {
            float m = fmaxf(fmaxf(sv[0][rg], sv[1][rg]), fmaxf(sv[2][rg], sv[3][rg]));
            #pragma unroll
            for (int d = 1; d < 16; d <<= 1) m = fmaxf(m, __shfl_xor(m, d));
            m_new[rg] = fmaxf(m_old[rg], m);
            alpha[rg] = __expf(m_old[rg] - m_new[rg]);
        }
        #pragma unroll
        for (int rg = 0; rg < 4; rg++) {
            float p0_ = __expf(sv[0][rg] - m_new[rg]);
            float p1_ = __expf(sv[1][rg] - m_new[rg]);
            float p2_ = __expf(sv[2][rg] - m_new[rg]);
            float p3_ = __expf(sv[3][rg] - m_new[rg]);
            pv[0][rg] = p0_; pv[1][rg] = p1_; pv[2][rg] = p2_; pv[3][rg] = p3_;
            float ss = p0_ + p1_ + p2_ + p3_;
            #pragma unroll
            for (int d = 1; d < 16; d <<= 1) ss += __shfl_xor(ss, d);
            tsum[rg] = ss;
        }
        #pragma unroll
        for (int rg = 0; rg < 4; rg++) {
            l_old[rg] = l_old[rg] * alpha[rg] + tsum[rg];
            m_old[rg] = m_new[rg];
        }
        #pragma unroll
        for (int vt = 0; vt < 8; vt++) {
            #pragma unroll
            for (int rg = 0; rg < 4; rg++) o[vt][rg] *= alpha[rg];
        }
        #pragma unroll
        for (int tg = 0; tg < 4; tg++) {
            #pragma unroll
            for (int rg = 0; rg < 4; rg++) {
                int off = ((quad << 2) + rg) * 72 + (tg << 4) + lm;
                float p = pv[tg][rg];
                unsigned short h = f2bf(p);
                Ph[wv][off] = h;
                Plo[wv][off] = f2bf_t(p - bf2f(h));
            }
        }
        __asm__ volatile("s_waitcnt lgkmcnt(0)" ::: "memory");
        #pragma unroll
        for (int c2 = 0; c2 < 2; c2++) {
            int poff = pwr + (c2 << 5) + (quad << 3);
            short8 pah = *(const short8*)&Ph[wv][poff];
            short8 pal = *(const short8*)&Plo[wv][poff];
            int cg = (jt << 1) + c2;
            #pragma unroll
            for (int vt = 0; vt < 8; vt++) {
                size_t b0 = ((size_t)(vt * 128 + cg) * 64 + lane) * 8;
                short8 vh = *(const short8*)(Vh + b0);
                short8 vl = *(const short8*)(Vl + b0);
                o[vt] = MFMA16(pah, vh, o[vt]);
                o[vt] = MFMA16(pah, vl, o[vt]);
                o[vt] = MFMA16(pal, vh, o[vt]);
            }
        }
    }
    size_t pb = ((size_t)rgg * 8 + pidx) * 16;
    #pragma unroll
    for (int rg = 0; rg < 4; rg++) {
        int r = (quad << 2) + rg;
        #pragma unroll
        for (int vt = 0; vt < 8; vt++)
            pO[(pb + r) * 128 + (vt << 4) + lm] = o[vt][rg];
    }
    if (lm == 0) {
        #pragma unroll
        for (int rg = 0; rg < 4; rg++) {
            int r = (quad << 2) + rg;
            pM[pb + r] = m_old[rg];
            pL[pb + r] = l_old[rg];
        }
    }
}

// Merge the 8 col-chunk partials per 16-row group (exact fp32 softmax merge).
__global__ __launch_bounds__(256) void hc2s_merge(const float* __restrict__ pO,
        const float* __restrict__ pM, const float* __restrict__ pL,
        float* __restrict__ O)
{
    int rgg = blockIdx.x;
    int tid = threadIdx.x;
    int r = tid >> 4;
    int c0 = (tid & 15) << 3;
    float m[8], e[8];
    float M = -INFINITY;
    #pragma unroll
    for (int i = 0; i < 8; i++) {
        m[i] = pM[((size_t)rgg * 8 + i) * 16 + r];
        M = fmaxf(M, m[i]);
    }
    float L = 0.f;
    #pragma unroll
    for (int i = 0; i < 8; i++) {
        e[i] = __expf(m[i] - M);
        L += pL[((size_t)rgg * 8 + i) * 16 + r] * e[i];
    }
    float invL = __builtin_amdgcn_rcpf(L);
    float a[8];
    #pragma unroll
    for (int k = 0; k < 8; k++) a[k] = 0.f;
    #pragma unroll
    for (int i = 0; i < 8; i++) {
        const float* src = pO + (((size_t)rgg * 8 + i) * 16 + r) * 128 + c0;
        float4 v0 = *(const float4*)src;
        float4 v1 = *(const float4*)(src + 4);
        a[0] += v0.x * e[i]; a[1] += v0.y * e[i]; a[2] += v0.z * e[i]; a[3] += v0.w * e[i];
        a[4] += v1.x * e[i]; a[5] += v1.y * e[i]; a[6] += v1.z * e[i]; a[7] += v1.w * e[i];
    }
    float* dst = O + ((size_t)rgg * 16 + r) * 128 + c0;
    #pragma unroll
    for (int k = 0; k < 8; k++) dst[k] = a[k] * invL;
}

// ---------------------------------------------------------------------------
// GRU weight pack
// ---------------------------------------------------------------------------
__global__ void pack_wb(const float* __restrict__ W, unsigned short* __restrict__ Wp,
                        int K, int nch)
{
    int idx = blockIdx.x * 256 + threadIdx.x;
    if (idx >= 24 * nch * 64) return;
    int lane = idx & 63;
    int c = (idx >> 6) % nch;
    int t = idx / (nch * 64);
    int n = t * 16 + (lane & 15);
    int kb = c * 32 + (lane >> 4) * 8;
    #pragma unroll
    for (int j = 0; j < 8; j++) {
        int k = kb + j;
        float f = (k < K) ? W[(size_t)n * K + k] : 0.f;
        Wp[(size_t)idx * 8 + j] = f2bf(f);
    }
}

// ---------------------------------------------------------------------------
// MFMA 2-layer GRU, MERGED-PHASE version:
// iteration i does ONE MFMA phase computing L0-gates(i+1) [x(i+1), h0(i)] AND
// L1-gates(i) [h0(i) shared, h1(i-1)] -> 18 ds_read_b128/wave/iter (was 26),
// one barrier/iter. h-recurrence values live in fp32 REGISTERS (the thread
// that wrote h(row,col) is the thread that needs it next step) -> zero scalar
// LDS hold-reads. Accumulators are bias-initialized. x is read DIRECTLY from
// the input (L2-resident per block), converted on the fly.
// Buffers: iter i reads h0A[B], h1A[B^1], xA[B^1]; writes h0A[B^1], h1A[B],
// xA[B]  (B = i&1; read/write sets disjoint -> single end-of-iter barrier).
// ---------------------------------------------------------------------------
__global__ __launch_bounds__(512, 2) void gru_mfma(
    const float* __restrict__ xg,
    const unsigned short* __restrict__ wih0p,
    const unsigned short* __restrict__ whh0p,
    const unsigned short* __restrict__ wih1p,
    const unsigned short* __restrict__ whh1p,
    const float* __restrict__ bih0, const float* __restrict__ bhh0,
    const float* __restrict__ bih1, const float* __restrict__ bhh1,
    float* __restrict__ xh)
{
    __shared__ __attribute__((aligned(16))) unsigned short h0A[2][2][16 * 136]; // 17.4 KB
    __shared__ __attribute__((aligned(16))) unsigned short h1A[2][2][16 * 136]; // 17.4 KB
    __shared__ __attribute__((aligned(16))) unsigned short xA[2][2][16 * 40];   // 5.1 KB

    const int tid = threadIdx.x;
    const int w2 = tid >> 6;
    const int lane = tid & 63;
    const int quad = lane >> 4;
    const int lm = lane & 15;
    const int n0 = blockIdx.x << 4;
    const int j = (w2 << 4) + lm;

    for (int i = tid; i < 2 * 2 * 16 * 136; i += 512) {
        ((unsigned short*)h0A)[i] = 0;
        ((unsigned short*)h1A)[i] = 0;
    }
    for (int i = tid; i < 2 * 2 * 16 * 40; i += 512) ((unsigned short*)xA)[i] = 0;

    float br0 = bih0[j] + bhh0[j];
    float bz0 = bih0[128 + j] + bhh0[128 + j];
    float bni0 = bih0[256 + j];
    float bnh0 = bhh0[256 + j];
    float br1 = bih1[j] + bhh1[j];
    float bz1 = bih1[128 + j] + bhh1[128 + j];
    float bni1 = bih1[256 + j];
    float bnh1 = bhh1[256 + j];

    // register-resident weight fragments (t-invariant)
    short8 W0x[3], W0h[3][4], W1x[3][4], W1h[3][4];
    {
        const int lb = lane * 8;
        W0x[0] = *(const short8*)&wih0p[(size_t)(w2) * 512 + lb];
        W0x[1] = *(const short8*)&wih0p[(size_t)(8 + w2) * 512 + lb];
        W0x[2] = *(const short8*)&wih0p[(size_t)(16 + w2) * 512 + lb];
        #pragma unroll
        for (int c = 0; c < 4; c++) {
            W0h[0][c] = *(const short8*)&whh0p[(size_t)((w2) * 4 + c) * 512 + lb];
            W0h[1][c] = *(const short8*)&whh0p[(size_t)((8 + w2) * 4 + c) * 512 + lb];
            W0h[2][c] = *(const short8*)&whh0p[(size_t)((16 + w2) * 4 + c) * 512 + lb];
            W1x[0][c] = *(const short8*)&wih1p[(size_t)((w2) * 4 + c) * 512 + lb];
            W1x[1][c] = *(const short8*)&wih1p[(size_t)((8 + w2) * 4 + c) * 512 + lb];
            W1x[2][c] = *(const short8*)&wih1p[(size_t)((16 + w2) * 4 + c) * 512 + lb];
            W1h[0][c] = *(const short8*)&whh1p[(size_t)((w2) * 4 + c) * 512 + lb];
            W1h[1][c] = *(const short8*)&whh1p[(size_t)((8 + w2) * 4 + c) * 512 + lb];
            W1h[2][c] = *(const short8*)&whh1p[(size_t)((16 + w2) * 4 + c) * 512 + lb];
        }
    }

    const int aoff = lm * 136 + quad * 8;
    const int xoff = lm * 40 + quad * 8;
    const bool stager = tid < 16 * DDIM;
    const int sn = tid / DDIM, sd = tid % DDIM;            // hoisted div/mod
    const float* xrow = xg + (size_t)(n0 + sn) * (DDIM * TSTEPS) + sd * TSTEPS;
    const int soff = sn * 40 + sd;

    float h0reg[4] = {0.f, 0.f, 0.f, 0.f};
    float h1reg[4] = {0.f, 0.f, 0.f, 0.f};

    // ---- prologue: stage x(0)->xA[0], x(1)->xA[1] ----
    if (stager) {
        float v0 = xrow[0], v1 = xrow[1];
        unsigned short a = f2bf_t(v0);
        xA[0][0][soff] = a; xA[0][1][soff] = f2bf_t(v0 - bf2f(a));
        unsigned short b = f2bf_t(v1);
        xA[1][0][soff] = b; xA[1][1][soff] = f2bf_t(v1 - bf2f(b));
    }
    __syncthreads();

    // ---- prologue: L0(0) with h0(-1)=0 (x-term only) -> h0(0) ----
    {
        f32x4 accr = (f32x4){br0, br0, br0, br0};
        f32x4 accz = (f32x4){bz0, bz0, bz0, bz0};
        f32x4 accni = (f32x4){bni0, bni0, bni0, bni0};
        short8 axh = *(const short8*)&xA[0][0][xoff];
        short8 axl = *(const short8*)&xA[0][1][xoff];
        accr = MFMA16(axh, W0x[0], accr);
        accr = MFMA16(axl, W0x[0], accr);
        accz = MFMA16(axh, W0x[1], accz);
        accz = MFMA16(axl, W0x[1], accz);
        accni = MFMA16(axh, W0x[2], accni);
        accni = MFMA16(axl, W0x[2], accni);
        #pragma unroll
        for (int rg = 0; rg < 4; rg++) {
            float r = sigm(accr[rg]);
            float z = sigm(accz[rg]);
            float nc = tanh_f(accni[rg] + r * bnh0);
            float hnew = nc - z * nc;     // h_old = 0
            h0reg[rg] = hnew;
            int off = (quad * 4 + rg) * 136 + j;
            unsigned short hh_ = f2bf_t(hnew);
            h0A[0][0][off] = hh_;
            h0A[0][1][off] = f2bf_t(hnew - bf2f(hh_));
        }
    }
    __syncthreads();

#define GRU_IT(B, DO_L0, XT, LAST)                                                \
{                                                                                 \
    float xv = 0.f;                                                               \
    if ((XT) >= 0 && stager) xv = xrow[XT];   /* issue early, write late */       \
    f32x4 accr0 = (f32x4){br0, br0, br0, br0};                                    \
    f32x4 accz0 = (f32x4){bz0, bz0, bz0, bz0};                                    \
    f32x4 accni0 = (f32x4){bni0, bni0, bni0, bni0};                               \
    f32x4 accnh0 = (f32x4){bnh0, bnh0, bnh0, bnh0};                               \
    f32x4 accr1 = (f32x4){br1, br1, br1, br1};                                    \
    f32x4 accz1 = (f32x4){bz1, bz1, bz1, bz1};                                    \
    f32x4 accni1 = (f32x4){bni1, bni1, bni1, bni1};                               \
    f32x4 accnh1 = (f32x4){bnh1, bnh1, bnh1, bnh1};                               \
    if (DO_L0) {                                                                  \
        short8 axh = *(const short8*)&xA[(B) ^ 1][0][xoff];                       \
        short8 axl = *(const short8*)&xA[(B) ^ 1][1][xoff];                       \
        accr0 = MFMA16(axh, W0x[0], accr0);                                       \
        accr0 = MFMA16(axl, W0x[0], accr0);                                       \
        accz0 = MFMA16(axh, W0x[1], accz0);                                       \
        accz0 = MFMA16(axl, W0x[1], accz0);                                       \
        accni0 = MFMA16(axh, W0x[2], accni0);                                     \
        accni0 = MFMA16(axl, W0x[2], accni0);                                     \
    }                                                                             \
    _Pragma("unroll")                                                             \
    for (int c = 0; c < 4; c++) {                                                 \
        short8 a0h = *(const short8*)&h0A[B][0][aoff + c * 32];                   \
        short8 a0l = *(const short8*)&h0A[B][1][aoff + c * 32];                   \
        if (DO_L0) {                                                              \
            accr0 = MFMA16(a0h, W0h[0][c], accr0);                                \
            accr0 = MFMA16(a0l, W0h[0][c], accr0);                                \
            accz0 = MFMA16(a0h, W0h[1][c], accz0);                                \
            accz0 = MFMA16(a0l, W0h[1][c], accz0);                                \
            accnh0 = MFMA16(a0h, W0h[2][c], accnh0);                              \
            accnh0 = MFMA16(a0l, W0h[2][c], accnh0);                              \
        }                                                                         \
        accr1 = MFMA16(a0h, W1x[0][c], accr1);                                    \
        accr1 = MFMA16(a0l, W1x[0][c], accr1);                                    \
        accz1 = MFMA16(a0h, W1x[1][c], accz1);                                    \
        accz1 = MFMA16(a0l, W1x[1][c], accz1);                                    \
        accni1 = MFMA16(a0h, W1x[2][c], accni1);                                  \
        accni1 = MFMA16(a0l, W1x[2][c], accni1);                                  \
        short8 a1h = *(const short8*)&h1A[(B) ^ 1][0][aoff + c * 32];             \
        short8 a1l = *(const short8*)&h1A[(B) ^ 1][1][aoff + c * 32];             \
        accr1 = MFMA16(a1h, W1h[0][c], accr1);                                    \
        accr1 = MFMA16(a1l, W1h[0][c], accr1);                                    \
        accz1 = MFMA16(a1h, W1h[1][c], accz1);                                    \
        accz1 = MFMA16(a1l, W1h[1][c], accz1);                                    \
        accnh1 = MFMA16(a1h, W1h[2][c], accnh1);                                  \
        accnh1 = MFMA16(a1l, W1h[2][c], accnh1);                                  \
    }                                                                             \
    if (DO_L0) {                                                                  \
        _Pragma("unroll")                                                         \
        for (int rg = 0; rg < 4; rg++) {                                          \
            float r = sigm(accr0[rg]);                                            \
            float z = sigm(accz0[rg]);                                            \
            float nc = tanh_f(accni0[rg] + r * accnh0[rg]);                       \
            float hnew = nc + z * (h0reg[rg] - nc);                               \
            h0reg[rg] = hnew;                                                     \
            int off = (quad * 4 + rg) * 136 + j;                                  \
            unsigned short hh_ = f2bf_t(hnew);                                    \
            h0A[(B) ^ 1][0][off] = hh_;                                           \
            h0A[(B) ^ 1][1][off] = f2bf_t(hnew - bf2f(hh_));                      \
        }                                                                         \
    }                                                                             \
    _Pragma("unroll")                                                             \
    for (int rg = 0; rg < 4; rg++) {                                              \
        float r = sigm(accr1[rg]);                                                \
        float z = sigm(accz1[rg]);                                                \
        float nc = tanh_f(accni1[rg] + r * accnh1[rg]);                           \
        float hnew = nc + z * (h1reg[rg] - nc);                                   \
        h1reg[rg] = hnew;                                                         \
        if (LAST) {                                                               \
            xh[(size_t)(n0 + quad * 4 + rg) * HDIM + j] = hnew;                   \
        } else {                                                                  \
            int off = (quad * 4 + rg) * 136 + j;                                  \
            unsigned short hh_ = f2bf_t(hnew);                                    \
            h1A[B][0][off] = hh_;                                                 \
            h1A[B][1][off] = f2bf_t(hnew - bf2f(hh_));                            \
        }                                                                         \
    }                                                                             \
    if ((XT) >= 0 && stager) {                                                    \
        unsigned short hh_ = f2bf_t(xv);                                          \
        xA[B][0][soff] = hh_;                                                     \
        xA[B][1][soff] = f2bf_t(xv - bf2f(hh_));                                  \
    }                                                                             \
    if (!(LAST)) __syncthreads();                                                 \
}

    // iters 0..61 (x-loads i+2 = 2..63 all valid)
    for (int i = 0; i < 62; i += 2) {
        GRU_IT(0, true, i + 2, false)
        GRU_IT(1, true, i + 3, false)
    }
    GRU_IT(0, true, -1, false)    // iter 62: L0(63)+L1(62), no more x
    GRU_IT(1, false, -1, true)    // iter 63: L1(63) only -> xh
#undef GRU_IT
}

// ---------------------------------------------------------------------------
// den / s2ct (unchanged)
// ---------------------------------------------------------------------------
__global__ __launch_bounds__(256) void den_atomic(const float* __restrict__ cm,
        const float* __restrict__ mv, float* __restrict__ den)
{
    int c = blockIdx.x * 64 + (threadIdx.x & 63);
    int rg = threadIdx.x >> 6;
    int nbase = blockIdx.y * 128;
    float acc = 0.f;
    for (int i = 0; i < 32; i++) {
        int n = nbase + rg + (i << 2);
        acc += cm[(size_t)n * CDIM + c] * mv[n];
    }
    __shared__ float red[4][64];
    red[rg][threadIdx.x & 63] = acc;
    __syncthreads();
    if (rg == 0)
        atomicAdd(&den[c], red[0][threadIdx.x] + red[1][threadIdx.x] +
                           red[2][threadIdx.x] + red[3][threadIdx.x]);
}

__global__ __launch_bounds__(256) void s2ct_trans(const float* __restrict__ cm,
        const float* __restrict__ mv, const float* __restrict__ den,
        float* __restrict__ s2cT)
{
    __shared__ float tile[64][65];
    __shared__ float mvs[64];
    const int tid = threadIdx.x;
    const int n0 = blockIdx.x << 6;
    const int c0 = blockIdx.y << 6;
    const int lc = tid & 63, lr = tid >> 6;
    if (tid < 64) mvs[tid] = mv[n0 + tid];
    #pragma unroll
    for (int i = 0; i < 16; i++) {
        int n = lr + (i << 2);
        tile[n][lc] = cm[(size_t)(n0 + n) * CDIM + c0 + lc];
    }
    __syncthreads();
    #pragma unroll
    for (int i = 0; i < 16; i++) {
        int c = lr + (i << 2);
        float m = tile[lc][c];
        float d = den[c0 + c];
        s2cT[(size_t)(c0 + c) * NR + n0 + lc] = (m * mvs[lc]) / (d * m + 1.f);
    }
}

// ---------------------------------------------------------------------------
// Small helpers
// ---------------------------------------------------------------------------
__global__ void row_norm(const float* __restrict__ a, float* __restrict__ out)
{
    int r = blockIdx.x;
    float acc = 0.f;
    for (int h = threadIdx.x; h < HDIM; h += 64) {
        float v = a[(size_t)r * HDIM + h];
        acc += v * v;
    }
    for (int o = 32; o > 0; o >>= 1) acc += __shfl_down(acc, o);
    if (threadIdx.x == 0) out[r] = sqrtf(acc);
}

__global__ void row_nonzero(const float* __restrict__ a, float* __restrict__ out)
{
    int r = blockIdx.x;
    float acc = 0.f;
    for (int h = threadIdx.x; h < HDIM; h += 64) acc += a[(size_t)r * HDIM + h];
    for (int o = 32; o > 0; o >>= 1) acc += __shfl_down(acc, o);
    if (threadIdx.x == 0) out[r] = (acc != 0.f) ? 1.f : 0.f;
}

__global__ void row_norm_nz(const float* __restrict__ a, float* __restrict__ nrm,
                            float* __restrict__ nz)
{
    int r = blockIdx.x;
    float acc = 0.f, s = 0.f;
    for (int h = threadIdx.x; h < HDIM; h += 64) {
        float v = a[(size_t)r * HDIM + h];
        acc += v * v;
        s += v;
    }
    for (int o = 32; o > 0; o >>= 1) { acc += __shfl_down(acc, o); s += __shfl_down(s, o); }
    if (threadIdx.x == 0) { nrm[r] = sqrtf(acc); nz[r] = (s != 0.f) ? 1.f : 0.f; }
}

// cos_softmax_row: wave-shuffle reductions, __expf + rcp.
__global__ __launch_bounds__(256) void cos_softmax_row(float* __restrict__ data, int N,
        const float* __restrict__ rn, const float* __restrict__ cn,
        const float* __restrict__ vmask)
{
    int row = blockIdx.x;
    float* d = data + (size_t)row * N;
    int tid = threadIdx.x;
    int wv = tid >> 6, lane = tid & 63;
    __shared__ float red[8];
    float rnv = rn ? rn[row] : 0.f;
    float mx = -INFINITY;
    for (int j = tid; j < N; j += 256) {
        float v = d[j];
        if (cn) v = v * __builtin_amdgcn_rcpf(fmaxf(rnv * cn[j], 1e-12f));
        if (vmask && vmask[j] == 0.f) v = -1e9f;
        d[j] = v;
        mx = fmaxf(mx, v);
    }
    #pragma unroll
    for (int m = 1; m < 64; m <<= 1) mx = fmaxf(mx, __shfl_xor(mx, m));
    if (lane == 0) red[wv] = mx;
    __syncthreads();
    float M = fmaxf(fmaxf(red[0], red[1]), fmaxf(red[2], red[3]));
    float sum = 0.f;
    for (int j = tid; j < N; j += 256) {
        float e = __expf(d[j] - M);
        d[j] = e;
        sum += e;
    }
    #pragma unroll
    for (int m = 1; m < 64; m <<= 1) sum += __shfl_xor(sum, m);
    if (lane == 0) red[4 + wv] = sum;
    __syncthreads();
    float inv = __builtin_amdgcn_rcpf(red[4] + red[5] + red[6] + red[7]);
    for (int j = tid; j < N; j += 256) {
        float v = d[j] * inv;
        if (vmask) v *= vmask[j];
        d[j] = v;
    }
}

__global__ void colsum_scatter(const float* __restrict__ vals, const int* __restrict__ idxs,
                               float* __restrict__ colsum)
{
    int idx = blockIdx.x * 256 + threadIdx.x;
    if (idx < NR * KTOP) atomicAdd(&colsum[idxs[idx]], vals[idx]);
}

__global__ void hh_scatter(const float* __restrict__ vals, const int* __restrict__ idxs,
                           const float* __restrict__ hsh, float* __restrict__ hh)
{
    int p = blockIdx.x;
    int j = idxs[p];
    float v = vals[p];
    int i = p / KTOP;
    atomicAdd(&hh[(size_t)j * HDIM + threadIdx.x], v * hsh[(size_t)i * HDIM + threadIdx.x]);
}

__global__ void hh_diag(const float* __restrict__ colsum, const float* __restrict__ diag,
                        const float* __restrict__ hsh, float* __restrict__ hh)
{
    int idx = blockIdx.x * 256 + threadIdx.x;
    int j = idx >> 7;
    if (colsum[j] != 0.f) hh[idx] += diag[j] * hsh[idx];
}

__global__ void head_kernel(const float* __restrict__ ps, const float* __restrict__ hs,
                            const float* __restrict__ indi, const float* __restrict__ w,
                            const float* __restrict__ b, float* __restrict__ out)
{
    int n = blockIdx.x;
    int t = threadIdx.x;
    float acc = 0.f;
    for (int h = t; h < HDIM; h += 64) {
        size_t k = (size_t)n * HDIM + h;
        acc += (ps[k] + hs[k] + indi[k]) * w[h];
    }
    for (int o = 32; o > 0; o >>= 1) acc += __shfl_down(acc, o);
    if (t == 0) out[n] = acc + b[0];
}

// ---------------------------------------------------------------------------
// host-side helpers
// ---------------------------------------------------------------------------
static inline void mg(hipStream_t s, const float* A, const unsigned short* Bh,
                      const unsigned short* Bl, const float* bias, float* C,
                      int M, int N, int K, int z, int flags,
                      const float* aux = nullptr, float* sub = nullptr,
                      const unsigned short* Ah = nullptr, const unsigned short* Al = nullptr)
{
    MG g{A, Bh, Bl, bias, C, aux, sub, Ah, Al, N, K, K / z,
         flags | (z > 1 ? 4 : 0) | (Ah ? 16 : 0)};
    mfma_gemm<<<dim3(N / 64, M / 64, z), 256, 0, s>>>(g);
}
static inline void pbt(hipStream_t s, const float* src, unsigned short* hi,
                       unsigned short* lo, int N, int K)
{
    int total = (N / 16) * (K / 32) * 64;
    pack_bt<<<(total + 255) / 256, 256, 0, s>>>(src, hi, lo, K, total);
}
static inline void pboth(hipStream_t s, const float* src,
                         unsigned short* bth, unsigned short* btl,
                         unsigned short* knh, unsigned short* knl, int N)
{
    int totBT = (N / 16) * 4 * 64;
    int totKN = 8 * (N / 32) * 64;
    int tot = totBT > totKN ? totBT : totKN;
    pack_both<<<(tot + 255) / 256, 256, 0, s>>>(src, bth, btl, knh, knl, N, totKN);
}

extern "C" void kernel_launch(void* const* d_in, const int* in_sizes, int n_in,
                              void* d_out, int out_size, void* d_ws, size_t ws_size,
                              hipStream_t stream)
{
    (void)in_sizes; (void)n_in; (void)out_size; (void)ws_size;
    const float* x    = (const float*)d_in[0];
    const float* cm   = (const float*)d_in[1];
    const float* mv   = (const float*)d_in[2];
    const float* wih0 = (const float*)d_in[3];
    const float* whh0 = (const float*)d_in[4];
    const float* bih0 = (const float*)d_in[5];
    const float* bhh0 = (const float*)d_in[6];
    const float* wih1 = (const float*)d_in[7];
    const float* whh1 = (const float*)d_in[8];
    const float* bih1 = (const float*)d_in[9];
    const float* bhh1 = (const float*)d_in[10];
    const float* w_ps = (const float*)d_in[11];
    const float* b_ps = (const float*)d_in[12];
    const float* w_hs = (const float*)d_in[13];
    const float* b_hs = (const float*)d_in[14];
    const float* w_ps_fore = (const float*)d_in[15];
    const float* b_ps_fore = (const float*)d_in[16];
    const float* w_hs_fore = (const float*)d_in[17];
    const float* b_hs_fore = (const float*)d_in[18];
    const float* w_ps_back = (const float*)d_in[19];
    const float* b_ps_back = (const float*)d_in[20];
    const float* w_hs_back = (const float*)d_in[21];
    const float* b_hs_back = (const float*)d_in[22];
    const float* w_indi = (const float*)d_in[23];
    const float* b_indi = (const float*)d_in[24];
    const float* w_out  = (const float*)d_in[25];
    const float* b_out  = (const float*)d_in[26];
    float* out = (float*)d_out;

    // ---- workspace layout (floats) ----
    float* ws = (float*)d_ws;
    float* BIG = ws;                         // 16,777,216 (overlaid)
    float* h0 = ws + 16777216;               // 524288 (unused)
    float* h1 = h0 + 524288;                 // x_hidden
    float* den = h1 + 524288;                // 512
    float* v1 = den + 512;                   // 512
    float* hidden = v1 + 512;                // 65536
    float* hidden2 = hidden + 65536;         // 65536
    float* xnorm = hidden2 + 65536;          // 4096
    float* h2n = xnorm + 4096;               // 512
    float* p0 = h2n + 512;                   // 524288
    float* p_shared = p0 + 524288;
    float* p_back = p_shared + 524288;
    float* out_ps = p_back + 524288;
    float* h_shared = out_ps + 524288;
    float* hn = h_shared + 524288;           // 4096
    float* diagv = hn + 4096;                // 4096
    float* colsum = diagv + 4096;            // 4096
    float* tvals = colsum + 4096;            // 40960
    int*   tidx = (int*)(tvals + 40960);     // 40960 ints
    float* hidden_h = (float*)(tidx + 40960);
    float* v2 = hidden_h + 524288;           // 4096
    float* hhn = v2 + 4096;                  // 4096
    float* hsi0 = hhn + 4096;                // 524288
    float* h_si = hsi0 + 524288;
    float* h_back = h_si + 524288;
    float* out_hs = h_back + 524288;
    float* indi = out_hs + 524288;
    float* out_indi = indi + 524288;
    float* extra = out_indi + 524288;

    // GRU-phase overlays inside BIG:
    unsigned short* wih0p = (unsigned short*)(BIG + 5242880);
    unsigned short* whh0p = wih0p + 12288;
    unsigned short* wih1p = whh0p + 49152;
    unsigned short* whh1p = wih1p + 49152;
    // concept-phase overlays inside BIG:
    float* s2cT = BIG;
    float* L    = BIG + 2097152;
    float* c2s  = BIG + 4194304;
    unsigned short* PB = (unsigned short*)(BIG + 6291456);
    unsigned short* pbt_xh_hi = PB;
    unsigned short* pbt_xh_lo = pbt_xh_hi + 524288;
    unsigned short* pkn_xh_hi = pbt_xh_lo + 524288;
    unsigned short* pkn_xh_lo = pkn_xh_hi + 524288;
    unsigned short* pbt_h2_hi = pkn_xh_lo + 524288;
    unsigned short* pbt_h2_lo = pbt_h2_hi + 65536;
    unsigned short* pkn_h2_hi = pbt_h2_lo + 65536;
    unsigned short* pkn_h2_lo = pkn_h2_hi + 65536;
    unsigned short* wps_hi  = pkn_h2_lo + 65536;
    unsigned short* wps_lo  = wps_hi + 16384;
    unsigned short* wpsb_hi = wps_lo + 16384;
    unsigned short* wpsb_lo = wpsb_hi + 16384;
    unsigned short* wpsf_hi = wpsb_lo + 16384;
    unsigned short* wpsf_lo = wpsf_hi + 16384;
    unsigned short* pbt_hsh_hi = (unsigned short*)p0;
    unsigned short* pbt_hsh_lo = pbt_hsh_hi + 524288;
    unsigned short* pbt_hh_hi = (unsigned short*)indi;
    unsigned short* pbt_hh_lo = pbt_hh_hi + 524288;
    unsigned short* pkn_hh_hi = (unsigned short*)out_indi;
    unsigned short* pkn_hh_lo = pkn_hh_hi + 524288;
    // flash-partial overlays inside BIG (dead after scan_topk):
    float* part_O = BIG;                     // 4,194,304 floats
    float* part_m = BIG + 4194304;           // 32,768
    float* part_l = BIG + 4227072;           // 32,768
    unsigned short* EX = (unsigned short*)extra;
    unsigned short* whs_hi  = EX;            unsigned short* whs_lo  = EX + 16384;
    unsigned short* whsb_hi = EX + 32768;    unsigned short* whsb_lo = EX + 49152;
    unsigned short* whsf_hi = EX + 65536;    unsigned short* whsf_lo = EX + 81920;
    unsigned short* wind_hi = EX + 98304;    unsigned short* wind_lo = EX + 114688;

    // ================= Phase A: MFMA 2-layer GRU =================
    pack_wb<<<6, 256, 0, stream>>>(wih0, wih0p, DDIM, 1);
    pack_wb<<<24, 256, 0, stream>>>(whh0, whh0p, HDIM, 4);
    pack_wb<<<24, 256, 0, stream>>>(wih1, wih1p, HDIM, 4);
    pack_wb<<<24, 256, 0, stream>>>(whh1, whh1p, HDIM, 4);
    {
        W7 w7;
        w7.src[0] = w_ps;      w7.hi[0] = wps_hi;  w7.lo[0] = wps_lo;
        w7.src[1] = w_ps_back; w7.hi[1] = wpsb_hi; w7.lo[1] = wpsb_lo;
        w7.src[2] = w_ps_fore; w7.hi[2] = wpsf_hi; w7.lo[2] = wpsf_lo;
        w7.src[3] = w_hs;      w7.hi[3] = whs_hi;  w7.lo[3] = whs_lo;
        w7.src[4] = w_hs_back; w7.hi[4] = whsb_hi; w7.lo[4] = whsb_lo;
        w7.src[5] = w_hs_fore; w7.hi[5] = whsf_hi; w7.lo[5] = whsf_lo;
        w7.src[6] = w_indi;    w7.hi[6] = wind_hi; w7.lo[6] = wind_lo;
        pack_w7<<<56, 256, 0, stream>>>(w7);
    }
    gru_mfma<<<NR / 16, 512, 0, stream>>>(x, wih0p, whh0p, wih1p, whh1p,
                                          bih0, bhh0, bih1, bhh1, h1);
    float* x_hidden = h1;

    // ================= Phase B: predefined-concept branch =================
    hipMemsetAsync(den, 0, CDIM * sizeof(float), stream);
    den_atomic<<<dim3(CDIM / 64, 32), 256, 0, stream>>>(cm, mv, den);
    s2ct_trans<<<dim3(NR / 64, CDIM / 64), 256, 0, stream>>>(cm, mv, den, s2cT);
    pboth(stream, x_hidden, pbt_xh_hi, pbt_xh_lo, pkn_xh_hi, pkn_xh_lo, NR);
    hipMemsetAsync(hidden, 0, 65536 * sizeof(float), stream);
    mg(stream, s2cT, pkn_xh_hi, pkn_xh_lo, nullptr, hidden, CDIM, HDIM, NR, 8, 0);
    row_nonzero<<<CDIM, 64, 0, stream>>>(hidden, v1);
    mg(stream, hidden, pbt_xh_hi, pbt_xh_lo, nullptr, L, CDIM, NR, HDIM, 1, 0);
    cos_softmax_row<<<CDIM, 256, 0, stream>>>(L, NR, nullptr, nullptr, nullptr);
    hipMemsetAsync(hidden2, 0, 65536 * sizeof(float), stream);
    mg(stream, L, pkn_xh_hi, pkn_xh_lo, nullptr, hidden2, CDIM, HDIM, NR, 8, 0);
    row_norm<<<NR, 64, 0, stream>>>(x_hidden, xnorm);
    row_norm<<<CDIM, 64, 0, stream>>>(hidden2, h2n);
    pboth(stream, hidden2, pbt_h2_hi, pbt_h2_lo, pkn_h2_hi, pkn_h2_lo, CDIM);
    // packed-A: x_hidden already packed as pbt_xh
    mg(stream, x_hidden, pbt_h2_hi, pbt_h2_lo, nullptr, c2s, NR, CDIM, HDIM, 1, 0,
       nullptr, nullptr, pbt_xh_hi, pbt_xh_lo);
    cos_softmax_row<<<NR, 256, 0, stream>>>(c2s, CDIM, xnorm, h2n, v1);
    hipMemsetAsync(p0, 0, 524288 * sizeof(float), stream);
    mg(stream, c2s, pkn_h2_hi, pkn_h2_lo, nullptr, p0, NR, HDIM, CDIM, 2, 0);
    mg(stream, p0, wps_hi, wps_lo, b_ps, p_shared, NR, HDIM, HDIM, 1, 1);
    // p_back fused with h_shared = x_hidden - p_back
    mg(stream, p_shared, wpsb_hi, wpsb_lo, b_ps_back, p_back, NR, HDIM, HDIM, 1, 1 | 8,
       x_hidden, h_shared);
    mg(stream, p_shared, wpsf_hi, wpsf_lo, b_ps_fore, out_ps, NR, HDIM, HDIM, 1, 1 | 2);

    // ================= Phase C: hidden-concept branch =================
    row_norm<<<NR, 64, 0, stream>>>(h_shared, hn);
    pbt(stream, h_shared, pbt_hsh_hi, pbt_hsh_lo, NR, HDIM);
    // packed-A: the 4096-block NxN GEMM reuses pbt_hsh for BOTH operands
    mg(stream, h_shared, pbt_hsh_hi, pbt_hsh_lo, nullptr, BIG, NR, NR, HDIM, 1, 0,
       nullptr, nullptr, pbt_hsh_hi, pbt_hsh_lo);
    scan_topk<<<NR, 256, 0, stream>>>(BIG, hn, diagv, tvals, tidx);
    hipMemsetAsync(colsum, 0, NR * sizeof(float), stream);
    hipMemsetAsync(hidden_h, 0, 524288 * sizeof(float), stream);
    colsum_scatter<<<(NR * KTOP + 255) / 256, 256, 0, stream>>>(tvals, tidx, colsum);
    hh_scatter<<<NR * KTOP, HDIM, 0, stream>>>(tvals, tidx, h_shared, hidden_h);
    hh_diag<<<2048, 256, 0, stream>>>(colsum, diagv, h_shared, hidden_h);
    row_norm_nz<<<NR, 64, 0, stream>>>(hidden_h, hhn, v2);
    pboth(stream, hidden_h, pbt_hh_hi, pbt_hh_lo, pkn_hh_hi, pkn_hh_lo, NR);
    hc2s_flash<<<dim3(NR / 64, 4), 512, 0, stream>>>(h_shared, hn, hhn, v2,
                                                     pbt_hh_hi, pbt_hh_lo,
                                                     pkn_hh_hi, pkn_hh_lo,
                                                     part_O, part_m, part_l);
    hc2s_merge<<<NR / 16, 256, 0, stream>>>(part_O, part_m, part_l, hsi0);
    mg(stream, hsi0, whs_hi, whs_lo, b_hs, h_si, NR, HDIM, HDIM, 1, 1);
    // h_back fused with indi = h_shared - h_back = x_hidden - p_back - h_back
    mg(stream, h_si, whsb_hi, whsb_lo, b_hs_back, h_back, NR, HDIM, HDIM, 1, 1 | 8,
       h_shared, indi);
    mg(stream, h_si, whsf_hi, whsf_lo, b_hs_fore, out_hs, NR, HDIM, HDIM, 1, 1 | 2);

    // ================= Phase D: individual branch + head =================
    mg(stream, indi, wind_hi, wind_lo, b_indi, out_indi, NR, HDIM, HDIM, 1, 1 | 2);
    head_kernel<<<NR, 64, 0, stream>>>(out_ps, out_hs, out_indi, w_out, b_out, out);
}

// Round 4
// 697.131 us; speedup vs baseline: 1.3604x; 1.0752x over previous
//
#include <hip/hip_runtime.h>
#include <cstddef>

// Problem dims
#define NR 4096      // batch
#define CDIM 512     // concepts
#define HDIM 128     // hidden
#define TSTEPS 64
#define DDIM 20
#define KTOP 10

typedef __attribute__((ext_vector_type(8))) short short8;
typedef __attribute__((ext_vector_type(4))) float f32x4;

__device__ __forceinline__ unsigned short f2bf(float f) {
    union { float f; unsigned u; } x; x.f = f;
    unsigned r = (x.u + 0x7fffu + ((x.u >> 16) & 1u)) >> 16;
    return (unsigned short)r;
}
// truncating bf16 (lo plane captures the residual; hi+lo exact to ~2^-17)
__device__ __forceinline__ unsigned short f2bf_t(float f) {
    union { float f; unsigned u; } x; x.f = f;
    return (unsigned short)(x.u >> 16);
}
__device__ __forceinline__ float bf2f(unsigned short h) {
    union { unsigned u; float f; } x; x.u = ((unsigned)h) << 16;
    return x.f;
}
// inf-safe, clamp-free activations (v_exp + v_rcp only)
__device__ __forceinline__ float sigm(float v) {
    return __builtin_amdgcn_rcpf(1.f + __expf(-v));
}
__device__ __forceinline__ float tanh_f(float v) {
    return 1.f - 2.f * __builtin_amdgcn_rcpf(1.f + __expf(2.f * v));
}

#define MFMA16(a, b, c) __builtin_amdgcn_mfma_f32_16x16x32_bf16(a, b, c, 0, 0, 0)

// ---------------------------------------------------------------------------
// Generic MFMA GEMM. flags: 1 bias, 2 lrelu, 4 atomicAdd (split-K),
// 8 fused subtract: sub[r,c] = aux[r,c] - C[r,c], 16 pre-packed A (BT layout),
// 32 dual-output (blockIdx.z selects {Bh,Bl,bias,C,flags} vs {Bh2,...,flags2}),
// 64 head-accumulate: atomicAdd(hout[row], sum_col v*wout[col]),
// 128 skip C store, 256 add bout[0] once per row (use with 64, on bn==0).
// ---------------------------------------------------------------------------
struct MG {
    const float* A; const unsigned short* Bh; const unsigned short* Bl;
    const float* bias; float* C; const float* aux; float* sub;
    const unsigned short* Ah; const unsigned short* Al;
    const unsigned short* Bh2; const unsigned short* Bl2;
    const float* bias2; float* C2;
    const float* wout; const float* bout; float* hout;
    int N, K, kchunk, flags, flags2;
};

__global__ __launch_bounds__(256) void mfma_gemm(MG g)
{
    const int tid = threadIdx.x;
    const int w = tid >> 6, lane = tid & 63, quad = lane >> 4, lm = lane & 15;
    const int bm = (blockIdx.y << 6) + (w << 4);
    const int bn = blockIdx.x << 6;
    const int NC = g.K >> 5;
    int flags = g.flags;
    const unsigned short* Bh = g.Bh;
    const unsigned short* Bl = g.Bl;
    const float* bias = g.bias;
    float* C = g.C;
    int zk = blockIdx.z;
    if (g.flags & 32) {
        if (blockIdx.z) { Bh = g.Bh2; Bl = g.Bl2; bias = g.bias2; C = g.C2; flags = g.flags2; }
        zk = 0;
    }
    const int c0 = (zk * g.kchunk) >> 5;
    const int c1 = c0 + (g.kchunk >> 5);
    const float* arow = g.A + (size_t)(bm + lm) * g.K;
    const int packA = g.flags & 16;
    f32x4 acc[4];
    #pragma unroll
    for (int t = 0; t < 4; t++) acc[t] = (f32x4){0.f, 0.f, 0.f, 0.f};

    for (int c = c0; c < c1; c++) {
        short8 ah, al;
        if (packA) {
            size_t aidx = ((size_t)((bm >> 4) * NC + c) * 64 + lane) * 8;
            ah = *(const short8*)(g.Ah + aidx);
            al = *(const short8*)(g.Al + aidx);
        } else {
            const float* ap = arow + (c << 5) + (quad << 3);
            float4 a0 = *(const float4*)ap;
            float4 a1 = *(const float4*)(ap + 4);
            #pragma unroll
            for (int jj = 0; jj < 4; jj++) {
                float f = (&a0.x)[jj];
                unsigned short h = f2bf(f);
                ah[jj] = h; al[jj] = f2bf_t(f - bf2f(h));
                f = (&a1.x)[jj];
                h = f2bf(f);
                ah[4 + jj] = h; al[4 + jj] = f2bf_t(f - bf2f(h));
            }
        }
        #pragma unroll
        for (int t = 0; t < 4; t++) {
            size_t bidx = ((size_t)(((bn >> 4) + t) * NC + c) * 64 + lane) * 8;
            short8 bh = *(const short8*)(Bh + bidx);
            short8 bl = *(const short8*)(Bl + bidx);
            acc[t] = MFMA16(ah, bh, acc[t]);
            acc[t] = MFMA16(ah, bl, acc[t]);
            acc[t] = MFMA16(al, bh, acc[t]);
        }
    }
    float rsum[4] = {0.f, 0.f, 0.f, 0.f};
    #pragma unroll
    for (int t = 0; t < 4; t++) {
        #pragma unroll
        for (int rg = 0; rg < 4; rg++) {
            int row = bm + (quad << 2) + rg;
            int col = bn + (t << 4) + lm;
            float v = acc[t][rg];
            if (flags & 1) v += bias[col];
            if (flags & 2) v = v > 0.f ? v : 0.01f * v;
            if (flags & 64) rsum[rg] += v * g.wout[col];
            if (!(flags & 128)) {
                if (flags & 4) atomicAdd(&C[(size_t)row * g.N + col], v);
                else C[(size_t)row * g.N + col] = v;
            }
            if (flags & 8)
                g.sub[(size_t)row * g.N + col] = g.aux[(size_t)row * g.N + col] - v;
        }
    }
    if (flags & 64) {
        #pragma unroll
        for (int rg = 0; rg < 4; rg++) {
            #pragma unroll
            for (int d = 1; d < 16; d <<= 1) rsum[rg] += __shfl_xor(rsum[rg], d);
        }
        if (lm == 0) {
            #pragma unroll
            for (int rg = 0; rg < 4; rg++) {
                float s = rsum[rg];
                if ((flags & 256) && bn == 0) s += g.bout[0];
                atomicAdd(&g.hout[bm + (quad << 2) + rg], s);
            }
        }
    }
}

// B-pack from [N,K] rows; layout [nt][c][lane][8], hi/lo planes.
__global__ void pack_bt(const float* __restrict__ src, unsigned short* __restrict__ hi,
                        unsigned short* __restrict__ lo, int K, int total)
{
    int idx = blockIdx.x * 256 + threadIdx.x;
    if (idx >= total) return;
    int NC = K >> 5;
    int lane = idx & 63;
    int c = (idx >> 6) % NC;
    int t = idx / (NC * 64);
    int n = (t << 4) + (lane & 15);
    int kb = (c << 5) + ((lane >> 4) << 3);
    #pragma unroll
    for (int j = 0; j < 8; j++) {
        float f = src[(size_t)n * K + kb + j];
        unsigned short h = f2bf(f);
        hi[(size_t)idx * 8 + j] = h;
        lo[(size_t)idx * 8 + j] = f2bf_t(f - bf2f(h));
    }
}

// Combined pack (K = HDIM = 128 only): BT (B[n][k]) + KN (B[k][n]) in one pass.
__global__ void pack_both(const float* __restrict__ src,
                          unsigned short* __restrict__ bth, unsigned short* __restrict__ btl,
                          unsigned short* __restrict__ knh, unsigned short* __restrict__ knl,
                          int N, int total_kn)
{
    int idx = blockIdx.x * 256 + threadIdx.x;
    int lane = idx & 63;
    int totBT = (N >> 4) * 256;
    if (idx < totBT) {
        int c = (idx >> 6) & 3;
        int t = idx >> 8;
        int n = (t << 4) + (lane & 15);
        int kb = (c << 5) + ((lane >> 4) << 3);
        #pragma unroll
        for (int j = 0; j < 8; j++) {
            float f = src[(size_t)n * HDIM + kb + j];
            unsigned short h = f2bf(f);
            bth[(size_t)idx * 8 + j] = h;
            btl[(size_t)idx * 8 + j] = f2bf_t(f - bf2f(h));
        }
    }
    if (idx < total_kn) {
        int NC = N >> 5;
        int c = (idx >> 6) % NC;
        int t = idx / (NC * 64);
        int n = (t << 4) + (lane & 15);
        int kb = (c << 5) + ((lane >> 4) << 3);
        #pragma unroll
        for (int j = 0; j < 8; j++) {
            float f = src[(size_t)(kb + j) * HDIM + n];
            unsigned short h = f2bf(f);
            knh[(size_t)idx * 8 + j] = h;
            knl[(size_t)idx * 8 + j] = f2bf_t(f - bf2f(h));
        }
    }
}

// Pack all seven [128,128] weight matrices in one launch.
struct W7 {
    const float* src[7];
    unsigned short* hi[7];
    unsigned short* lo[7];
};
__global__ void pack_w7(W7 p)
{
    int idx = blockIdx.x * 256 + threadIdx.x;   // 7 * 2048
    if (idx >= 7 * 2048) return;
    int m = idx >> 11;
    int r = idx & 2047;
    int lane = r & 63;
    int c = (r >> 6) & 3;
    int t = r >> 8;
    int n = (t << 4) + (lane & 15);
    int kb = (c << 5) + ((lane >> 4) << 3);
    const float* src = p.src[m];
    unsigned short* hi = p.hi[m];
    unsigned short* lo = p.lo[m];
    #pragma unroll
    for (int j = 0; j < 8; j++) {
        float f = src[(size_t)n * HDIM + kb + j];
        unsigned short h = f2bf(f);
        hi[(size_t)r * 8 + j] = h;
        lo[(size_t)r * 8 + j] = f2bf_t(f - bf2f(h));
    }
}

// ---------------------------------------------------------------------------
// scan_topk: wave-shuffle argmax reduce. Tie-break: value desc, index asc.
// ---------------------------------------------------------------------------
__global__ __launch_bounds__(256) void scan_topk(const float* __restrict__ S,
        const float* __restrict__ hn, float* __restrict__ diagv,
        float* __restrict__ tvals, int* __restrict__ tidx)
{
    int row = blockIdx.x;
    const float* d = S + (size_t)row * NR;
    int tid = threadIdx.x;
    int wv = tid >> 6, lane = tid & 63;
    float hi_ = hn[row];
    float lv[16];
    #pragma unroll
    for (int i = 0; i < 16; i++) {
        int j = tid + (i << 8);
        float v = d[j] / fmaxf(hi_ * hn[j], 1e-12f);
        if (j == row) { diagv[row] = v; v = 0.f; }
        lv[i] = v;
    }
    __shared__ float sv[4];
    __shared__ int si[4];
    for (int k = 0; k < KTOP; k++) {
        float bv = -INFINITY; int bi = 0x7fffffff;
        #pragma unroll
        for (int i = 0; i < 16; i++) {
            int j = tid + (i << 8);
            if (lv[i] > bv || (lv[i] == bv && j < bi)) { bv = lv[i]; bi = j; }
        }
        #pragma unroll
        for (int m = 1; m < 64; m <<= 1) {
            float ov = __shfl_xor(bv, m); int oi = __shfl_xor(bi, m);
            if (ov > bv || (ov == bv && oi < bi)) { bv = ov; bi = oi; }
        }
        if (lane == 0) { sv[wv] = bv; si[wv] = bi; }
        __syncthreads();
        bv = sv[0]; bi = si[0];
        #pragma unroll
        for (int w = 1; w < 4; w++) {
            float ov = sv[w]; int oi = si[w];
            if (ov > bv || (ov == bv && oi < bi)) { bv = ov; bi = oi; }
        }
        if (tid == 0) { tvals[row * KTOP + k] = bv; tidx[row * KTOP + k] = bi; }
        if ((bi & 255) == tid) lv[bi >> 8] = -INFINITY;
        __syncthreads();   // protect sv/si reuse next round
    }
}

// ---------------------------------------------------------------------------
// hc2s_flash: split-KV flash with wave-private online softmax (see R1 notes).
// ---------------------------------------------------------------------------
__global__ __launch_bounds__(512) void hc2s_flash(
    const float* __restrict__ hsh, const float* __restrict__ hn,
    const float* __restrict__ hhn, const float* __restrict__ v2,
    const unsigned short* __restrict__ Bh, const unsigned short* __restrict__ Bl,
    const unsigned short* __restrict__ Vh, const unsigned short* __restrict__ Vl,
    float* __restrict__ pO, float* __restrict__ pM, float* __restrict__ pL)
{
    __shared__ __attribute__((aligned(16))) unsigned short Ph[8][16 * 72];
    __shared__ __attribute__((aligned(16))) unsigned short Plo[8][16 * 72];

    const int tid = threadIdx.x;
    const int wv = tid >> 6, lane = tid & 63, quad = lane >> 4, lm = lane & 15;
    const int rg2 = wv >> 1;             // row-group within block (0..3)
    const int cc = wv & 1;               // col-chunk within block (0..1)
    const int bm = (blockIdx.x << 6) + (rg2 << 4);   // wave's 16 rows
    const int rgg = (blockIdx.x << 2) + rg2;         // global 16-row group
    const int pidx = (blockIdx.y << 1) + cc;         // partial index (0..7)
    const int jt0 = (blockIdx.y << 4) + (cc << 3);   // first 64-col tile

    short8 ahh[4], ahl[4];
    #pragma unroll
    for (int c = 0; c < 4; c++) {
        const float* ap = hsh + (size_t)(bm + lm) * HDIM + (c << 5) + (quad << 3);
        float4 a0 = *(const float4*)ap;
        float4 a1 = *(const float4*)(ap + 4);
        #pragma unroll
        for (int j = 0; j < 4; j++) {
            float f = (&a0.x)[j];
            unsigned short h = f2bf(f);
            ahh[c][j] = h; ahl[c][j] = f2bf_t(f - bf2f(h));
            f = (&a1.x)[j];
            h = f2bf(f);
            ahh[c][4 + j] = h; ahl[c][4 + j] = f2bf_t(f - bf2f(h));
        }
    }
    float hnr[4];
    #pragma unroll
    for (int rg = 0; rg < 4; rg++) hnr[rg] = hn[bm + (quad << 2) + rg];

    float m_old[4], l_old[4];
    #pragma unroll
    for (int rg = 0; rg < 4; rg++) { m_old[rg] = -INFINITY; l_old[rg] = 0.f; }
    f32x4 o[8];
    #pragma unroll
    for (int vt = 0; vt < 8; vt++) o[vt] = (f32x4){0.f, 0.f, 0.f, 0.f};

    const int pwr = lm * 72;
    for (int it = 0; it < 8; it++) {
        const int jt = jt0 + it;
        f32x4 s[4];
        #pragma unroll
        for (int tg = 0; tg < 4; tg++) {
            s[tg] = (f32x4){0.f, 0.f, 0.f, 0.f};
            #pragma unroll
            for (int c = 0; c < 4; c++) {
                size_t bidx = ((size_t)(((jt << 2) + tg) * 4 + c) * 64 + lane) * 8;
                short8 bh = *(const short8*)(Bh + bidx);
                short8 bl = *(const short8*)(Bl + bidx);
                s[tg] = MFMA16(ahh[c], bh, s[tg]);
                s[tg] = MFMA16(ahh[c], bl, s[tg]);
                s[tg] = MFMA16(ahl[c], bh, s[tg]);
            }
        }
        float sv[4][4];
        #pragma unroll
        for (int tg = 0; tg < 4; tg++) {
            int col = (jt << 6) + (tg << 4) + lm;
            float hc = hhn[col];
            float vm = v2[col];
            #pragma unroll
            for (int rg = 0; rg < 4; rg++) {
                float v = s[tg][rg] * __builtin_amdgcn_rcpf(fmaxf(hnr[rg] * hc, 1e-12f));
                sv[tg][rg] = (vm == 0.f) ? -1e9f : v;
            }
        }
        float m_new[4], alpha[4], tsum[4], pv[4][4];
        #pragma unroll
        for (int rg = 0; rg < 4; rg++) {
            float m = fmaxf(fmaxf(sv[0][rg], sv[1][rg]), fmaxf(sv[2][rg], sv[3][rg]));
            #pragma unroll
            for (int d = 1; d < 16; d <<= 1) m = fmaxf(m, __shfl_xor(m, d));
            m_new[rg] = fmaxf(m_old[rg], m);
            alpha[rg] = __expf(m_old[rg] - m_new[rg]);
        }
        #pragma unroll
        for (int rg = 0; rg < 4; rg++) {
            float p0_ = __expf(sv[0][rg] - m_new[rg]);
            float p1_ = __expf(sv[1][rg] - m_new[rg]);
            float p2_ = __expf(sv[2][rg] - m_new[rg]);
            float p3_ = __expf(sv[3][rg] - m_new[rg]);
            pv[0][rg] = p0_; pv[1][rg] = p1_; pv[2][rg] = p2_; pv[3][rg] = p3_;
            float ss = p0_ + p1_ + p2_ + p3_;
            #pragma unroll
            for (int d = 1; d < 16; d <<= 1) ss += __shfl_xor(ss, d);
            tsum[rg] = ss;
        }
        #pragma unroll
        for (int rg = 0; rg < 4; rg++) {
            l_old[rg] = l_old[rg] * alpha[rg] + tsum[rg];
            m_old[rg] = m_new[rg];
        }
        #pragma unroll
        for (int vt = 0; vt < 8; vt++) {
            #pragma unroll
            for (int rg = 0; rg < 4; rg++) o[vt][rg] *= alpha[rg];
        }
        #pragma unroll
        for (int tg = 0; tg < 4; tg++) {
            #pragma unroll
            for (int rg = 0; rg < 4; rg++) {
                int off = ((quad << 2) + rg) * 72 + (tg << 4) + lm;
                float p = pv[tg][rg];
                unsigned short h = f2bf(p);
                Ph[wv][off] = h;
                Plo[wv][off] = f2bf_t(p - bf2f(h));
            }
        }
        __asm__ volatile("s_waitcnt lgkmcnt(0)" ::: "memory");
        #pragma unroll
        for (int c2 = 0; c2 < 2; c2++) {
            int poff = pwr + (c2 << 5) + (quad << 3);
            short8 pah = *(const short8*)&Ph[wv][poff];
            short8 pal = *(const short8*)&Plo[wv][poff];
            int cg = (jt << 1) + c2;
            #pragma unroll
            for (int vt = 0; vt < 8; vt++) {
                size_t b0 = ((size_t)(vt * 128 + cg) * 64 + lane) * 8;
                short8 vh = *(const short8*)(Vh + b0);
                short8 vl = *(const short8*)(Vl + b0);
                o[vt] = MFMA16(pah, vh, o[vt]);
                o[vt] = MFMA16(pah, vl, o[vt]);
                o[vt] = MFMA16(pal, vh, o[vt]);
            }
        }
    }
    size_t pb = ((size_t)rgg * 8 + pidx) * 16;
    #pragma unroll
    for (int rg = 0; rg < 4; rg++) {
        int r = (quad << 2) + rg;
        #pragma unroll
        for (int vt = 0; vt < 8; vt++)
            pO[(pb + r) * 128 + (vt << 4) + lm] = o[vt][rg];
    }
    if (lm == 0) {
        #pragma unroll
        for (int rg = 0; rg < 4; rg++) {
            int r = (quad << 2) + rg;
            pM[pb + r] = m_old[rg];
            pL[pb + r] = l_old[rg];
        }
    }
}

// Merge the 8 col-chunk partials per 16-row group (exact fp32 softmax merge).
__global__ __launch_bounds__(256) void hc2s_merge(const float* __restrict__ pO,
        const float* __restrict__ pM, const float* __restrict__ pL,
        float* __restrict__ O)
{
    int rgg = blockIdx.x;
    int tid = threadIdx.x;
    int r = tid >> 4;
    int c0 = (tid & 15) << 3;
    float m[8], e[8];
    float M = -INFINITY;
    #pragma unroll
    for (int i = 0; i < 8; i++) {
        m[i] = pM[((size_t)rgg * 8 + i) * 16 + r];
        M = fmaxf(M, m[i]);
    }
    float L = 0.f;
    #pragma unroll
    for (int i = 0; i < 8; i++) {
        e[i] = __expf(m[i] - M);
        L += pL[((size_t)rgg * 8 + i) * 16 + r] * e[i];
    }
    float invL = __builtin_amdgcn_rcpf(L);
    float a[8];
    #pragma unroll
    for (int k = 0; k < 8; k++) a[k] = 0.f;
    #pragma unroll
    for (int i = 0; i < 8; i++) {
        const float* src = pO + (((size_t)rgg * 8 + i) * 16 + r) * 128 + c0;
        float4 v0 = *(const float4*)src;
        float4 v1 = *(const float4*)(src + 4);
        a[0] += v0.x * e[i]; a[1] += v0.y * e[i]; a[2] += v0.z * e[i]; a[3] += v0.w * e[i];
        a[4] += v1.x * e[i]; a[5] += v1.y * e[i]; a[6] += v1.z * e[i]; a[7] += v1.w * e[i];
    }
    float* dst = O + ((size_t)rgg * 16 + r) * 128 + c0;
    #pragma unroll
    for (int k = 0; k < 8; k++) dst[k] = a[k] * invL;
}

// ---------------------------------------------------------------------------
// GRU weight pack
// ---------------------------------------------------------------------------
__global__ void pack_wb(const float* __restrict__ W, unsigned short* __restrict__ Wp,
                        int K, int nch)
{
    int idx = blockIdx.x * 256 + threadIdx.x;
    if (idx >= 24 * nch * 64) return;
    int lane = idx & 63;
    int c = (idx >> 6) % nch;
    int t = idx / (nch * 64);
    int n = t * 16 + (lane & 15);
    int kb = c * 32 + (lane >> 4) * 8;
    #pragma unroll
    for (int j = 0; j < 8; j++) {
        int k = kb + j;
        float f = (k < K) ? W[(size_t)n * K + k] : 0.f;
        Wp[(size_t)idx * 8 + j] = f2bf(f);
    }
}

// ---------------------------------------------------------------------------
// MFMA 2-layer GRU, merged-phase, register-recurrence (see R2 notes).
// ---------------------------------------------------------------------------
__global__ __launch_bounds__(512, 2) void gru_mfma(
    const float* __restrict__ xg,
    const unsigned short* __restrict__ wih0p,
    const unsigned short* __restrict__ whh0p,
    const unsigned short* __restrict__ wih1p,
    const unsigned short* __restrict__ whh1p,
    const float* __restrict__ bih0, const float* __restrict__ bhh0,
    const float* __restrict__ bih1, const float* __restrict__ bhh1,
    float* __restrict__ xh)
{
    __shared__ __attribute__((aligned(16))) unsigned short h0A[2][2][16 * 136]; // 17.4 KB
    __shared__ __attribute__((aligned(16))) unsigned short h1A[2][2][16 * 136]; // 17.4 KB
    __shared__ __attribute__((aligned(16))) unsigned short xA[2][2][16 * 40];   // 5.1 KB

    const int tid = threadIdx.x;
    const int w2 = tid >> 6;
    const int lane = tid & 63;
    const int quad = lane >> 4;
    const int lm = lane & 15;
    const int n0 = blockIdx.x << 4;
    const int j = (w2 << 4) + lm;

    for (int i = tid; i < 2 * 2 * 16 * 136; i += 512) {
        ((unsigned short*)h0A)[i] = 0;
        ((unsigned short*)h1A)[i] = 0;
    }
    for (int i = tid; i < 2 * 2 * 16 * 40; i += 512) ((unsigned short*)xA)[i] = 0;

    float br0 = bih0[j] + bhh0[j];
    float bz0 = bih0[128 + j] + bhh0[128 + j];
    float bni0 = bih0[256 + j];
    float bnh0 = bhh0[256 + j];
    float br1 = bih1[j] + bhh1[j];
    float bz1 = bih1[128 + j] + bhh1[128 + j];
    float bni1 = bih1[256 + j];
    float bnh1 = bhh1[256 + j];

    // register-resident weight fragments (t-invariant)
    short8 W0x[3], W0h[3][4], W1x[3][4], W1h[3][4];
    {
        const int lb = lane * 8;
        W0x[0] = *(const short8*)&wih0p[(size_t)(w2) * 512 + lb];
        W0x[1] = *(const short8*)&wih0p[(size_t)(8 + w2) * 512 + lb];
        W0x[2] = *(const short8*)&wih0p[(size_t)(16 + w2) * 512 + lb];
        #pragma unroll
        for (int c = 0; c < 4; c++) {
            W0h[0][c] = *(const short8*)&whh0p[(size_t)((w2) * 4 + c) * 512 + lb];
            W0h[1][c] = *(const short8*)&whh0p[(size_t)((8 + w2) * 4 + c) * 512 + lb];
            W0h[2][c] = *(const short8*)&whh0p[(size_t)((16 + w2) * 4 + c) * 512 + lb];
            W1x[0][c] = *(const short8*)&wih1p[(size_t)((w2) * 4 + c) * 512 + lb];
            W1x[1][c] = *(const short8*)&wih1p[(size_t)((8 + w2) * 4 + c) * 512 + lb];
            W1x[2][c] = *(const short8*)&wih1p[(size_t)((16 + w2) * 4 + c) * 512 + lb];
            W1h[0][c] = *(const short8*)&whh1p[(size_t)((w2) * 4 + c) * 512 + lb];
            W1h[1][c] = *(const short8*)&whh1p[(size_t)((8 + w2) * 4 + c) * 512 + lb];
            W1h[2][c] = *(const short8*)&whh1p[(size_t)((16 + w2) * 4 + c) * 512 + lb];
        }
    }

    const int aoff = lm * 136 + quad * 8;
    const int xoff = lm * 40 + quad * 8;
    const bool stager = tid < 16 * DDIM;
    const int sn = tid / DDIM, sd = tid % DDIM;            // hoisted div/mod
    const float* xrow = xg + (size_t)(n0 + sn) * (DDIM * TSTEPS) + sd * TSTEPS;
    const int soff = sn * 40 + sd;

    float h0reg[4] = {0.f, 0.f, 0.f, 0.f};
    float h1reg[4] = {0.f, 0.f, 0.f, 0.f};

    // ---- prologue: stage x(0)->xA[0], x(1)->xA[1] ----
    if (stager) {
        float v0 = xrow[0], v1 = xrow[1];
        unsigned short a = f2bf_t(v0);
        xA[0][0][soff] = a; xA[0][1][soff] = f2bf_t(v0 - bf2f(a));
        unsigned short b = f2bf_t(v1);
        xA[1][0][soff] = b; xA[1][1][soff] = f2bf_t(v1 - bf2f(b));
    }
    __syncthreads();

    // ---- prologue: L0(0) with h0(-1)=0 (x-term only) -> h0(0) ----
    {
        f32x4 accr = (f32x4){br0, br0, br0, br0};
        f32x4 accz = (f32x4){bz0, bz0, bz0, bz0};
        f32x4 accni = (f32x4){bni0, bni0, bni0, bni0};
        short8 axh = *(const short8*)&xA[0][0][xoff];
        short8 axl = *(const short8*)&xA[0][1][xoff];
        accr = MFMA16(axh, W0x[0], accr);
        accr = MFMA16(axl, W0x[0], accr);
        accz = MFMA16(axh, W0x[1], accz);
        accz = MFMA16(axl, W0x[1], accz);
        accni = MFMA16(axh, W0x[2], accni);
        accni = MFMA16(axl, W0x[2], accni);
        #pragma unroll
        for (int rg = 0; rg < 4; rg++) {
            float r = sigm(accr[rg]);
            float z = sigm(accz[rg]);
            float nc = tanh_f(accni[rg] + r * bnh0);
            float hnew = nc - z * nc;     // h_old = 0
            h0reg[rg] = hnew;
            int off = (quad * 4 + rg) * 136 + j;
            unsigned short hh_ = f2bf_t(hnew);
            h0A[0][0][off] = hh_;
            h0A[0][1][off] = f2bf_t(hnew - bf2f(hh_));
        }
    }
    __syncthreads();

#define GRU_IT(B, DO_L0, XT, LAST)                                                \
{                                                                                 \
    float xv = 0.f;                                                               \
    if ((XT) >= 0 && stager) xv = xrow[XT];   /* issue early, write late */       \
    f32x4 accr0 = (f32x4){br0, br0, br0, br0};                                    \
    f32x4 accz0 = (f32x4){bz0, bz0, bz0, bz0};                                    \
    f32x4 accni0 = (f32x4){bni0, bni0, bni0, bni0};                               \
    f32x4 accnh0 = (f32x4){bnh0, bnh0, bnh0, bnh0};                               \
    f32x4 accr1 = (f32x4){br1, br1, br1, br1};                                    \
    f32x4 accz1 = (f32x4){bz1, bz1, bz1, bz1};                                    \
    f32x4 accni1 = (f32x4){bni1, bni1, bni1, bni1};                               \
    f32x4 accnh1 = (f32x4){bnh1, bnh1, bnh1, bnh1};                               \
    if (DO_L0) {                                                                  \
        short8 axh = *(const short8*)&xA[(B) ^ 1][0][xoff];                       \
        short8 axl = *(const short8*)&xA[(B) ^ 1][1][xoff];                       \
        accr0 = MFMA16(axh, W0x[0], accr0);                                       \
        accr0 = MFMA16(axl, W0x[0], accr0);                                       \
        accz0 = MFMA16(axh, W0x[1], accz0);                                       \
        accz0 = MFMA16(axl, W0x[1], accz0);                                       \
        accni0 = MFMA16(axh, W0x[2], accni0);                                     \
        accni0 = MFMA16(axl, W0x[2], accni0);                                     \
    }                                                                             \
    _Pragma("unroll")                                                             \
    for (int c = 0; c < 4; c++) {                                                 \
        short8 a0h = *(const short8*)&h0A[B][0][aoff + c * 32];                   \
        short8 a0l = *(const short8*)&h0A[B][1][aoff + c * 32];                   \
        if (DO_L0) {                                                              \
            accr0 = MFMA16(a0h, W0h[0][c], accr0);                                \
            accr0 = MFMA16(a0l, W0h[0][c], accr0);                                \
            accz0 = MFMA16(a0h, W0h[1][c], accz0);                                \
            accz0 = MFMA16(a0l, W0h[1][c], accz0);                                \
            accnh0 = MFMA16(a0h, W0h[2][c], accnh0);                              \
            accnh0 = MFMA16(a0l, W0h[2][c], accnh0);                              \
        }                                                                         \
        accr1 = MFMA16(a0h, W1x[0][c], accr1);                                    \
        accr1 = MFMA16(a0l, W1x[0][c], accr1);                                    \
        accz1 = MFMA16(a0h, W1x[1][c], accz1);                                    \
        accz1 = MFMA16(a0l, W1x[1][c], accz1);                                    \
        accni1 = MFMA16(a0h, W1x[2][c], accni1);                                  \
        accni1 = MFMA16(a0l, W1x[2][c], accni1);                                  \
        short8 a1h = *(const short8*)&h1A[(B) ^ 1][0][aoff + c * 32];             \
        short8 a1l = *(const short8*)&h1A[(B) ^ 1][1][aoff + c * 32];             \
        accr1 = MFMA16(a1h, W1h[0][c], accr1);                                    \
        accr1 = MFMA16(a1l, W1h[0][c], accr1);                                    \
        accz1 = MFMA16(a1h, W1h[1][c], accz1);                                    \
        accz1 = MFMA16(a1l, W1h[1][c], accz1);                                    \
        accnh1 = MFMA16(a1h, W1h[2][c], accnh1);                                  \
        accnh1 = MFMA16(a1l, W1h[2][c], accnh1);                                  \
    }                                                                             \
    if (DO_L0) {                                                                  \
        _Pragma("unroll")                                                         \
        for (int rg = 0; rg < 4; rg++) {                                          \
            float r = sigm(accr0[rg]);                                            \
            float z = sigm(accz0[rg]);                                            \
            float nc = tanh_f(accni0[rg] + r * accnh0[rg]);                       \
            float hnew = nc + z * (h0reg[rg] - nc);                               \
            h0reg[rg] = hnew;                                                     \
            int off = (quad * 4 + rg) * 136 + j;                                  \
            unsigned short hh_ = f2bf_t(hnew);                                    \
            h0A[(B) ^ 1][0][off] = hh_;                                           \
            h0A[(B) ^ 1][1][off] = f2bf_t(hnew - bf2f(hh_));                      \
        }                                                                         \
    }                                                                             \
    _Pragma("unroll")                                                             \
    for (int rg = 0; rg < 4; rg++) {                                              \
        float r = sigm(accr1[rg]);                                                \
        float z = sigm(accz1[rg]);                                                \
        float nc = tanh_f(accni1[rg] + r * accnh1[rg]);                           \
        float hnew = nc + z * (h1reg[rg] - nc);                                   \
        h1reg[rg] = hnew;                                                         \
        if (LAST) {                                                               \
            xh[(size_t)(n0 + quad * 4 + rg) * HDIM + j] = hnew;                   \
        } else {                                                                  \
            int off = (quad * 4 + rg) * 136 + j;                                  \
            unsigned short hh_ = f2bf_t(hnew);                                    \
            h1A[B][0][off] = hh_;                                                 \
            h1A[B][1][off] = f2bf_t(hnew - bf2f(hh_));                            \
        }                                                                         \
    }                                                                             \
    if ((XT) >= 0 && stager) {                                                    \
        unsigned short hh_ = f2bf_t(xv);                                          \
        xA[B][0][soff] = hh_;                                                     \
        xA[B][1][soff] = f2bf_t(xv - bf2f(hh_));                                  \
    }                                                                             \
    if (!(LAST)) __syncthreads();                                                 \
}

    // iters 0..61 (x-loads i+2 = 2..63 all valid)
    for (int i = 0; i < 62; i += 2) {
        GRU_IT(0, true, i + 2, false)
        GRU_IT(1, true, i + 3, false)
    }
    GRU_IT(0, true, -1, false)    // iter 62: L0(63)+L1(62), no more x
    GRU_IT(1, false, -1, true)    // iter 63: L1(63) only -> xh
#undef GRU_IT
}

// ---------------------------------------------------------------------------
// den / s2ct (unchanged)
// ---------------------------------------------------------------------------
__global__ __launch_bounds__(256) void den_atomic(const float* __restrict__ cm,
        const float* __restrict__ mv, float* __restrict__ den)
{
    int c = blockIdx.x * 64 + (threadIdx.x & 63);
    int rg = threadIdx.x >> 6;
    int nbase = blockIdx.y * 128;
    float acc = 0.f;
    for (int i = 0; i < 32; i++) {
        int n = nbase + rg + (i << 2);
        acc += cm[(size_t)n * CDIM + c] * mv[n];
    }
    __shared__ float red[4][64];
    red[rg][threadIdx.x & 63] = acc;
    __syncthreads();
    if (rg == 0)
        atomicAdd(&den[c], red[0][threadIdx.x] + red[1][threadIdx.x] +
                           red[2][threadIdx.x] + red[3][threadIdx.x]);
}

__global__ __launch_bounds__(256) void s2ct_trans(const float* __restrict__ cm,
        const float* __restrict__ mv, const float* __restrict__ den,
        float* __restrict__ s2cT)
{
    __shared__ float tile[64][65];
    __shared__ float mvs[64];
    const int tid = threadIdx.x;
    const int n0 = blockIdx.x << 6;
    const int c0 = blockIdx.y << 6;
    const int lc = tid & 63, lr = tid >> 6;
    if (tid < 64) mvs[tid] = mv[n0 + tid];
    #pragma unroll
    for (int i = 0; i < 16; i++) {
        int n = lr + (i << 2);
        tile[n][lc] = cm[(size_t)(n0 + n) * CDIM + c0 + lc];
    }
    __syncthreads();
    #pragma unroll
    for (int i = 0; i < 16; i++) {
        int c = lr + (i << 2);
        float m = tile[lc][c];
        float d = den[c0 + c];
        s2cT[(size_t)(c0 + c) * NR + n0 + lc] = (m * mvs[lc]) / (d * m + 1.f);
    }
}

// ---------------------------------------------------------------------------
// Small helpers
// ---------------------------------------------------------------------------
__global__ void row_norm(const float* __restrict__ a, float* __restrict__ out)
{
    int r = blockIdx.x;
    float acc = 0.f;
    for (int h = threadIdx.x; h < HDIM; h += 64) {
        float v = a[(size_t)r * HDIM + h];
        acc += v * v;
    }
    for (int o = 32; o > 0; o >>= 1) acc += __shfl_down(acc, o);
    if (threadIdx.x == 0) out[r] = sqrtf(acc);
}

__global__ void row_nonzero(const float* __restrict__ a, float* __restrict__ out)
{
    int r = blockIdx.x;
    float acc = 0.f;
    for (int h = threadIdx.x; h < HDIM; h += 64) acc += a[(size_t)r * HDIM + h];
    for (int o = 32; o > 0; o >>= 1) acc += __shfl_down(acc, o);
    if (threadIdx.x == 0) out[r] = (acc != 0.f) ? 1.f : 0.f;
}

__global__ void row_norm_nz(const float* __restrict__ a, float* __restrict__ nrm,
                            float* __restrict__ nz)
{
    int r = blockIdx.x;
    float acc = 0.f, s = 0.f;
    for (int h = threadIdx.x; h < HDIM; h += 64) {
        float v = a[(size_t)r * HDIM + h];
        acc += v * v;
        s += v;
    }
    for (int o = 32; o > 0; o >>= 1) { acc += __shfl_down(acc, o); s += __shfl_down(s, o); }
    if (threadIdx.x == 0) { nrm[r] = sqrtf(acc); nz[r] = (s != 0.f) ? 1.f : 0.f; }
}

// cos_softmax_row: wave-shuffle reductions, __expf + rcp.
__global__ __launch_bounds__(256) void cos_softmax_row(float* __restrict__ data, int N,
        const float* __restrict__ rn, const float* __restrict__ cn,
        const float* __restrict__ vmask)
{
    int row = blockIdx.x;
    float* d = data + (size_t)row * N;
    int tid = threadIdx.x;
    int wv = tid >> 6, lane = tid & 63;
    __shared__ float red[8];
    float rnv = rn ? rn[row] : 0.f;
    float mx = -INFINITY;
    for (int j = tid; j < N; j += 256) {
        float v = d[j];
        if (cn) v = v * __builtin_amdgcn_rcpf(fmaxf(rnv * cn[j], 1e-12f));
        if (vmask && vmask[j] == 0.f) v = -1e9f;
        d[j] = v;
        mx = fmaxf(mx, v);
    }
    #pragma unroll
    for (int m = 1; m < 64; m <<= 1) mx = fmaxf(mx, __shfl_xor(mx, m));
    if (lane == 0) red[wv] = mx;
    __syncthreads();
    float M = fmaxf(fmaxf(red[0], red[1]), fmaxf(red[2], red[3]));
    float sum = 0.f;
    for (int j = tid; j < N; j += 256) {
        float e = __expf(d[j] - M);
        d[j] = e;
        sum += e;
    }
    #pragma unroll
    for (int m = 1; m < 64; m <<= 1) sum += __shfl_xor(sum, m);
    if (lane == 0) red[4 + wv] = sum;
    __syncthreads();
    float inv = __builtin_amdgcn_rcpf(red[4] + red[5] + red[6] + red[7]);
    for (int j = tid; j < N; j += 256) {
        float v = d[j] * inv;
        if (vmask) v *= vmask[j];
        d[j] = v;
    }
}

// hh_scatter: one block per row i; loads hsh[i,:] once, scatters its K
// neighbors; threads 0..K-1 also handle the colsum scatter (fused).
__global__ void hh_scatter(const float* __restrict__ vals, const int* __restrict__ idxs,
                           const float* __restrict__ hsh, float* __restrict__ hh,
                           float* __restrict__ colsum)
{
    int i = blockIdx.x;
    int t = threadIdx.x;
    float hv = hsh[(size_t)i * HDIM + t];
    #pragma unroll
    for (int k = 0; k < KTOP; k++) {
        int p = i * KTOP + k;
        int jj = idxs[p];
        float v = vals[p];
        atomicAdd(&hh[(size_t)jj * HDIM + t], v * hv);
    }
    if (t < KTOP) {
        int p = i * KTOP + t;
        atomicAdd(&colsum[idxs[p]], vals[p]);
    }
}

__global__ void hh_diag(const float* __restrict__ colsum, const float* __restrict__ diag,
                        const float* __restrict__ hsh, float* __restrict__ hh)
{
    int idx = blockIdx.x * 256 + threadIdx.x;
    int j = idx >> 7;
    if (colsum[j] != 0.f) hh[idx] += diag[j] * hsh[idx];
}

// ---------------------------------------------------------------------------
// host-side helpers
// ---------------------------------------------------------------------------
static inline void mg(hipStream_t s, const float* A, const unsigned short* Bh,
                      const unsigned short* Bl, const float* bias, float* C,
                      int M, int N, int K, int z, int flags,
                      const float* aux = nullptr, float* sub = nullptr,
                      const unsigned short* Ah = nullptr, const unsigned short* Al = nullptr,
                      const float* wout = nullptr, const float* bout = nullptr,
                      float* hout = nullptr)
{
    MG g{A, Bh, Bl, bias, C, aux, sub, Ah, Al,
         nullptr, nullptr, nullptr, nullptr, wout, bout, hout,
         N, K, K / z, flags | (z > 1 ? 4 : 0) | (Ah ? 16 : 0), 0};
    mfma_gemm<<<dim3(N / 64, M / 64, z), 256, 0, s>>>(g);
}
// dual-output: z-dim selects output set; same A, full K both.
static inline void mg_dual(hipStream_t s, const float* A,
                           const unsigned short* Bh, const unsigned short* Bl,
                           const float* bias, float* C, int flags1,
                           const unsigned short* Bh2, const unsigned short* Bl2,
                           const float* bias2, float* C2, int flags2,
                           int M, int N, int K,
                           const float* aux, float* sub,
                           const float* wout, const float* bout, float* hout)
{
    MG g{A, Bh, Bl, bias, C, aux, sub, nullptr, nullptr,
         Bh2, Bl2, bias2, C2, wout, bout, hout,
         N, K, K, flags1 | 32, flags2};
    mfma_gemm<<<dim3(N / 64, M / 64, 2), 256, 0, s>>>(g);
}
static inline void pbt(hipStream_t s, const float* src, unsigned short* hi,
                       unsigned short* lo, int N, int K)
{
    int total = (N / 16) * (K / 32) * 64;
    pack_bt<<<(total + 255) / 256, 256, 0, s>>>(src, hi, lo, K, total);
}
static inline void pboth(hipStream_t s, const float* src,
                         unsigned short* bth, unsigned short* btl,
                         unsigned short* knh, unsigned short* knl, int N)
{
    int totBT = (N / 16) * 4 * 64;
    int totKN = 8 * (N / 32) * 64;
    int tot = totBT > totKN ? totBT : totKN;
    pack_both<<<(tot + 255) / 256, 256, 0, s>>>(src, bth, btl, knh, knl, N, totKN);
}

extern "C" void kernel_launch(void* const* d_in, const int* in_sizes, int n_in,
                              void* d_out, int out_size, void* d_ws, size_t ws_size,
                              hipStream_t stream)
{
    (void)in_sizes; (void)n_in; (void)out_size; (void)ws_size;
    const float* x    = (const float*)d_in[0];
    const float* cm   = (const float*)d_in[1];
    const float* mv   = (const float*)d_in[2];
    const float* wih0 = (const float*)d_in[3];
    const float* whh0 = (const float*)d_in[4];
    const float* bih0 = (const float*)d_in[5];
    const float* bhh0 = (const float*)d_in[6];
    const float* wih1 = (const float*)d_in[7];
    const float* whh1 = (const float*)d_in[8];
    const float* bih1 = (const float*)d_in[9];
    const float* bhh1 = (const float*)d_in[10];
    const float* w_ps = (const float*)d_in[11];
    const float* b_ps = (const float*)d_in[12];
    const float* w_hs = (const float*)d_in[13];
    const float* b_hs = (const float*)d_in[14];
    const float* w_ps_fore = (const float*)d_in[15];
    const float* b_ps_fore = (const float*)d_in[16];
    const float* w_hs_fore = (const float*)d_in[17];
    const float* b_hs_fore = (const float*)d_in[18];
    const float* w_ps_back = (const float*)d_in[19];
    const float* b_ps_back = (const float*)d_in[20];
    const float* w_hs_back = (const float*)d_in[21];
    const float* b_hs_back = (const float*)d_in[22];
    const float* w_indi = (const float*)d_in[23];
    const float* b_indi = (const float*)d_in[24];
    const float* w_out  = (const float*)d_in[25];
    const float* b_out  = (const float*)d_in[26];
    float* out = (float*)d_out;

    // ---- workspace layout (floats) ----
    float* ws = (float*)d_ws;
    float* BIG = ws;                         // 16,777,216 (overlaid)
    // zero cluster (ONE memset covers all of it):
    float* zero0 = ws + 16777216;
    float* den      = zero0;                 // 512
    float* hidden   = den + 512;             // 65536
    float* hidden2  = hidden + 65536;        // 65536
    float* colsum   = hidden2 + 65536;       // 4096
    float* p0       = colsum + 4096;         // 524288
    float* hidden_h = p0 + 524288;           // 524288
    const size_t ZERO_FLOATS = 512 + 65536 + 65536 + 4096 + 524288 + 524288;
    // live buffers:
    float* h1 = hidden_h + 524288;           // x_hidden
    float* v1 = h1 + 524288;                 // 512
    float* xnorm = v1 + 512;                 // 4096
    float* h2n = xnorm + 4096;               // 512
    float* p_shared = h2n + 512;             // 524288
    float* p_back = p_shared + 524288;       // 524288
    float* h_shared = p_back + 524288;       // 524288
    float* hn = h_shared + 524288;           // 4096
    float* diagv = hn + 4096;                // 4096
    float* tvals = diagv + 4096;             // 40960
    int*   tidx = (int*)(tvals + 40960);     // 40960 ints
    float* v2 = (float*)(tidx + 40960);      // 4096
    float* hhn = v2 + 4096;                  // 4096
    float* hsi0 = hhn + 4096;                // 524288
    float* h_si = hsi0 + 524288;             // 524288
    float* h_back = h_si + 524288;           // 524288
    float* indi = h_back + 524288;           // 524288
    float* extra = indi + 524288;            // 131072

    // GRU-phase overlays inside BIG:
    unsigned short* wih0p = (unsigned short*)(BIG + 5242880);
    unsigned short* whh0p = wih0p + 12288;
    unsigned short* wih1p = whh0p + 49152;
    unsigned short* whh1p = wih1p + 49152;
    // concept-phase overlays inside BIG:
    float* s2cT = BIG;
    float* L    = BIG + 2097152;
    float* c2s  = BIG + 4194304;
    unsigned short* PB = (unsigned short*)(BIG + 6291456);
    unsigned short* pbt_xh_hi = PB;
    unsigned short* pbt_xh_lo = pbt_xh_hi + 524288;
    unsigned short* pkn_xh_hi = pbt_xh_lo + 524288;
    unsigned short* pkn_xh_lo = pkn_xh_hi + 524288;
    unsigned short* pbt_h2_hi = pkn_xh_lo + 524288;
    unsigned short* pbt_h2_lo = pbt_h2_hi + 65536;
    unsigned short* pkn_h2_hi = pbt_h2_lo + 65536;
    unsigned short* pkn_h2_lo = pkn_h2_hi + 65536;
    unsigned short* wps_hi  = pkn_h2_lo + 65536;
    unsigned short* wps_lo  = wps_hi + 16384;
    unsigned short* wpsb_hi = wps_lo + 16384;
    unsigned short* wpsb_lo = wpsb_hi + 16384;
    unsigned short* wpsf_hi = wpsb_lo + 16384;
    unsigned short* wpsf_lo = wpsf_hi + 16384;
    unsigned short* pbt_hsh_hi = (unsigned short*)p0;      // p0 dead after p_shared GEMM
    unsigned short* pbt_hsh_lo = pbt_hsh_hi + 524288;
    unsigned short* pbt_hh_hi = (unsigned short*)indi;     // indi written after flash
    unsigned short* pbt_hh_lo = pbt_hh_hi + 524288;
    unsigned short* pkn_hh_hi = (unsigned short*)hsi0;     // hsi0 written after flash
    unsigned short* pkn_hh_lo = pkn_hh_hi + 524288;
    // flash-partial overlays inside BIG (dead after scan_topk):
    float* part_O = BIG;                     // 4,194,304 floats
    float* part_m = BIG + 4194304;           // 32,768
    float* part_l = BIG + 4227072;           // 32,768
    unsigned short* EX = (unsigned short*)extra;
    unsigned short* whs_hi  = EX;            unsigned short* whs_lo  = EX + 16384;
    unsigned short* whsb_hi = EX + 32768;    unsigned short* whsb_lo = EX + 49152;
    unsigned short* whsf_hi = EX + 65536;    unsigned short* whsf_lo = EX + 81920;
    unsigned short* wind_hi = EX + 98304;    unsigned short* wind_lo = EX + 114688;

    // ---- one consolidated memset for all zero-init buffers + head output ----
    hipMemsetAsync(zero0, 0, ZERO_FLOATS * sizeof(float), stream);
    hipMemsetAsync(out, 0, NR * sizeof(float), stream);

    // ================= Phase A: MFMA 2-layer GRU =================
    pack_wb<<<6, 256, 0, stream>>>(wih0, wih0p, DDIM, 1);
    pack_wb<<<24, 256, 0, stream>>>(whh0, whh0p, HDIM, 4);
    pack_wb<<<24, 256, 0, stream>>>(wih1, wih1p, HDIM, 4);
    pack_wb<<<24, 256, 0, stream>>>(whh1, whh1p, HDIM, 4);
    {
        W7 w7;
        w7.src[0] = w_ps;      w7.hi[0] = wps_hi;  w7.lo[0] = wps_lo;
        w7.src[1] = w_ps_back; w7.hi[1] = wpsb_hi; w7.lo[1] = wpsb_lo;
        w7.src[2] = w_ps_fore; w7.hi[2] = wpsf_hi; w7.lo[2] = wpsf_lo;
        w7.src[3] = w_hs;      w7.hi[3] = whs_hi;  w7.lo[3] = whs_lo;
        w7.src[4] = w_hs_back; w7.hi[4] = whsb_hi; w7.lo[4] = whsb_lo;
        w7.src[5] = w_hs_fore; w7.hi[5] = whsf_hi; w7.lo[5] = whsf_lo;
        w7.src[6] = w_indi;    w7.hi[6] = wind_hi; w7.lo[6] = wind_lo;
        pack_w7<<<56, 256, 0, stream>>>(w7);
    }
    gru_mfma<<<NR / 16, 512, 0, stream>>>(x, wih0p, whh0p, wih1p, whh1p,
                                          bih0, bhh0, bih1, bhh1, h1);
    float* x_hidden = h1;

    // ================= Phase B: predefined-concept branch =================
    den_atomic<<<dim3(CDIM / 64, 32), 256, 0, stream>>>(cm, mv, den);
    s2ct_trans<<<dim3(NR / 64, CDIM / 64), 256, 0, stream>>>(cm, mv, den, s2cT);
    pboth(stream, x_hidden, pbt_xh_hi, pbt_xh_lo, pkn_xh_hi, pkn_xh_lo, NR);
    mg(stream, s2cT, pkn_xh_hi, pkn_xh_lo, nullptr, hidden, CDIM, HDIM, NR, 16, 0);
    row_nonzero<<<CDIM, 64, 0, stream>>>(hidden, v1);
    mg(stream, hidden, pbt_xh_hi, pbt_xh_lo, nullptr, L, CDIM, NR, HDIM, 1, 0);
    cos_softmax_row<<<CDIM, 256, 0, stream>>>(L, NR, nullptr, nullptr, nullptr);
    mg(stream, L, pkn_xh_hi, pkn_xh_lo, nullptr, hidden2, CDIM, HDIM, NR, 16, 0);
    row_norm<<<NR, 64, 0, stream>>>(x_hidden, xnorm);
    row_norm<<<CDIM, 64, 0, stream>>>(hidden2, h2n);
    pboth(stream, hidden2, pbt_h2_hi, pbt_h2_lo, pkn_h2_hi, pkn_h2_lo, CDIM);
    // packed-A: x_hidden already packed as pbt_xh
    mg(stream, x_hidden, pbt_h2_hi, pbt_h2_lo, nullptr, c2s, NR, CDIM, HDIM, 1, 0,
       nullptr, nullptr, pbt_xh_hi, pbt_xh_lo);
    cos_softmax_row<<<NR, 256, 0, stream>>>(c2s, CDIM, xnorm, h2n, v1);
    mg(stream, c2s, pkn_h2_hi, pkn_h2_lo, nullptr, p0, NR, HDIM, CDIM, 4, 0);
    mg(stream, p0, wps_hi, wps_lo, b_ps, p_shared, NR, HDIM, HDIM, 1, 1);
    // DUAL: z=0 -> p_back (+fused h_shared = x_hidden - p_back)
    //       z=1 -> out_ps head-accumulated into out (no store)
    mg_dual(stream, p_shared,
            wpsb_hi, wpsb_lo, b_ps_back, p_back, 1 | 8,
            wpsf_hi, wpsf_lo, b_ps_fore, nullptr, 1 | 2 | 64 | 128,
            NR, HDIM, HDIM, x_hidden, h_shared, w_out, b_out, out);

    // ================= Phase C: hidden-concept branch =================
    row_norm<<<NR, 64, 0, stream>>>(h_shared, hn);
    pbt(stream, h_shared, pbt_hsh_hi, pbt_hsh_lo, NR, HDIM);
    // packed-A: the 4096-block NxN GEMM reuses pbt_hsh for BOTH operands
    mg(stream, h_shared, pbt_hsh_hi, pbt_hsh_lo, nullptr, BIG, NR, NR, HDIM, 1, 0,
       nullptr, nullptr, pbt_hsh_hi, pbt_hsh_lo);
    scan_topk<<<NR, 256, 0, stream>>>(BIG, hn, diagv, tvals, tidx);
    hh_scatter<<<NR, HDIM, 0, stream>>>(tvals, tidx, h_shared, hidden_h, colsum);
    hh_diag<<<2048, 256, 0, stream>>>(colsum, diagv, h_shared, hidden_h);
    row_norm_nz<<<NR, 64, 0, stream>>>(hidden_h, hhn, v2);
    pboth(stream, hidden_h, pbt_hh_hi, pbt_hh_lo, pkn_hh_hi, pkn_hh_lo, NR);
    hc2s_flash<<<dim3(NR / 64, 4), 512, 0, stream>>>(h_shared, hn, hhn, v2,
                                                     pbt_hh_hi, pbt_hh_lo,
                                                     pkn_hh_hi, pkn_hh_lo,
                                                     part_O, part_m, part_l);
    hc2s_merge<<<NR / 16, 256, 0, stream>>>(part_O, part_m, part_l, hsi0);
    mg(stream, hsi0, whs_hi, whs_lo, b_hs, h_si, NR, HDIM, HDIM, 1, 1);
    // DUAL: z=0 -> h_back (+fused indi = h_shared - h_back)
    //       z=1 -> out_hs head-accumulated into out (no store)
    mg_dual(stream, h_si,
            whsb_hi, whsb_lo, b_hs_back, h_back, 1 | 8,
            whsf_hi, whsf_lo, b_hs_fore, nullptr, 1 | 2 | 64 | 128,
            NR, HDIM, HDIM, h_shared, indi, w_out, b_out, out);

    // ================= Phase D: individual branch + head (fused) =================
    // out_indi head-accumulated; bn==0 blocks add b_out once per row.
    mg(stream, indi, wind_hi, wind_lo, b_indi, nullptr, NR, HDIM, HDIM, 1,
       1 | 2 | 64 | 128 | 256, nullptr, nullptr, nullptr, nullptr,
       w_out, b_out, out);
}

// Round 6
// 669.575 us; speedup vs baseline: 1.4164x; 1.0412x over previous
//
#include <hip/hip_runtime.h>
#include <cstddef>

// Problem dims
#define NR 4096      // batch
#define CDIM 512     // concepts
#define HDIM 128     // hidden
#define TSTEPS 64
#define DDIM 20
#define KTOP 10

typedef __attribute__((ext_vector_type(8))) short short8;
typedef __attribute__((ext_vector_type(4))) float f32x4;

__device__ __forceinline__ unsigned short f2bf(float f) {
    union { float f; unsigned u; } x; x.f = f;
    unsigned r = (x.u + 0x7fffu + ((x.u >> 16) & 1u)) >> 16;
    return (unsigned short)r;
}
// truncating bf16 (lo plane captures the residual; hi+lo exact to ~2^-17)
__device__ __forceinline__ unsigned short f2bf_t(float f) {
    union { float f; unsigned u; } x; x.f = f;
    return (unsigned short)(x.u >> 16);
}
__device__ __forceinline__ float bf2f(unsigned short h) {
    union { unsigned u; float f; } x; x.u = ((unsigned)h) << 16;
    return x.f;
}
// inf-safe, clamp-free activations (v_exp + v_rcp only)
__device__ __forceinline__ float sigm(float v) {
    return __builtin_amdgcn_rcpf(1.f + __expf(-v));
}
__device__ __forceinline__ float tanh_f(float v) {
    return 1.f - 2.f * __builtin_amdgcn_rcpf(1.f + __expf(2.f * v));
}

#define MFMA16(a, b, c) __builtin_amdgcn_mfma_f32_16x16x32_bf16(a, b, c, 0, 0, 0)

// ---------------------------------------------------------------------------
// Generic MFMA GEMM. flags: 1 bias (split-K: z==0 chunk only), 2 lrelu,
// 4 atomicAdd (split-K), 8 fused subtract: sub = aux - C, 16 pre-packed A,
// 32 dual-output (blockIdx.z selects output set), 64 head-accumulate,
// 128 skip C store, 256 add bout[0] once per row (with 64, bn==0).
// ---------------------------------------------------------------------------
struct MG {
    const float* A; const unsigned short* Bh; const unsigned short* Bl;
    const float* bias; float* C; const float* aux; float* sub;
    const unsigned short* Ah; const unsigned short* Al;
    const unsigned short* Bh2; const unsigned short* Bl2;
    const float* bias2; float* C2;
    const float* wout; const float* bout; float* hout;
    int N, K, kchunk, flags, flags2;
};

__global__ __launch_bounds__(256) void mfma_gemm(MG g)
{
    const int tid = threadIdx.x;
    const int w = tid >> 6, lane = tid & 63, quad = lane >> 4, lm = lane & 15;
    const int bm = (blockIdx.y << 6) + (w << 4);
    const int bn = blockIdx.x << 6;
    const int NC = g.K >> 5;
    int flags = g.flags;
    const unsigned short* Bh = g.Bh;
    const unsigned short* Bl = g.Bl;
    const float* bias = g.bias;
    float* C = g.C;
    int zk = blockIdx.z;
    if (g.flags & 32) {
        if (blockIdx.z) { Bh = g.Bh2; Bl = g.Bl2; bias = g.bias2; C = g.C2; flags = g.flags2; }
        zk = 0;
    }
    const int c0 = (zk * g.kchunk) >> 5;
    const int c1 = c0 + (g.kchunk >> 5);
    const float* arow = g.A + (size_t)(bm + lm) * g.K;
    const int packA = g.flags & 16;
    f32x4 acc[4];
    #pragma unroll
    for (int t = 0; t < 4; t++) acc[t] = (f32x4){0.f, 0.f, 0.f, 0.f};

    for (int c = c0; c < c1; c++) {
        short8 ah, al;
        if (packA) {
            size_t aidx = ((size_t)((bm >> 4) * NC + c) * 64 + lane) * 8;
            ah = *(const short8*)(g.Ah + aidx);
            al = *(const short8*)(g.Al + aidx);
        } else {
            const float* ap = arow + (c << 5) + (quad << 3);
            float4 a0 = *(const float4*)ap;
            float4 a1 = *(const float4*)(ap + 4);
            #pragma unroll
            for (int jj = 0; jj < 4; jj++) {
                float f = (&a0.x)[jj];
                unsigned short h = f2bf(f);
                ah[jj] = h; al[jj] = f2bf_t(f - bf2f(h));
                f = (&a1.x)[jj];
                h = f2bf(f);
                ah[4 + jj] = h; al[4 + jj] = f2bf_t(f - bf2f(h));
            }
        }
        #pragma unroll
        for (int t = 0; t < 4; t++) {
            size_t bidx = ((size_t)(((bn >> 4) + t) * NC + c) * 64 + lane) * 8;
            short8 bh = *(const short8*)(Bh + bidx);
            short8 bl = *(const short8*)(Bl + bidx);
            acc[t] = MFMA16(ah, bh, acc[t]);
            acc[t] = MFMA16(ah, bl, acc[t]);
            acc[t] = MFMA16(al, bh, acc[t]);
        }
    }
    float rsum[4] = {0.f, 0.f, 0.f, 0.f};
    #pragma unroll
    for (int t = 0; t < 4; t++) {
        #pragma unroll
        for (int rg = 0; rg < 4; rg++) {
            int row = bm + (quad << 2) + rg;
            int col = bn + (t << 4) + lm;
            float v = acc[t][rg];
            if ((flags & 1) && (!(flags & 4) || zk == 0)) v += bias[col];
            if (flags & 2) v = v > 0.f ? v : 0.01f * v;
            if (flags & 64) rsum[rg] += v * g.wout[col];
            if (!(flags & 128)) {
                if (flags & 4) atomicAdd(&C[(size_t)row * g.N + col], v);
                else C[(size_t)row * g.N + col] = v;
            }
            if (flags & 8)
                g.sub[(size_t)row * g.N + col] = g.aux[(size_t)row * g.N + col] - v;
        }
    }
    if (flags & 64) {
        #pragma unroll
        for (int rg = 0; rg < 4; rg++) {
            #pragma unroll
            for (int d = 1; d < 16; d <<= 1) rsum[rg] += __shfl_xor(rsum[rg], d);
        }
        if (lm == 0) {
            #pragma unroll
            for (int rg = 0; rg < 4; rg++) {
                float s = rsum[rg];
                if ((flags & 256) && bn == 0) s += g.bout[0];
                atomicAdd(&g.hout[bm + (quad << 2) + rg], s);
            }
        }
    }
}

// B-pack from [N,K] rows; layout [nt][c][lane][8], hi/lo planes.
__global__ void pack_bt(const float* __restrict__ src, unsigned short* __restrict__ hi,
                        unsigned short* __restrict__ lo, int K, int total)
{
    int idx = blockIdx.x * 256 + threadIdx.x;
    if (idx >= total) return;
    int NC = K >> 5;
    int lane = idx & 63;
    int c = (idx >> 6) % NC;
    int t = idx / (NC * 64);
    int n = (t << 4) + (lane & 15);
    int kb = (c << 5) + ((lane >> 4) << 3);
    #pragma unroll
    for (int j = 0; j < 8; j++) {
        float f = src[(size_t)n * K + kb + j];
        unsigned short h = f2bf(f);
        hi[(size_t)idx * 8 + j] = h;
        lo[(size_t)idx * 8 + j] = f2bf_t(f - bf2f(h));
    }
}

// Combined pack (K = HDIM = 128 only): BT (B[n][k]) + KN (B[k][n]) in one pass.
__global__ void pack_both(const float* __restrict__ src,
                          unsigned short* __restrict__ bth, unsigned short* __restrict__ btl,
                          unsigned short* __restrict__ knh, unsigned short* __restrict__ knl,
                          int N, int total_kn)
{
    int idx = blockIdx.x * 256 + threadIdx.x;
    int lane = idx & 63;
    int totBT = (N >> 4) * 256;
    if (idx < totBT) {
        int c = (idx >> 6) & 3;
        int t = idx >> 8;
        int n = (t << 4) + (lane & 15);
        int kb = (c << 5) + ((lane >> 4) << 3);
        #pragma unroll
        for (int j = 0; j < 8; j++) {
            float f = src[(size_t)n * HDIM + kb + j];
            unsigned short h = f2bf(f);
            bth[(size_t)idx * 8 + j] = h;
            btl[(size_t)idx * 8 + j] = f2bf_t(f - bf2f(h));
        }
    }
    if (idx < total_kn) {
        int NC = N >> 5;
        int c = (idx >> 6) % NC;
        int t = idx / (NC * 64);
        int n = (t << 4) + (lane & 15);
        int kb = (c << 5) + ((lane >> 4) << 3);
        #pragma unroll
        for (int j = 0; j < 8; j++) {
            float f = src[(size_t)(kb + j) * HDIM + n];
            unsigned short h = f2bf(f);
            knh[(size_t)idx * 8 + j] = h;
            knl[(size_t)idx * 8 + j] = f2bf_t(f - bf2f(h));
        }
    }
}

// ---------------------------------------------------------------------------
// pack_all: ALL weight packing in one launch.
// [0,1536): wih0 (K=20 pad to 32); next 3x6144: whh0/wih1/whh1 (K=128);
// last 7*2048: the seven [128,128] head matrices (hi/lo planes).
// ---------------------------------------------------------------------------
struct PAll {
    const float* wb_src[4];
    unsigned short* wb_dst[4];
    const float* w7_src[7];
    unsigned short* w7_hi[7];
    unsigned short* w7_lo[7];
};
__global__ void pack_all(PAll p)
{
    int idx = blockIdx.x * 256 + threadIdx.x;
    const int WB_END = 1536 + 3 * 6144;
    if (idx < WB_END) {
        int m, base, nch, K;
        if (idx < 1536) { m = 0; base = 0; nch = 1; K = DDIM; }
        else {
            int q = (idx - 1536) / 6144;
            m = 1 + q;
            base = 1536 + q * 6144;
            nch = 4; K = HDIM;
        }
        int r = idx - base;
        int lane = r & 63;
        int c = (r >> 6) % nch;
        int t = r / (nch * 64);
        int n = t * 16 + (lane & 15);
        int kb = c * 32 + (lane >> 4) * 8;
        const float* W = p.wb_src[m];
        unsigned short* Wp = p.wb_dst[m];
        #pragma unroll
        for (int j = 0; j < 8; j++) {
            int k = kb + j;
            float f = (k < K) ? W[(size_t)n * K + k] : 0.f;
            Wp[(size_t)r * 8 + j] = f2bf(f);
        }
    } else {
        int q = idx - WB_END;
        if (q >= 7 * 2048) return;
        int m = q >> 11;
        int r = q & 2047;
        int lane = r & 63;
        int c = (r >> 6) & 3;
        int t = r >> 8;
        int n = (t << 4) + (lane & 15);
        int kb = (c << 5) + ((lane >> 4) << 3);
        const float* src = p.w7_src[m];
        unsigned short* hi = p.w7_hi[m];
        unsigned short* lo = p.w7_lo[m];
        #pragma unroll
        for (int j = 0; j < 8; j++) {
            float f = src[(size_t)n * HDIM + kb + j];
            unsigned short h = f2bf(f);
            hi[(size_t)r * 8 + j] = h;
            lo[(size_t)r * 8 + j] = f2bf_t(f - bf2f(h));
        }
    }
}

// ---------------------------------------------------------------------------
// scan_topk: wave-shuffle argmax reduce. Tie-break: value desc, index asc.
// ---------------------------------------------------------------------------
__global__ __launch_bounds__(256) void scan_topk(const float* __restrict__ S,
        const float* __restrict__ hn, float* __restrict__ diagv,
        float* __restrict__ tvals, int* __restrict__ tidx)
{
    int row = blockIdx.x;
    const float* d = S + (size_t)row * NR;
    int tid = threadIdx.x;
    int wv = tid >> 6, lane = tid & 63;
    float hi_ = hn[row];
    float lv[16];
    #pragma unroll
    for (int i = 0; i < 16; i++) {
        int j = tid + (i << 8);
        float v = d[j] / fmaxf(hi_ * hn[j], 1e-12f);
        if (j == row) { diagv[row] = v; v = 0.f; }
        lv[i] = v;
    }
    __shared__ float sv[4];
    __shared__ int si[4];
    for (int k = 0; k < KTOP; k++) {
        float bv = -INFINITY; int bi = 0x7fffffff;
        #pragma unroll
        for (int i = 0; i < 16; i++) {
            int j = tid + (i << 8);
            if (lv[i] > bv || (lv[i] == bv && j < bi)) { bv = lv[i]; bi = j; }
        }
        #pragma unroll
        for (int m = 1; m < 64; m <<= 1) {
            float ov = __shfl_xor(bv, m); int oi = __shfl_xor(bi, m);
            if (ov > bv || (ov == bv && oi < bi)) { bv = ov; bi = oi; }
        }
        if (lane == 0) { sv[wv] = bv; si[wv] = bi; }
        __syncthreads();
        bv = sv[0]; bi = si[0];
        #pragma unroll
        for (int w = 1; w < 4; w++) {
            float ov = sv[w]; int oi = si[w];
            if (ov > bv || (ov == bv && oi < bi)) { bv = ov; bi = oi; }
        }
        if (tid == 0) { tvals[row * KTOP + k] = bv; tidx[row * KTOP + k] = bi; }
        if ((bi & 255) == tid) lv[bi >> 8] = -INFINITY;
        __syncthreads();   // protect sv/si reuse next round
    }
}

// ---------------------------------------------------------------------------
// hc2s_flash: split-KV flash with wave-private online softmax (see R1 notes).
// ---------------------------------------------------------------------------
__global__ __launch_bounds__(512) void hc2s_flash(
    const float* __restrict__ hsh, const float* __restrict__ hn,
    const float* __restrict__ hhn, const float* __restrict__ v2,
    const unsigned short* __restrict__ Bh, const unsigned short* __restrict__ Bl,
    const unsigned short* __restrict__ Vh, const unsigned short* __restrict__ Vl,
    float* __restrict__ pO, float* __restrict__ pM, float* __restrict__ pL)
{
    __shared__ __attribute__((aligned(16))) unsigned short Ph[8][16 * 72];
    __shared__ __attribute__((aligned(16))) unsigned short Plo[8][16 * 72];

    const int tid = threadIdx.x;
    const int wv = tid >> 6, lane = tid & 63, quad = lane >> 4, lm = lane & 15;
    const int rg2 = wv >> 1;             // row-group within block (0..3)
    const int cc = wv & 1;               // col-chunk within block (0..1)
    const int bm = (blockIdx.x << 6) + (rg2 << 4);   // wave's 16 rows
    const int rgg = (blockIdx.x << 2) + rg2;         // global 16-row group
    const int pidx = (blockIdx.y << 1) + cc;         // partial index (0..7)
    const int jt0 = (blockIdx.y << 4) + (cc << 3);   // first 64-col tile

    short8 ahh[4], ahl[4];
    #pragma unroll
    for (int c = 0; c < 4; c++) {
        const float* ap = hsh + (size_t)(bm + lm) * HDIM + (c << 5) + (quad << 3);
        float4 a0 = *(const float4*)ap;
        float4 a1 = *(const float4*)(ap + 4);
        #pragma unroll
        for (int j = 0; j < 4; j++) {
            float f = (&a0.x)[j];
            unsigned short h = f2bf(f);
            ahh[c][j] = h; ahl[c][j] = f2bf_t(f - bf2f(h));
            f = (&a1.x)[j];
            h = f2bf(f);
            ahh[c][4 + j] = h; ahl[c][4 + j] = f2bf_t(f - bf2f(h));
        }
    }
    float hnr[4];
    #pragma unroll
    for (int rg = 0; rg < 4; rg++) hnr[rg] = hn[bm + (quad << 2) + rg];

    float m_old[4], l_old[4];
    #pragma unroll
    for (int rg = 0; rg < 4; rg++) { m_old[rg] = -INFINITY; l_old[rg] = 0.f; }
    f32x4 o[8];
    #pragma unroll
    for (int vt = 0; vt < 8; vt++) o[vt] = (f32x4){0.f, 0.f, 0.f, 0.f};

    const int pwr = lm * 72;
    for (int it = 0; it < 8; it++) {
        const int jt = jt0 + it;
        f32x4 s[4];
        #pragma unroll
        for (int tg = 0; tg < 4; tg++) {
            s[tg] = (f32x4){0.f, 0.f, 0.f, 0.f};
            #pragma unroll
            for (int c = 0; c < 4; c++) {
                size_t bidx = ((size_t)(((jt << 2) + tg) * 4 + c) * 64 + lane) * 8;
                short8 bh = *(const short8*)(Bh + bidx);
                short8 bl = *(const short8*)(Bl + bidx);
                s[tg] = MFMA16(ahh[c], bh, s[tg]);
                s[tg] = MFMA16(ahh[c], bl, s[tg]);
                s[tg] = MFMA16(ahl[c], bh, s[tg]);
            }
        }
        float sv[4][4];
        #pragma unroll
        for (int tg = 0; tg < 4; tg++) {
            int col = (jt << 6) + (tg << 4) + lm;
            float hc = hhn[col];
            float vm = v2[col];
            #pragma unroll
            for (int rg = 0; rg < 4; rg++) {
                float v = s[tg][rg] * __builtin_amdgcn_rcpf(fmaxf(hnr[rg] * hc, 1e-12f));
                sv[tg][rg] = (vm == 0.f) ? -1e9f : v;
            }
        }
        float m_new[4], alpha[4], tsum[4], pv[4][4];
        #pragma unroll
        for (int rg = 0; rg < 4; rg++) {
            float m = fmaxf(fmaxf(sv[0][rg], sv[1][rg]), fmaxf(sv[2][rg], sv[3][rg]));
            #pragma unroll
            for (int d = 1; d < 16; d <<= 1) m = fmaxf(m, __shfl_xor(m, d));
            m_new[rg] = fmaxf(m_old[rg], m);
            alpha[rg] = __expf(m_old[rg] - m_new[rg]);
        }
        #pragma unroll
        for (int rg = 0; rg < 4; rg++) {
            float p0_ = __expf(sv[0][rg] - m_new[rg]);
            float p1_ = __expf(sv[1][rg] - m_new[rg]);
            float p2_ = __expf(sv[2][rg] - m_new[rg]);
            float p3_ = __expf(sv[3][rg] - m_new[rg]);
            pv[0][rg] = p0_; pv[1][rg] = p1_; pv[2][rg] = p2_; pv[3][rg] = p3_;
            float ss = p0_ + p1_ + p2_ + p3_;
            #pragma unroll
            for (int d = 1; d < 16; d <<= 1) ss += __shfl_xor(ss, d);
            tsum[rg] = ss;
        }
        #pragma unroll
        for (int rg = 0; rg < 4; rg++) {
            l_old[rg] = l_old[rg] * alpha[rg] + tsum[rg];
            m_old[rg] = m_new[rg];
        }
        #pragma unroll
        for (int vt = 0; vt < 8; vt++) {
            #pragma unroll
            for (int rg = 0; rg < 4; rg++) o[vt][rg] *= alpha[rg];
        }
        #pragma unroll
        for (int tg = 0; tg < 4; tg++) {
            #pragma unroll
            for (int rg = 0; rg < 4; rg++) {
                int off = ((quad << 2) + rg) * 72 + (tg << 4) + lm;
                float p = pv[tg][rg];
                unsigned short h = f2bf(p);
                Ph[wv][off] = h;
                Plo[wv][off] = f2bf_t(p - bf2f(h));
            }
        }
        __asm__ volatile("s_waitcnt lgkmcnt(0)" ::: "memory");
        #pragma unroll
        for (int c2 = 0; c2 < 2; c2++) {
            int poff = pwr + (c2 << 5) + (quad << 3);
            short8 pah = *(const short8*)&Ph[wv][poff];
            short8 pal = *(const short8*)&Plo[wv][poff];
            int cg = (jt << 1) + c2;
            #pragma unroll
            for (int vt = 0; vt < 8; vt++) {
                size_t b0 = ((size_t)(vt * 128 + cg) * 64 + lane) * 8;
                short8 vh = *(const short8*)(Vh + b0);
                short8 vl = *(const short8*)(Vl + b0);
                o[vt] = MFMA16(pah, vh, o[vt]);
                o[vt] = MFMA16(pah, vl, o[vt]);
                o[vt] = MFMA16(pal, vh, o[vt]);
            }
        }
    }
    size_t pb = ((size_t)rgg * 8 + pidx) * 16;
    #pragma unroll
    for (int rg = 0; rg < 4; rg++) {
        int r = (quad << 2) + rg;
        #pragma unroll
        for (int vt = 0; vt < 8; vt++)
            pO[(pb + r) * 128 + (vt << 4) + lm] = o[vt][rg];
    }
    if (lm == 0) {
        #pragma unroll
        for (int rg = 0; rg < 4; rg++) {
            int r = (quad << 2) + rg;
            pM[pb + r] = m_old[rg];
            pL[pb + r] = l_old[rg];
        }
    }
}

// Merge the 8 col-chunk partials per 16-row group (exact fp32 softmax merge).
__global__ __launch_bounds__(256) void hc2s_merge(const float* __restrict__ pO,
        const float* __restrict__ pM, const float* __restrict__ pL,
        float* __restrict__ O)
{
    int rgg = blockIdx.x;
    int tid = threadIdx.x;
    int r = tid >> 4;
    int c0 = (tid & 15) << 3;
    float m[8], e[8];
    float M = -INFINITY;
    #pragma unroll
    for (int i = 0; i < 8; i++) {
        m[i] = pM[((size_t)rgg * 8 + i) * 16 + r];
        M = fmaxf(M, m[i]);
    }
    float L = 0.f;
    #pragma unroll
    for (int i = 0; i < 8; i++) {
        e[i] = __expf(m[i] - M);
        L += pL[((size_t)rgg * 8 + i) * 16 + r] * e[i];
    }
    float invL = __builtin_amdgcn_rcpf(L);
    float a[8];
    #pragma unroll
    for (int k = 0; k < 8; k++) a[k] = 0.f;
    #pragma unroll
    for (int i = 0; i < 8; i++) {
        const float* src = pO + (((size_t)rgg * 8 + i) * 16 + r) * 128 + c0;
        float4 v0 = *(const float4*)src;
        float4 v1 = *(const float4*)(src + 4);
        a[0] += v0.x * e[i]; a[1] += v0.y * e[i]; a[2] += v0.z * e[i]; a[3] += v0.w * e[i];
        a[4] += v1.x * e[i]; a[5] += v1.y * e[i]; a[6] += v1.z * e[i]; a[7] += v1.w * e[i];
    }
    float* dst = O + ((size_t)rgg * 16 + r) * 128 + c0;
    #pragma unroll
    for (int k = 0; k < 8; k++) dst[k] = a[k] * invL;
}

// ---------------------------------------------------------------------------
// MFMA 2-layer GRU, merged-phase, register-recurrence.
// MFMA issue order ROUND-ROBINS the 8 accumulators per operand slot
// (per-accumulator operand order preserved -> bit-identical results; only
// inter-acc interleave changes, breaking latency-bound dependency chains).
// ---------------------------------------------------------------------------
__global__ __launch_bounds__(512, 2) void gru_mfma(
    const float* __restrict__ xg,
    const unsigned short* __restrict__ wih0p,
    const unsigned short* __restrict__ whh0p,
    const unsigned short* __restrict__ wih1p,
    const unsigned short* __restrict__ whh1p,
    const float* __restrict__ bih0, const float* __restrict__ bhh0,
    const float* __restrict__ bih1, const float* __restrict__ bhh1,
    float* __restrict__ xh)
{
    __shared__ __attribute__((aligned(16))) unsigned short h0A[2][2][16 * 136]; // 17.4 KB
    __shared__ __attribute__((aligned(16))) unsigned short h1A[2][2][16 * 136]; // 17.4 KB
    __shared__ __attribute__((aligned(16))) unsigned short xA[2][2][16 * 40];   // 5.1 KB

    const int tid = threadIdx.x;
    const int w2 = tid >> 6;
    const int lane = tid & 63;
    const int quad = lane >> 4;
    const int lm = lane & 15;
    const int n0 = blockIdx.x << 4;
    const int j = (w2 << 4) + lm;

    for (int i = tid; i < 2 * 2 * 16 * 136; i += 512) {
        ((unsigned short*)h0A)[i] = 0;
        ((unsigned short*)h1A)[i] = 0;
    }
    for (int i = tid; i < 2 * 2 * 16 * 40; i += 512) ((unsigned short*)xA)[i] = 0;

    float br0 = bih0[j] + bhh0[j];
    float bz0 = bih0[128 + j] + bhh0[128 + j];
    float bni0 = bih0[256 + j];
    float bnh0 = bhh0[256 + j];
    float br1 = bih1[j] + bhh1[j];
    float bz1 = bih1[128 + j] + bhh1[128 + j];
    float bni1 = bih1[256 + j];
    float bnh1 = bhh1[256 + j];

    // register-resident weight fragments (t-invariant)
    short8 W0x[3], W0h[3][4], W1x[3][4], W1h[3][4];
    {
        const int lb = lane * 8;
        W0x[0] = *(const short8*)&wih0p[(size_t)(w2) * 512 + lb];
        W0x[1] = *(const short8*)&wih0p[(size_t)(8 + w2) * 512 + lb];
        W0x[2] = *(const short8*)&wih0p[(size_t)(16 + w2) * 512 + lb];
        #pragma unroll
        for (int c = 0; c < 4; c++) {
            W0h[0][c] = *(const short8*)&whh0p[(size_t)((w2) * 4 + c) * 512 + lb];
            W0h[1][c] = *(const short8*)&whh0p[(size_t)((8 + w2) * 4 + c) * 512 + lb];
            W0h[2][c] = *(const short8*)&whh0p[(size_t)((16 + w2) * 4 + c) * 512 + lb];
            W1x[0][c] = *(const short8*)&wih1p[(size_t)((w2) * 4 + c) * 512 + lb];
            W1x[1][c] = *(const short8*)&wih1p[(size_t)((8 + w2) * 4 + c) * 512 + lb];
            W1x[2][c] = *(const short8*)&wih1p[(size_t)((16 + w2) * 4 + c) * 512 + lb];
            W1h[0][c] = *(const short8*)&whh1p[(size_t)((w2) * 4 + c) * 512 + lb];
            W1h[1][c] = *(const short8*)&whh1p[(size_t)((8 + w2) * 4 + c) * 512 + lb];
            W1h[2][c] = *(const short8*)&whh1p[(size_t)((16 + w2) * 4 + c) * 512 + lb];
        }
    }

    const int aoff = lm * 136 + quad * 8;
    const int xoff = lm * 40 + quad * 8;
    const bool stager = tid < 16 * DDIM;
    const int sn = tid / DDIM, sd = tid % DDIM;            // hoisted div/mod
    const float* xrow = xg + (size_t)(n0 + sn) * (DDIM * TSTEPS) + sd * TSTEPS;
    const int soff = sn * 40 + sd;

    float h0reg[4] = {0.f, 0.f, 0.f, 0.f};
    float h1reg[4] = {0.f, 0.f, 0.f, 0.f};

    // ---- prologue: stage x(0)->xA[0], x(1)->xA[1] ----
    if (stager) {
        float v0 = xrow[0], v1 = xrow[1];
        unsigned short a = f2bf_t(v0);
        xA[0][0][soff] = a; xA[0][1][soff] = f2bf_t(v0 - bf2f(a));
        unsigned short b = f2bf_t(v1);
        xA[1][0][soff] = b; xA[1][1][soff] = f2bf_t(v1 - bf2f(b));
    }
    __syncthreads();

    // ---- prologue: L0(0) with h0(-1)=0 (x-term only) -> h0(0) ----
    {
        f32x4 accr = (f32x4){br0, br0, br0, br0};
        f32x4 accz = (f32x4){bz0, bz0, bz0, bz0};
        f32x4 accni = (f32x4){bni0, bni0, bni0, bni0};
        short8 axh = *(const short8*)&xA[0][0][xoff];
        short8 axl = *(const short8*)&xA[0][1][xoff];
        accr = MFMA16(axh, W0x[0], accr);
        accz = MFMA16(axh, W0x[1], accz);
        accni = MFMA16(axh, W0x[2], accni);
        accr = MFMA16(axl, W0x[0], accr);
        accz = MFMA16(axl, W0x[1], accz);
        accni = MFMA16(axl, W0x[2], accni);
        #pragma unroll
        for (int rg = 0; rg < 4; rg++) {
            float r = sigm(accr[rg]);
            float z = sigm(accz[rg]);
            float nc = tanh_f(accni[rg] + r * bnh0);
            float hnew = nc - z * nc;     // h_old = 0
            h0reg[rg] = hnew;
            int off = (quad * 4 + rg) * 136 + j;
            unsigned short hh_ = f2bf_t(hnew);
            h0A[0][0][off] = hh_;
            h0A[0][1][off] = f2bf_t(hnew - bf2f(hh_));
        }
    }
    __syncthreads();

#define GRU_IT(B, DO_L0, XT, LAST)                                                \
{                                                                                 \
    float xv = 0.f;                                                               \
    if ((XT) >= 0 && stager) xv = xrow[XT];   /* issue early, write late */       \
    f32x4 accr0 = (f32x4){br0, br0, br0, br0};                                    \
    f32x4 accz0 = (f32x4){bz0, bz0, bz0, bz0};                                    \
    f32x4 accni0 = (f32x4){bni0, bni0, bni0, bni0};                               \
    f32x4 accnh0 = (f32x4){bnh0, bnh0, bnh0, bnh0};                               \
    f32x4 accr1 = (f32x4){br1, br1, br1, br1};                                    \
    f32x4 accz1 = (f32x4){bz1, bz1, bz1, bz1};                                    \
    f32x4 accni1 = (f32x4){bni1, bni1, bni1, bni1};                               \
    f32x4 accnh1 = (f32x4){bnh1, bnh1, bnh1, bnh1};                               \
    if (DO_L0) {                                                                  \
        short8 axh = *(const short8*)&xA[(B) ^ 1][0][xoff];                       \
        short8 axl = *(const short8*)&xA[(B) ^ 1][1][xoff];                       \
        accr0 = MFMA16(axh, W0x[0], accr0);                                       \
        accz0 = MFMA16(axh, W0x[1], accz0);                                       \
        accni0 = MFMA16(axh, W0x[2], accni0);                                     \
        accr0 = MFMA16(axl, W0x[0], accr0);                                       \
        accz0 = MFMA16(axl, W0x[1], accz0);                                       \
        accni0 = MFMA16(axl, W0x[2], accni0);                                     \
    }                                                                             \
    _Pragma("unroll")                                                             \
    for (int c = 0; c < 4; c++) {                                                 \
        short8 a0h = *(const short8*)&h0A[B][0][aoff + c * 32];                   \
        short8 a0l = *(const short8*)&h0A[B][1][aoff + c * 32];                   \
        short8 a1h = *(const short8*)&h1A[(B) ^ 1][0][aoff + c * 32];             \
        short8 a1l = *(const short8*)&h1A[(B) ^ 1][1][aoff + c * 32];             \
        /* slot a0h: round-robin accs (per-acc operand order preserved) */        \
        if (DO_L0) {                                                              \
            accr0 = MFMA16(a0h, W0h[0][c], accr0);                                \
            accz0 = MFMA16(a0h, W0h[1][c], accz0);                                \
            accnh0 = MFMA16(a0h, W0h[2][c], accnh0);                              \
        }                                                                         \
        accr1 = MFMA16(a0h, W1x[0][c], accr1);                                    \
        accz1 = MFMA16(a0h, W1x[1][c], accz1);                                    \
        accni1 = MFMA16(a0h, W1x[2][c], accni1);                                  \
        /* slot a0l */                                                            \
        if (DO_L0) {                                                              \
            accr0 = MFMA16(a0l, W0h[0][c], accr0);                                \
            accz0 = MFMA16(a0l, W0h[1][c], accz0);                                \
            accnh0 = MFMA16(a0l, W0h[2][c], accnh0);                              \
        }                                                                         \
        accr1 = MFMA16(a0l, W1x[0][c], accr1);                                    \
        accz1 = MFMA16(a0l, W1x[1][c], accz1);                                    \
        accni1 = MFMA16(a0l, W1x[2][c], accni1);                                  \
        /* slot a1h */                                                            \
        accr1 = MFMA16(a1h, W1h[0][c], accr1);                                    \
        accz1 = MFMA16(a1h, W1h[1][c], accz1);                                    \
        accnh1 = MFMA16(a1h, W1h[2][c], accnh1);                                  \
        /* slot a1l */                                                            \
        accr1 = MFMA16(a1l, W1h[0][c], accr1);                                    \
        accz1 = MFMA16(a1l, W1h[1][c], accz1);                                    \
        accnh1 = MFMA16(a1l, W1h[2][c], accnh1);                                  \
    }                                                                             \
    if (DO_L0) {                                                                  \
        _Pragma("unroll")                                                         \
        for (int rg = 0; rg < 4; rg++) {                                          \
            float r = sigm(accr0[rg]);                                            \
            float z = sigm(accz0[rg]);                                            \
            float nc = tanh_f(accni0[rg] + r * accnh0[rg]);                       \
            float hnew = nc + z * (h0reg[rg] - nc);                               \
            h0reg[rg] = hnew;                                                     \
            int off = (quad * 4 + rg) * 136 + j;                                  \
            unsigned short hh_ = f2bf_t(hnew);                                    \
            h0A[(B) ^ 1][0][off] = hh_;                                           \
            h0A[(B) ^ 1][1][off] = f2bf_t(hnew - bf2f(hh_));                      \
        }                                                                         \
    }                                                                             \
    _Pragma("unroll")                                                             \
    for (int rg = 0; rg < 4; rg++) {                                              \
        float r = sigm(accr1[rg]);                                                \
        float z = sigm(accz1[rg]);                                                \
        float nc = tanh_f(accni1[rg] + r * accnh1[rg]);                           \
        float hnew = nc + z * (h1reg[rg] - nc);                                   \
        h1reg[rg] = hnew;                                                         \
        if (LAST) {                                                               \
            xh[(size_t)(n0 + quad * 4 + rg) * HDIM + j] = hnew;                   \
        } else {                                                                  \
            int off = (quad * 4 + rg) * 136 + j;                                  \
            unsigned short hh_ = f2bf_t(hnew);                                    \
            h1A[B][0][off] = hh_;                                                 \
            h1A[B][1][off] = f2bf_t(hnew - bf2f(hh_));                            \
        }                                                                         \
    }                                                                             \
    if ((XT) >= 0 && stager) {                                                    \
        unsigned short hh_ = f2bf_t(xv);                                          \
        xA[B][0][soff] = hh_;                                                     \
        xA[B][1][soff] = f2bf_t(xv - bf2f(hh_));                                  \
    }                                                                             \
    if (!(LAST)) __syncthreads();                                                 \
}

    // iters 0..61 (x-loads i+2 = 2..63 all valid)
    for (int i = 0; i < 62; i += 2) {
        GRU_IT(0, true, i + 2, false)
        GRU_IT(1, true, i + 3, false)
    }
    GRU_IT(0, true, -1, false)    // iter 62: L0(63)+L1(62), no more x
    GRU_IT(1, false, -1, true)    // iter 63: L1(63) only -> xh
#undef GRU_IT
}

// ---------------------------------------------------------------------------
// den / s2ct (unchanged)
// ---------------------------------------------------------------------------
__global__ __launch_bounds__(256) void den_atomic(const float* __restrict__ cm,
        const float* __restrict__ mv, float* __restrict__ den)
{
    int c = blockIdx.x * 64 + (threadIdx.x & 63);
    int rg = threadIdx.x >> 6;
    int nbase = blockIdx.y * 128;
    float acc = 0.f;
    for (int i = 0; i < 32; i++) {
        int n = nbase + rg + (i << 2);
        acc += cm[(size_t)n * CDIM + c] * mv[n];
    }
    __shared__ float red[4][64];
    red[rg][threadIdx.x & 63] = acc;
    __syncthreads();
    if (rg == 0)
        atomicAdd(&den[c], red[0][threadIdx.x] + red[1][threadIdx.x] +
                           red[2][threadIdx.x] + red[3][threadIdx.x]);
}

__global__ __launch_bounds__(256) void s2ct_trans(const float* __restrict__ cm,
        const float* __restrict__ mv, const float* __restrict__ den,
        float* __restrict__ s2cT)
{
    __shared__ float tile[64][65];
    __shared__ float mvs[64];
    const int tid = threadIdx.x;
    const int n0 = blockIdx.x << 6;
    const int c0 = blockIdx.y << 6;
    const int lc = tid & 63, lr = tid >> 6;
    if (tid < 64) mvs[tid] = mv[n0 + tid];
    #pragma unroll
    for (int i = 0; i < 16; i++) {
        int n = lr + (i << 2);
        tile[n][lc] = cm[(size_t)(n0 + n) * CDIM + c0 + lc];
    }
    __syncthreads();
    #pragma unroll
    for (int i = 0; i < 16; i++) {
        int c = lr + (i << 2);
        float m = tile[lc][c];
        float d = den[c0 + c];
        s2cT[(size_t)(c0 + c) * NR + n0 + lc] = (m * mvs[lc]) / (d * m + 1.f);
    }
}

// ---------------------------------------------------------------------------
// Small helpers
// ---------------------------------------------------------------------------
__global__ void row_norm(const float* __restrict__ a, float* __restrict__ out)
{
    int r = blockIdx.x;
    float acc = 0.f;
    for (int h = threadIdx.x; h < HDIM; h += 64) {
        float v = a[(size_t)r * HDIM + h];
        acc += v * v;
    }
    for (int o = 32; o > 0; o >>= 1) acc += __shfl_down(acc, o);
    if (threadIdx.x == 0) out[r] = sqrtf(acc);
}

__global__ void row_nonzero(const float* __restrict__ a, float* __restrict__ out)
{
    int r = blockIdx.x;
    float acc = 0.f;
    for (int h = threadIdx.x; h < HDIM; h += 64) acc += a[(size_t)r * HDIM + h];
    for (int o = 32; o > 0; o >>= 1) acc += __shfl_down(acc, o);
    if (threadIdx.x == 0) out[r] = (acc != 0.f) ? 1.f : 0.f;
}

__global__ void row_norm_nz(const float* __restrict__ a, float* __restrict__ nrm,
                            float* __restrict__ nz)
{
    int r = blockIdx.x;
    float acc = 0.f, s = 0.f;
    for (int h = threadIdx.x; h < HDIM; h += 64) {
        float v = a[(size_t)r * HDIM + h];
        acc += v * v;
        s += v;
    }
    for (int o = 32; o > 0; o >>= 1) { acc += __shfl_down(acc, o); s += __shfl_down(s, o); }
    if (threadIdx.x == 0) { nrm[r] = sqrtf(acc); nz[r] = (s != 0.f) ? 1.f : 0.f; }
}

// cos_softmax_row: wave-shuffle reductions, __expf + rcp.
__global__ __launch_bounds__(256) void cos_softmax_row(float* __restrict__ data, int N,
        const float* __restrict__ rn, const float* __restrict__ cn,
        const float* __restrict__ vmask)
{
    int row = blockIdx.x;
    float* d = data + (size_t)row * N;
    int tid = threadIdx.x;
    int wv = tid >> 6, lane = tid & 63;
    __shared__ float red[8];
    float rnv = rn ? rn[row] : 0.f;
    float mx = -INFINITY;
    for (int j = tid; j < N; j += 256) {
        float v = d[j];
        if (cn) v = v * __builtin_amdgcn_rcpf(fmaxf(rnv * cn[j], 1e-12f));
        if (vmask && vmask[j] == 0.f) v = -1e9f;
        d[j] = v;
        mx = fmaxf(mx, v);
    }
    #pragma unroll
    for (int m = 1; m < 64; m <<= 1) mx = fmaxf(mx, __shfl_xor(mx, m));
    if (lane == 0) red[wv] = mx;
    __syncthreads();
    float M = fmaxf(fmaxf(red[0], red[1]), fmaxf(red[2], red[3]));
    float sum = 0.f;
    for (int j = tid; j < N; j += 256) {
        float e = __expf(d[j] - M);
        d[j] = e;
        sum += e;
    }
    #pragma unroll
    for (int m = 1; m < 64; m <<= 1) sum += __shfl_xor(sum, m);
    if (lane == 0) red[4 + wv] = sum;
    __syncthreads();
    float inv = __builtin_amdgcn_rcpf(red[4] + red[5] + red[6] + red[7]);
    for (int j = tid; j < N; j += 256) {
        float v = d[j] * inv;
        if (vmask) v *= vmask[j];
        d[j] = v;
    }
}

// hh_scatter: one block per row i; loads hsh[i,:] once, scatters its K
// neighbors; threads 0..K-1 also handle the colsum scatter (fused).
__global__ void hh_scatter(const float* __restrict__ vals, const int* __restrict__ idxs,
                           const float* __restrict__ hsh, float* __restrict__ hh,
                           float* __restrict__ colsum)
{
    int i = blockIdx.x;
    int t = threadIdx.x;
    float hv = hsh[(size_t)i * HDIM + t];
    #pragma unroll
    for (int k = 0; k < KTOP; k++) {
        int p = i * KTOP + k;
        int jj = idxs[p];
        float v = vals[p];
        atomicAdd(&hh[(size_t)jj * HDIM + t], v * hv);
    }
    if (t < KTOP) {
        int p = i * KTOP + t;
        atomicAdd(&colsum[idxs[p]], vals[p]);
    }
}

__global__ void hh_diag(const float* __restrict__ colsum, const float* __restrict__ diag,
                        const float* __restrict__ hsh, float* __restrict__ hh)
{
    int idx = blockIdx.x * 256 + threadIdx.x;
    int j = idx >> 7;
    if (colsum[j] != 0.f) hh[idx] += diag[j] * hsh[idx];
}

// ---------------------------------------------------------------------------
// host-side helpers
// ---------------------------------------------------------------------------
static inline void mg(hipStream_t s, const float* A, const unsigned short* Bh,
                      const unsigned short* Bl, const float* bias, float* C,
                      int M, int N, int K, int z, int flags,
                      const float* aux = nullptr, float* sub = nullptr,
                      const unsigned short* Ah = nullptr, const unsigned short* Al = nullptr,
                      const float* wout = nullptr, const float* bout = nullptr,
                      float* hout = nullptr)
{
    MG g{A, Bh, Bl, bias, C, aux, sub, Ah, Al,
         nullptr, nullptr, nullptr, nullptr, wout, bout, hout,
         N, K, K / z, flags | (z > 1 ? 4 : 0) | (Ah ? 16 : 0), 0};
    mfma_gemm<<<dim3(N / 64, M / 64, z), 256, 0, s>>>(g);
}
// dual-output: z-dim selects output set; same A, full K both.
static inline void mg_dual(hipStream_t s, const float* A,
                           const unsigned short* Bh, const unsigned short* Bl,
                           const float* bias, float* C, int flags1,
                           const unsigned short* Bh2, const unsigned short* Bl2,
                           const float* bias2, float* C2, int flags2,
                           int M, int N, int K,
                           const float* aux, float* sub,
                           const float* wout, const float* bout, float* hout)
{
    MG g{A, Bh, Bl, bias, C, aux, sub, nullptr, nullptr,
         Bh2, Bl2, bias2, C2, wout, bout, hout,
         N, K, K, flags1 | 32, flags2};
    mfma_gemm<<<dim3(N / 64, M / 64, 2), 256, 0, s>>>(g);
}
static inline void pbt(hipStream_t s, const float* src, unsigned short* hi,
                       unsigned short* lo, int N, int K)
{
    int total = (N / 16) * (K / 32) * 64;
    pack_bt<<<(total + 255) / 256, 256, 0, s>>>(src, hi, lo, K, total);
}
static inline void pboth(hipStream_t s, const float* src,
                         unsigned short* bth, unsigned short* btl,
                         unsigned short* knh, unsigned short* knl, int N)
{
    int totBT = (N / 16) * 4 * 64;
    int totKN = 8 * (N / 32) * 64;
    int tot = totBT > totKN ? totBT : totKN;
    pack_both<<<(tot + 255) / 256, 256, 0, s>>>(src, bth, btl, knh, knl, N, totKN);
}

extern "C" void kernel_launch(void* const* d_in, const int* in_sizes, int n_in,
                              void* d_out, int out_size, void* d_ws, size_t ws_size,
                              hipStream_t stream)
{
    (void)in_sizes; (void)n_in; (void)out_size; (void)ws_size;
    const float* x    = (const float*)d_in[0];
    const float* cm   = (const float*)d_in[1];
    const float* mv   = (const float*)d_in[2];
    const float* wih0 = (const float*)d_in[3];
    const float* whh0 = (const float*)d_in[4];
    const float* bih0 = (const float*)d_in[5];
    const float* bhh0 = (const float*)d_in[6];
    const float* wih1 = (const float*)d_in[7];
    const float* whh1 = (const float*)d_in[8];
    const float* bih1 = (const float*)d_in[9];
    const float* bhh1 = (const float*)d_in[10];
    const float* w_ps = (const float*)d_in[11];
    const float* b_ps = (const float*)d_in[12];
    const float* w_hs = (const float*)d_in[13];
    const float* b_hs = (const float*)d_in[14];
    const float* w_ps_fore = (const float*)d_in[15];
    const float* b_ps_fore = (const float*)d_in[16];
    const float* w_hs_fore = (const float*)d_in[17];
    const float* b_hs_fore = (const float*)d_in[18];
    const float* w_ps_back = (const float*)d_in[19];
    const float* b_ps_back = (const float*)d_in[20];
    const float* w_hs_back = (const float*)d_in[21];
    const float* b_hs_back = (const float*)d_in[22];
    const float* w_indi = (const float*)d_in[23];
    const float* b_indi = (const float*)d_in[24];
    const float* w_out  = (const float*)d_in[25];
    const float* b_out  = (const float*)d_in[26];
    float* out = (float*)d_out;

    // ---- workspace layout (floats) ----
    float* ws = (float*)d_ws;
    float* BIG = ws;                         // 16,777,216 (overlaid)
    // zero cluster (ONE memset covers all of it):
    float* zero0 = ws + 16777216;
    float* den      = zero0;                 // 512
    float* hidden   = den + 512;             // 65536
    float* hidden2  = hidden + 65536;        // 65536
    float* colsum   = hidden2 + 65536;       // 4096
    float* p0       = colsum + 4096;         // 524288
    float* hidden_h = p0 + 524288;           // 524288
    float* p_shared = hidden_h + 524288;     // 524288 (split-K atomics)
    float* h_si     = p_shared + 524288;     // 524288 (split-K atomics)
    const size_t ZERO_FLOATS = 512 + 65536 + 65536 + 4096 + 4 * 524288;
    // live buffers:
    float* h1 = h_si + 524288;               // x_hidden
    float* v1 = h1 + 524288;                 // 512
    float* xnorm = v1 + 512;                 // 4096
    float* h2n = xnorm + 4096;               // 512
    float* p_back = h2n + 512;               // 524288
    float* h_shared = p_back + 524288;       // 524288
    float* hn = h_shared + 524288;           // 4096
    float* diagv = hn + 4096;                // 4096
    float* tvals = diagv + 4096;             // 40960
    int*   tidx = (int*)(tvals + 40960);     // 40960 ints
    float* v2 = (float*)(tidx + 40960);      // 4096
    float* hhn = v2 + 4096;                  // 4096
    float* hsi0 = hhn + 4096;                // 524288
    float* h_back = hsi0 + 524288;           // 524288
    float* indi = h_back + 524288;           // 524288
    float* extra = indi + 524288;            // 131072

    // GRU-phase overlays inside BIG:
    unsigned short* wih0p = (unsigned short*)(BIG + 5242880);
    unsigned short* whh0p = wih0p + 12288;
    unsigned short* wih1p = whh0p + 49152;
    unsigned short* whh1p = wih1p + 49152;
    // concept-phase overlays inside BIG:
    float* s2cT = BIG;
    float* L    = BIG + 2097152;
    float* c2s  = BIG + 4194304;
    unsigned short* PB = (unsigned short*)(BIG + 6291456);
    unsigned short* pbt_xh_hi = PB;
    unsigned short* pbt_xh_lo = pbt_xh_hi + 524288;
    unsigned short* pkn_xh_hi = pbt_xh_lo + 524288;
    unsigned short* pkn_xh_lo = pkn_xh_hi + 524288;
    unsigned short* pbt_h2_hi = pkn_xh_lo + 524288;
    unsigned short* pbt_h2_lo = pbt_h2_hi + 65536;
    unsigned short* pkn_h2_hi = pbt_h2_lo + 65536;
    unsigned short* pkn_h2_lo = pkn_h2_hi + 65536;
    unsigned short* wps_hi  = pkn_h2_lo + 65536;
    unsigned short* wps_lo  = wps_hi + 16384;
    unsigned short* wpsb_hi = wps_lo + 16384;
    unsigned short* wpsb_lo = wpsb_hi + 16384;
    unsigned short* wpsf_hi = wpsb_lo + 16384;
    unsigned short* wpsf_lo = wpsf_hi + 16384;
    unsigned short* pbt_hsh_hi = (unsigned short*)p0;      // p0 dead after p_shared GEMM
    unsigned short* pbt_hsh_lo = pbt_hsh_hi + 524288;
    unsigned short* pbt_hh_hi = (unsigned short*)indi;     // indi written after flash
    unsigned short* pbt_hh_lo = pbt_hh_hi + 524288;
    unsigned short* pkn_hh_hi = (unsigned short*)hsi0;     // hsi0 written after flash
    unsigned short* pkn_hh_lo = pkn_hh_hi + 524288;
    // flash-partial overlays inside BIG (dead after scan_topk):
    float* part_O = BIG;                     // 4,194,304 floats
    float* part_m = BIG + 4194304;           // 32,768
    float* part_l = BIG + 4227072;           // 32,768
    unsigned short* EX = (unsigned short*)extra;
    unsigned short* whs_hi  = EX;            unsigned short* whs_lo  = EX + 16384;
    unsigned short* whsb_hi = EX + 32768;    unsigned short* whsb_lo = EX + 49152;
    unsigned short* whsf_hi = EX + 65536;    unsigned short* whsf_lo = EX + 81920;
    unsigned short* wind_hi = EX + 98304;    unsigned short* wind_lo = EX + 114688;

    // ---- one consolidated memset for all zero-init buffers + head output ----
    hipMemsetAsync(zero0, 0, ZERO_FLOATS * sizeof(float), stream);
    hipMemsetAsync(out, 0, NR * sizeof(float), stream);

    // ================= Phase A: MFMA 2-layer GRU =================
    {
        PAll pa;
        pa.wb_src[0] = wih0; pa.wb_dst[0] = wih0p;
        pa.wb_src[1] = whh0; pa.wb_dst[1] = whh0p;
        pa.wb_src[2] = wih1; pa.wb_dst[2] = wih1p;
        pa.wb_src[3] = whh1; pa.wb_dst[3] = whh1p;
        pa.w7_src[0] = w_ps;      pa.w7_hi[0] = wps_hi;  pa.w7_lo[0] = wps_lo;
        pa.w7_src[1] = w_ps_back; pa.w7_hi[1] = wpsb_hi; pa.w7_lo[1] = wpsb_lo;
        pa.w7_src[2] = w_ps_fore; pa.w7_hi[2] = wpsf_hi; pa.w7_lo[2] = wpsf_lo;
        pa.w7_src[3] = w_hs;      pa.w7_hi[3] = whs_hi;  pa.w7_lo[3] = whs_lo;
        pa.w7_src[4] = w_hs_back; pa.w7_hi[4] = whsb_hi; pa.w7_lo[4] = whsb_lo;
        pa.w7_src[5] = w_hs_fore; pa.w7_hi[5] = whsf_hi; pa.w7_lo[5] = whsf_lo;
        pa.w7_src[6] = w_indi;    pa.w7_hi[6] = wind_hi; pa.w7_lo[6] = wind_lo;
        pack_all<<<134, 256, 0, stream>>>(pa);
    }
    gru_mfma<<<NR / 16, 512, 0, stream>>>(x, wih0p, whh0p, wih1p, whh1p,
                                          bih0, bhh0, bih1, bhh1, h1);
    float* x_hidden = h1;

    // ================= Phase B: predefined-concept branch =================
    den_atomic<<<dim3(CDIM / 64, 32), 256, 0, stream>>>(cm, mv, den);
    s2ct_trans<<<dim3(NR / 64, CDIM / 64), 256, 0, stream>>>(cm, mv, den, s2cT);
    pboth(stream, x_hidden, pbt_xh_hi, pbt_xh_lo, pkn_xh_hi, pkn_xh_lo, NR);
    mg(stream, s2cT, pkn_xh_hi, pkn_xh_lo, nullptr, hidden, CDIM, HDIM, NR, 16, 0);
    row_nonzero<<<CDIM, 64, 0, stream>>>(hidden, v1);
    mg(stream, hidden, pbt_xh_hi, pbt_xh_lo, nullptr, L, CDIM, NR, HDIM, 1, 0);
    cos_softmax_row<<<CDIM, 256, 0, stream>>>(L, NR, nullptr, nullptr, nullptr);
    mg(stream, L, pkn_xh_hi, pkn_xh_lo, nullptr, hidden2, CDIM, HDIM, NR, 16, 0);
    row_norm<<<NR, 64, 0, stream>>>(x_hidden, xnorm);
    row_norm<<<CDIM, 64, 0, stream>>>(hidden2, h2n);
    pboth(stream, hidden2, pbt_h2_hi, pbt_h2_lo, pkn_h2_hi, pkn_h2_lo, CDIM);
    // packed-A: x_hidden already packed as pbt_xh
    mg(stream, x_hidden, pbt_h2_hi, pbt_h2_lo, nullptr, c2s, NR, CDIM, HDIM, 1, 0,
       nullptr, nullptr, pbt_xh_hi, pbt_xh_lo);
    cos_softmax_row<<<NR, 256, 0, stream>>>(c2s, CDIM, xnorm, h2n, v1);
    mg(stream, c2s, pkn_h2_hi, pkn_h2_lo, nullptr, p0, NR, HDIM, CDIM, 4, 0);
    // split-K (z=2, bias on z0 only) -> 256 blocks, full CU coverage
    mg(stream, p0, wps_hi, wps_lo, b_ps, p_shared, NR, HDIM, HDIM, 2, 1);
    // DUAL: z=0 -> p_back (+fused h_shared = x_hidden - p_back)
    //       z=1 -> out_ps head-accumulated into out (no store)
    mg_dual(stream, p_shared,
            wpsb_hi, wpsb_lo, b_ps_back, p_back, 1 | 8,
            wpsf_hi, wpsf_lo, b_ps_fore, nullptr, 1 | 2 | 64 | 128,
            NR, HDIM, HDIM, x_hidden, h_shared, w_out, b_out, out);

    // ================= Phase C: hidden-concept branch =================
    row_norm<<<NR, 64, 0, stream>>>(h_shared, hn);
    pbt(stream, h_shared, pbt_hsh_hi, pbt_hsh_lo, NR, HDIM);
    // packed-A: the 4096-block NxN GEMM reuses pbt_hsh for BOTH operands
    mg(stream, h_shared, pbt_hsh_hi, pbt_hsh_lo, nullptr, BIG, NR, NR, HDIM, 1, 0,
       nullptr, nullptr, pbt_hsh_hi, pbt_hsh_lo);
    scan_topk<<<NR, 256, 0, stream>>>(BIG, hn, diagv, tvals, tidx);
    hh_scatter<<<NR, HDIM, 0, stream>>>(tvals, tidx, h_shared, hidden_h, colsum);
    hh_diag<<<2048, 256, 0, stream>>>(colsum, diagv, h_shared, hidden_h);
    row_norm_nz<<<NR, 64, 0, stream>>>(hidden_h, hhn, v2);
    pboth(stream, hidden_h, pbt_hh_hi, pbt_hh_lo, pkn_hh_hi, pkn_hh_lo, NR);
    hc2s_flash<<<dim3(NR / 64, 4), 512, 0, stream>>>(h_shared, hn, hhn, v2,
                                                     pbt_hh_hi, pbt_hh_lo,
                                                     pkn_hh_hi, pkn_hh_lo,
                                                     part_O, part_m, part_l);
    hc2s_merge<<<NR / 16, 256, 0, stream>>>(part_O, part_m, part_l, hsi0);
    // split-K (z=2, bias on z0 only) -> 256 blocks
    mg(stream, hsi0, whs_hi, whs_lo, b_hs, h_si, NR, HDIM, HDIM, 2, 1);
    // DUAL: z=0 -> h_back (+fused indi = h_shared - h_back)
    //       z=1 -> out_hs head-accumulated into out (no store)
    mg_dual(stream, h_si,
            whsb_hi, whsb_lo, b_hs_back, h_back, 1 | 8,
            whsf_hi, whsf_lo, b_hs_fore, nullptr, 1 | 2 | 64 | 128,
            NR, HDIM, HDIM, h_shared, indi, w_out, b_out, out);

    // ================= Phase D: individual branch + head (fused) =================
    // out_indi head-accumulated; bn==0 blocks add b_out once per row.
    mg(stream, indi, wind_hi, wind_lo, b_indi, nullptr, NR, HDIM, HDIM, 1,
       1 | 2 | 64 | 128 | 256, nullptr, nullptr, nullptr, nullptr,
       w_out, b_out, out);
}